// Round 3
// baseline (316.686 us; speedup 1.0000x reference)
//
#include <hip/hip_runtime.h>

typedef unsigned short u16;
typedef __attribute__((ext_vector_type(8))) short bf8_t;    // 8 x bf16 (4 VGPRs)
typedef __attribute__((ext_vector_type(4))) float f4_t;     // 4 x f32
typedef __attribute__((ext_vector_type(4))) unsigned short u16x4;
typedef __attribute__((ext_vector_type(8))) unsigned short u16x8;

__device__ __forceinline__ float b2f(u16 h) {
  union { unsigned u; float f; } v; v.u = ((unsigned)h) << 16; return v.f;
}
__device__ __forceinline__ u16 f2b(float f) {
  union { float f; unsigned u; } v; v.f = f;
  unsigned u = v.u;
  u += 0x7fffu + ((u >> 16) & 1u);   // round-nearest-even
  return (u16)(u >> 16);
}

#define AS1C(p) ((const __attribute__((address_space(1))) void*)(p))
#define AS3(p)  ((__attribute__((address_space(3))) void*)(p))

// one fused f32 -> bf16 convert over all 5 weight/input arrays
__global__ __launch_bounds__(256)
void cvt_all(const float* __restrict__ x, const float* __restrict__ inW,
             const float* __restrict__ xprojW, const float* __restrict__ dtW,
             const float* __restrict__ outW,
             u16* __restrict__ xb, u16* __restrict__ inWb, u16* __restrict__ xpb,
             u16* __restrict__ dtWb, u16* __restrict__ outWb)
{
  int i = blockIdx.x * 256 + threadIdx.x;      // float4 index, total 2703360
  if (i >= 2703360) return;
  const float* s; u16* d; int off;
  if (i < 1048576)      { s = x;      d = xb;    off = i; }
  else if (i < 2097152) { s = inW;    d = inWb;  off = i - 1048576; }
  else if (i < 2146304) { s = xprojW; d = xpb;   off = i - 2097152; }
  else if (i < 2179072) { s = dtW;    d = dtWb;  off = i - 2146304; }
  else                  { s = outW;   d = outWb; off = i - 2179072; }
  f4_t v = *(const f4_t*)(s + (size_t)off * 4);
  u16x4 o;
#pragma unroll
  for (int j = 0; j < 4; ++j) o[j] = f2b(v[j]);
  *(u16x4*)(d + (size_t)off * 4) = o;
}

// Stage one 128x64 bf16 tile (16 KB) into LDS, XOR-swizzled: granule (r,q)
// holds global colchunk q^(r&7). Staging lane i (chunk of 8 rows) fetches
// colchunk (i&7)^((i>>3)&7); reader uses granule (g ^ (row&7)). Bank-quad
// depends only on q_l -> 8 lanes per 4-bank group = 2/bank = conflict-free.
__device__ __forceinline__ void stage64(const u16* g, int ld, int row0, int rowmax,
                                        int k0, u16* lds, int wid, int lane) {
  int qg = (lane & 7) ^ ((lane >> 3) & 7);
#pragma unroll
  for (int c = 0; c < 4; ++c) {
    int chunk = wid * 4 + c;
    int r = row0 + chunk * 8 + (lane >> 3);
    if (r > rowmax) r = rowmax;                       // clamp (results discarded later)
    const u16* gp = g + (size_t)r * ld + k0 + qg * 8;
    __builtin_amdgcn_global_load_lds(AS1C(gp), AS3(lds + chunk * 512), 16, 0, 0);
  }
}

// C = A * Bt^T : A[M,K] bf16 row-major (lda), Bt[N,K] bf16 row-major (ldb).
// BK=64 (two 32-k half-steps per barrier epoch).
// EPI 1: x_proj   -> split-K partials: of32[(bx*4096+m)*96+n], n<96
// EPI 2: dt_proj  -> o16[m*2048+n] = bf16(softplus(acc + biasf[n]))
template<int EPI>
__device__ __forceinline__ void gemm_body(const u16* __restrict__ A, int lda,
             const u16* __restrict__ Bt, int ldb,
             int Kblk, int Nact,
             u16* __restrict__ o16, float* __restrict__ of32,
             float* __restrict__ of32b, const float* __restrict__ biasf)
{
  __shared__ u16 lsA[128 * 64];
  __shared__ u16 lsB[128 * 64];
  const int tid = threadIdx.x;
  const int wid = tid >> 6, lane = tid & 63;
  const int wm = wid >> 1, wn = wid & 1;          // 2x2 wave grid, 64x64 each
  const int lrow = lane & 15;
  const int kq = lane >> 4;                       // 0..3
  const int sw = lrow & 7;                        // swizzle key
  const int m0 = blockIdx.y * 128;
  const int n0 = (EPI == 1) ? 0 : blockIdx.x * 128;
  int kbase = 0;
  if (EPI == 1) kbase = blockIdx.x * Kblk;

  f4_t acc[4][4];
#pragma unroll
  for (int i = 0; i < 4; ++i)
#pragma unroll
    for (int j = 0; j < 4; ++j) acc[i][j] = {0.f, 0.f, 0.f, 0.f};

  for (int kt = kbase; kt < kbase + Kblk; kt += 64) {
    stage64(A,  lda, m0, 0x3fffffff, kt, lsA, wid, lane);
    stage64(Bt, ldb, n0, Nact - 1,   kt, lsB, wid, lane);
    __syncthreads();
#pragma unroll
    for (int h = 0; h < 2; ++h) {
      const int lk = ((h * 4 + kq) ^ sw) * 8;
      bf8_t af[4], bfr[4];
#pragma unroll
      for (int mi = 0; mi < 4; ++mi)
        af[mi] = *(const bf8_t*)&lsA[(wm * 64 + mi * 16 + lrow) * 64 + lk];
#pragma unroll
      for (int ni = 0; ni < 4; ++ni)
        bfr[ni] = *(const bf8_t*)&lsB[(wn * 64 + ni * 16 + lrow) * 64 + lk];
#pragma unroll
      for (int mi = 0; mi < 4; ++mi)
#pragma unroll
        for (int ni = 0; ni < 4; ++ni)
          acc[mi][ni] = __builtin_amdgcn_mfma_f32_16x16x32_bf16(af[mi], bfr[ni], acc[mi][ni], 0, 0, 0);
    }
    __syncthreads();
  }

  const int rq = (lane >> 4) * 4;                  // C/D: row=(lane>>4)*4+r, col=lane&15
#pragma unroll
  for (int mi = 0; mi < 4; ++mi) {
#pragma unroll
    for (int ni = 0; ni < 4; ++ni) {
#pragma unroll
      for (int r = 0; r < 4; ++r) {
        int m = m0 + wm * 64 + mi * 16 + rq + r;
        int n = n0 + wn * 64 + ni * 16 + lrow;
        float v = acc[mi][ni][r];
        if (EPI == 1) {
          if (n < 96) of32[((size_t)blockIdx.x * 4096 + m) * 96 + n] = v;
        } else if (EPI == 2) {
          float t = v + biasf[n];
          float sp = (t > 20.f) ? t : log1pf(__expf(t));
          o16[(size_t)m * 2048 + n] = f2b(sp);
        }
      }
    }
  }
}

__global__ __launch_bounds__(256)
void gemm_xp(const u16* A, int lda, const u16* Bt, int ldb, int Kblk, int Nact,
             u16* o16, float* of32, float* of32b, const float* biasf)
{ gemm_body<1>(A, lda, Bt, ldb, Kblk, Nact, o16, of32, of32b, biasf); }

__global__ __launch_bounds__(256)
void gemm_dt(const u16* A, int lda, const u16* Bt, int ldb, int Kblk, int Nact,
             u16* o16, float* of32, float* of32b, const float* biasf)
{ gemm_body<2>(A, lda, Bt, ldb, Kblk, Nact, o16, of32, of32b, biasf); }

// ---------------------------------------------------------------------------
// 4-phase 256x256 bf16 GEMM for in_proj (M=N=4096, K=1024).
// R1/R2 used 8 phases x 16 MFMA; since LDS (128 KB) pins occupancy at 1
// block/CU, VGPRs are free -> merge to 4 phases x 32 MFMA per 2 K-tiles,
// halving barriers (8->4/iter) and lgkm drains. B fragments (both N-halves)
// stay live across the A-half phases (registers already held them in R1).
// vmcnt invariant (loads/thread): prologue leaves B(t1)=4 in flight.
//   Q1: +A(t+1)4 -> 8;  consume buf0 (landed)
//   Q2: +B(t+2)4 -> 12; vmcnt(4) retires A(t+1),B(t+1) -> buf1 ready
//   Q3: +A(t+2)4 -> 8;  consume buf1
//   Q4: +B(t+3)4 -> 12; vmcnt(4) retires tile t+2 -> buf0 ready. invariant.
// Stage->region safety: buf.B reads complete in Q1/Q3 (sealed by barrier),
// buf.A by Q2/Q4 -> stages target only sealed regions.
// ---------------------------------------------------------------------------

// stage one 128x64 unit: 512 threads x 2 x 16B gload_lds. granule g = j*512 +
// wid*64 + lane -> lds row g>>3, slot g&7, global colchunk (g&7)^((g>>3)&7).
__device__ __forceinline__ void stageu(const u16* __restrict__ g, int ld,
                                       int row0, int k0, u16* ldsu,
                                       int wid, int lane) {
  int qg = (lane & 7) ^ ((lane >> 3) & 7);
#pragma unroll
  for (int j = 0; j < 2; ++j) {
    int rr = j * 64 + wid * 8 + (lane >> 3);
    const u16* gp = g + (size_t)(row0 + rr) * ld + k0 + qg * 8;
    __builtin_amdgcn_global_load_lds(AS1C(gp), AS3(ldsu + (j * 512 + wid * 64) * 8), 16, 0, 0);
  }
}

#define G8_BAR()   __builtin_amdgcn_s_barrier()
#define G8_LGKM0() do { asm volatile("s_waitcnt lgkmcnt(0)" ::: "memory"); \
                        __builtin_amdgcn_sched_barrier(0); } while (0)
#define G8_VM(N)   do { asm volatile("s_waitcnt vmcnt(" #N ")" ::: "memory"); \
                        __builtin_amdgcn_sched_barrier(0); } while (0)

#define RD_A(base, MH) do { \
  _Pragma("unroll") \
  for (int mi_ = 0; mi_ < 4; ++mi_) { \
    af[mi_][0] = *(const bf8_t*)((base) + arow + ((MH) * 64 + mi_ * 16) * 64 + aq0); \
    af[mi_][1] = *(const bf8_t*)((base) + arow + ((MH) * 64 + mi_ * 16) * 64 + aq1); \
  } } while (0)

#define RD_B(base, NH) do { \
  _Pragma("unroll") \
  for (int ni_ = 0; ni_ < 2; ++ni_) { \
    bfr[NH][ni_][0] = *(const bf8_t*)((base) + brow + ((NH) * 32 + ni_ * 16) * 64 + aq0); \
    bfr[NH][ni_][1] = *(const bf8_t*)((base) + brow + ((NH) * 32 + ni_ * 16) * 64 + aq1); \
  } } while (0)

#define MMA(MH, NH) do { \
  __builtin_amdgcn_s_setprio(1); \
  _Pragma("unroll") \
  for (int mi_ = 0; mi_ < 4; ++mi_) \
    _Pragma("unroll") \
    for (int ni_ = 0; ni_ < 2; ++ni_) { \
      acc[(MH) * 4 + mi_][(NH) * 2 + ni_] = __builtin_amdgcn_mfma_f32_16x16x32_bf16( \
          af[mi_][0], bfr[NH][ni_][0], acc[(MH) * 4 + mi_][(NH) * 2 + ni_], 0, 0, 0); \
      acc[(MH) * 4 + mi_][(NH) * 2 + ni_] = __builtin_amdgcn_mfma_f32_16x16x32_bf16( \
          af[mi_][1], bfr[NH][ni_][1], acc[(MH) * 4 + mi_][(NH) * 2 + ni_], 0, 0, 0); \
    } \
  __builtin_amdgcn_s_setprio(0); \
} while (0)

__global__ __launch_bounds__(512, 2)
void gemm8_in(const u16* __restrict__ A, const u16* __restrict__ Bt,
              u16* __restrict__ o16)
{
  __shared__ u16 ls[65536];                       // 128 KB: 2 buf x (A 32K + B 32K)
  const int tid = threadIdx.x;
  const int wid = tid >> 6, lane = tid & 63;
  const int wm = wid >> 2, wn = wid & 3;          // 2x4 wave grid, 128x64 per wave
  const int lrow = lane & 15;
  const int kq = lane >> 4;
  const int sw = lrow & 7;
  const int m0 = blockIdx.y * 256;
  const int n0 = blockIdx.x * 256;
  u16* lsA0 = ls;
  u16* lsB0 = ls + 16384;
  u16* lsA1 = ls + 32768;
  u16* lsB1 = ls + 49152;
  const int arow = (wm * 128 + lrow) * 64;
  const int brow = (wn * 64 + lrow) * 64;
  const int aq0 = (kq ^ sw) * 8;
  const int aq1 = ((4 + kq) ^ sw) * 8;

  f4_t acc[8][4];
#pragma unroll
  for (int i = 0; i < 8; ++i)
#pragma unroll
    for (int j = 0; j < 4; ++j) acc[i][j] = {0.f, 0.f, 0.f, 0.f};
  bf8_t af[4][2];
  bf8_t bfr[2][2][2];

  // prologue: tile0 (A0,A1,B0,B1)->buf0, tile1 (B0,B1)->buf1; keep 4 in flight
  stageu(A,  1024, m0,        0, lsA0,        wid, lane);
  stageu(A,  1024, m0 + 128,  0, lsA0 + 8192, wid, lane);
  stageu(Bt, 1024, n0,        0, lsB0,        wid, lane);
  stageu(Bt, 1024, n0 + 128,  0, lsB0 + 8192, wid, lane);
  stageu(Bt, 1024, n0,       64, lsB1,        wid, lane);
  stageu(Bt, 1024, n0 + 128, 64, lsB1 + 8192, wid, lane);
  G8_VM(4); G8_BAR();

#pragma unroll 1
  for (int i = 0; i < 7; ++i) {                   // iterations 0..6 (tiles 0..13)
    const int ka1 = (2 * i + 1) * 64;             // A of tile 2i+1
    const int k2  = ka1 + 64;                     // tile 2i+2
    const int kb3 = ka1 + 128;                    // B of tile 2i+3
    // Q1: read buf0 A-h0 + B (both halves); stage A(t+1)->buf1
    RD_A(lsA0, 0); RD_B(lsB0, 0); RD_B(lsB0, 1);
    stageu(A, 1024, m0,       ka1, lsA1,        wid, lane);
    stageu(A, 1024, m0 + 128, ka1, lsA1 + 8192, wid, lane);
    G8_BAR(); G8_LGKM0(); MMA(0, 0); MMA(0, 1); G8_BAR();
    // Q2: read buf0 A-h1; stage B(t+2)->buf0 (buf0.B sealed end Q1)
    RD_A(lsA0, 1);
    stageu(Bt, 1024, n0,       k2, lsB0,        wid, lane);
    stageu(Bt, 1024, n0 + 128, k2, lsB0 + 8192, wid, lane);
    G8_BAR(); G8_LGKM0(); MMA(1, 0); MMA(1, 1); G8_VM(4); G8_BAR();
    // Q3: read buf1 A-h0 + B (both); stage A(t+2)->buf0 (buf0.A sealed end Q2)
    RD_A(lsA1, 0); RD_B(lsB1, 0); RD_B(lsB1, 1);
    stageu(A, 1024, m0,       k2, lsA0,        wid, lane);
    stageu(A, 1024, m0 + 128, k2, lsA0 + 8192, wid, lane);
    G8_BAR(); G8_LGKM0(); MMA(0, 0); MMA(0, 1); G8_BAR();
    // Q4: read buf1 A-h1; stage B(t+3)->buf1 (buf1.B sealed end Q3)
    RD_A(lsA1, 1);
    stageu(Bt, 1024, n0,       kb3, lsB1,        wid, lane);
    stageu(Bt, 1024, n0 + 128, kb3, lsB1 + 8192, wid, lane);
    G8_BAR(); G8_LGKM0(); MMA(1, 0); MMA(1, 1); G8_VM(4); G8_BAR();
  }

  {                                               // last iteration: tiles 14,15
    const int ka1 = 960;
    RD_A(lsA0, 0); RD_B(lsB0, 0); RD_B(lsB0, 1);
    stageu(A, 1024, m0,       ka1, lsA1,        wid, lane);
    stageu(A, 1024, m0 + 128, ka1, lsA1 + 8192, wid, lane);
    G8_BAR(); G8_LGKM0(); MMA(0, 0); MMA(0, 1); G8_BAR();
    RD_A(lsA0, 1);
    G8_BAR(); G8_LGKM0(); MMA(1, 0); MMA(1, 1); G8_VM(0); G8_BAR();
    RD_A(lsA1, 0); RD_B(lsB1, 0); RD_B(lsB1, 1);
    G8_BAR(); G8_LGKM0(); MMA(0, 0); MMA(0, 1); G8_BAR();
    RD_A(lsA1, 1);
    G8_LGKM0(); MMA(1, 0); MMA(1, 1);
  }

  // epilogue: xi (n<2048) | z (n>=2048, at o16+8M)
  const int rq = (lane >> 4) * 4;
#pragma unroll
  for (int mi = 0; mi < 8; ++mi) {
#pragma unroll
    for (int ni = 0; ni < 4; ++ni) {
#pragma unroll
      for (int r = 0; r < 4; ++r) {
        int m = m0 + wm * 128 + mi * 16 + rq + r;
        int n = n0 + wn * 64 + ni * 16 + lrow;
        float v = acc[mi][ni][r];
        if (n < 2048) o16[(size_t)m * 2048 + n] = f2b(v);
        else          o16[(size_t)8388608 + (size_t)m * 2048 + (n - 2048)] = f2b(v);
      }
    }
  }
}

// ---------------------------------------------------------------------------
// 8-phase out_proj GEMM (verified R2): tile 128M x 256N, split-K=2,
// grid (4,32,2) = 256 blocks. LDS 96 KB dbuf.
// ---------------------------------------------------------------------------

#define ORD_A(base, MH) do { \
  _Pragma("unroll") \
  for (int mi_ = 0; mi_ < 2; ++mi_) { \
    af[mi_][0] = *(const bf8_t*)((base) + arow + ((MH) * 32 + mi_ * 16) * 64 + aq0); \
    af[mi_][1] = *(const bf8_t*)((base) + arow + ((MH) * 32 + mi_ * 16) * 64 + aq1); \
  } } while (0)

#define OMMA(MH, NH) do { \
  __builtin_amdgcn_s_setprio(1); \
  _Pragma("unroll") \
  for (int mi_ = 0; mi_ < 2; ++mi_) \
    _Pragma("unroll") \
    for (int ni_ = 0; ni_ < 2; ++ni_) { \
      acc[(MH) * 2 + mi_][(NH) * 2 + ni_] = __builtin_amdgcn_mfma_f32_16x16x32_bf16( \
          af[mi_][0], bfr[NH][ni_][0], acc[(MH) * 2 + mi_][(NH) * 2 + ni_], 0, 0, 0); \
      acc[(MH) * 2 + mi_][(NH) * 2 + ni_] = __builtin_amdgcn_mfma_f32_16x16x32_bf16( \
          af[mi_][1], bfr[NH][ni_][1], acc[(MH) * 2 + mi_][(NH) * 2 + ni_], 0, 0, 0); \
    } \
  __builtin_amdgcn_s_setprio(0); \
} while (0)

__global__ __launch_bounds__(512, 2)
void gemm8_out(const u16* __restrict__ A, const u16* __restrict__ Bt,
               float* __restrict__ of32, float* __restrict__ of32b)
{
  __shared__ u16 ls[49152];                       // 96 KB
  const int tid = threadIdx.x;
  const int wid = tid >> 6, lane = tid & 63;
  const int wm = wid >> 2, wn = wid & 3;          // 2Mx4N, 64x64 per wave
  const int lrow = lane & 15;
  const int kq = lane >> 4;
  const int sw = lrow & 7;
  const int m0 = blockIdx.y * 128;
  const int n0 = blockIdx.x * 256;
  const int kbase = blockIdx.z * 1024;
  u16* lsA0 = ls;                                 // 8192 u16 (128x64)
  u16* lsB0 = ls + 8192;                          // 16384 u16 (2 units)
  u16* lsA1 = ls + 24576;
  u16* lsB1 = ls + 32768;
  const int arow = (wm * 64 + lrow) * 64;
  const int brow = (wn >> 1) * 8192 + ((wn & 1) * 64 + lrow) * 64;
  const int aq0 = (kq ^ sw) * 8;
  const int aq1 = ((4 + kq) ^ sw) * 8;

  f4_t acc[4][4];
#pragma unroll
  for (int i = 0; i < 4; ++i)
#pragma unroll
    for (int j = 0; j < 4; ++j) acc[i][j] = {0.f, 0.f, 0.f, 0.f};
  bf8_t af[2][2];
  bf8_t bfr[2][2][2];

  // prologue: tile0 (A,B0,B1)->buf0, tile1 (B0,B1)->buf1; keep 4 in flight
  stageu(A,  2048, m0,        kbase,      lsA0,        wid, lane);
  stageu(Bt, 2048, n0,        kbase,      lsB0,        wid, lane);
  stageu(Bt, 2048, n0 + 128,  kbase,      lsB0 + 8192, wid, lane);
  stageu(Bt, 2048, n0,        kbase + 64, lsB1,        wid, lane);
  stageu(Bt, 2048, n0 + 128,  kbase + 64, lsB1 + 8192, wid, lane);
  G8_VM(4); G8_BAR();

#pragma unroll 1
  for (int i = 0; i < 7; ++i) {                   // tiles 0..13
    const int k1 = kbase + (2 * i + 1) * 64, k2 = k1 + 64, k3 = k1 + 128;
    // P1: stage A(t+1)->buf1
    ORD_A(lsA0, 0); RD_B(lsB0, 0);
    stageu(A, 2048, m0, k1, lsA1, wid, lane);
    G8_BAR(); G8_LGKM0(); OMMA(0, 0); G8_BAR();
    // P2
    RD_B(lsB0, 1);
    G8_BAR(); G8_LGKM0(); OMMA(0, 1); G8_BAR();
    // P3: stage B0(t+2)->buf0 (B(t) reads done end P2)
    ORD_A(lsA0, 1);
    stageu(Bt, 2048, n0, k2, lsB0, wid, lane);
    G8_BAR(); G8_LGKM0(); OMMA(1, 0); G8_BAR();
    // P4: stage B1(t+2)->buf0; vmcnt(4) -> A(t+1),B(t+1) landed
    stageu(Bt, 2048, n0 + 128, k2, lsB0 + 8192, wid, lane);
    G8_BAR(); G8_LGKM0(); OMMA(1, 1); G8_VM(4); G8_BAR();
    // P5: stage A(t+2)->buf0 (A(t) reads done end P3)
    ORD_A(lsA1, 0); RD_B(lsB1, 0);
    stageu(A, 2048, m0, k2, lsA0, wid, lane);
    G8_BAR(); G8_LGKM0(); OMMA(0, 0); G8_BAR();
    // P6
    RD_B(lsB1, 1);
    G8_BAR(); G8_LGKM0(); OMMA(0, 1); G8_BAR();
    // P7: stage B0(t+3)->buf1 (B(t+1) reads done end P6)
    ORD_A(lsA1, 1);
    stageu(Bt, 2048, n0, k3, lsB1, wid, lane);
    G8_BAR(); G8_LGKM0(); OMMA(1, 0); G8_BAR();
    // P8: stage B1(t+3)->buf1; vmcnt(4) -> tile t+2 landed
    stageu(Bt, 2048, n0 + 128, k3, lsB1 + 8192, wid, lane);
    G8_BAR(); G8_LGKM0(); OMMA(1, 1); G8_VM(4); G8_BAR();
  }

  {                                               // tiles 14,15
    const int k1 = kbase + 960;
    ORD_A(lsA0, 0); RD_B(lsB0, 0);
    stageu(A, 2048, m0, k1, lsA1, wid, lane);
    G8_BAR(); G8_LGKM0(); OMMA(0, 0); G8_BAR();
    RD_B(lsB0, 1);
    G8_BAR(); G8_LGKM0(); OMMA(0, 1); G8_BAR();
    ORD_A(lsA0, 1);
    G8_BAR(); G8_LGKM0(); OMMA(1, 0); G8_BAR();
    G8_BAR(); G8_LGKM0(); OMMA(1, 1); G8_VM(0); G8_BAR();
    ORD_A(lsA1, 0); RD_B(lsB1, 0);
    G8_BAR(); G8_LGKM0(); OMMA(0, 0); G8_BAR();
    RD_B(lsB1, 1);
    G8_BAR(); G8_LGKM0(); OMMA(0, 1); G8_BAR();
    ORD_A(lsA1, 1);
    G8_BAR(); G8_LGKM0(); OMMA(1, 0); G8_BAR();
    G8_LGKM0(); OMMA(1, 1);
  }

  float* dst = blockIdx.z ? of32b : of32;
  const int rq = (lane >> 4) * 4;
#pragma unroll
  for (int mi = 0; mi < 4; ++mi) {
#pragma unroll
    for (int ni = 0; ni < 4; ++ni) {
#pragma unroll
      for (int r = 0; r < 4; ++r) {
        int m = m0 + wm * 64 + mi * 16 + rq + r;
        int n = n0 + wn * 64 + ni * 16 + lrow;
        dst[(size_t)m * 1024 + n] = acc[mi][ni][r];
      }
    }
  }
}

// reduce 8 split-K partials of x_proj; emit dtA bf16 [4096,64] + bc f32 [4096,32]
__global__ __launch_bounds__(256)
void xproj_reduce(const float* __restrict__ part, u16* __restrict__ dtA,
                  float* __restrict__ bc)
{
  int idx = blockIdx.x * 256 + threadIdx.x;   // 4096*96
  int m = idx / 96, n = idx - m * 96;
  float s = 0.f;
#pragma unroll
  for (int p = 0; p < 8; ++p) s += part[(size_t)p * 393216 + idx];
  if (n < 64) dtA[(size_t)m * 64 + n] = f2b(s);
  else        bc[(size_t)m * 32 + (n - 64)] = s;
}

// causal depthwise conv1d (window 4) + bias + silu; vectorized 8 channels/thread
__global__ __launch_bounds__(256)
void conv_silu(const u16* __restrict__ xib, const float* __restrict__ cw,
               const float* __restrict__ cb, u16* __restrict__ ub)
{
  int i = blockIdx.x * 256 + threadIdx.x;     // 1,048,576 threads
  int c8 = (i & 255) * 8;
  int row = i >> 8;                           // b*2048 + l
  int l = row & 2047;
  const u16* base = xib + (size_t)row * 2048 + c8;
  u16x8 x0 = {0,0,0,0,0,0,0,0}, x1 = x0, x2 = x0, x3;
  x3 = *(const u16x8*)(base);
  if (l >= 1) x2 = *(const u16x8*)(base - 2048);
  if (l >= 2) x1 = *(const u16x8*)(base - 2 * 2048);
  if (l >= 3) x0 = *(const u16x8*)(base - 3 * 2048);
  f4_t cb0 = *(const f4_t*)(cb + c8);
  f4_t cb1 = *(const f4_t*)(cb + c8 + 4);
  u16x8 o;
#pragma unroll
  for (int j = 0; j < 8; ++j) {
    f4_t w = *(const f4_t*)(cw + (size_t)(c8 + j) * 4);
    float a = (j < 4 ? cb0[j] : cb1[j - 4])
            + w[0] * b2f(x0[j]) + w[1] * b2f(x1[j])
            + w[2] * b2f(x2[j]) + w[3] * b2f(x3[j]);
    float s = a / (1.f + __expf(-a));
    o[j] = f2b(s);
  }
  *(u16x8*)(ub + (size_t)row * 2048 + c8) = o;
}

// ---- chunk-parallel scan, d-in-lane layout. 32 chunks x 64 steps. ----
// (was 64x32; halving chunk count halves Q (16.8->8.4 MB) and S traffic
// across s1/comb/s3; s1/s3 still 512 blocks = 2/CU = 8 waves/CU.)
__global__ __launch_bounds__(256)
void scan_s1(const u16* __restrict__ delta_bf, const u16* __restrict__ ub,
             const float* __restrict__ bc, const float* __restrict__ alog,
             u16* __restrict__ S, float* __restrict__ Q)
{
  int blk = blockIdx.x;                // 512 blocks: b(1) x c(5) x g(3)
  int g = blk & 7, c = (blk >> 3) & 31, b = blk >> 8;
  int d = g * 256 + threadIdx.x;
  float Av[16];
#pragma unroll
  for (int nq = 0; nq < 4; ++nq) {
    f4_t al = *(const f4_t*)(alog + (size_t)d * 16 + nq * 4);
#pragma unroll
    for (int j = 0; j < 4; ++j) Av[nq * 4 + j] = -__expf(al[j]);
  }
  float Av0 = Av[0];
  bool st = true;
#pragma unroll
  for (int n = 1; n < 16; ++n)
    st = st && (fabsf(Av[n] - (float)(n + 1) * Av0) <= 1e-3f * (float)(n + 1));
  f4_t Qr[4];
#pragma unroll
  for (int nq = 0; nq < 4; ++nq) Qr[nq] = {0.f,0.f,0.f,0.f};
  float Sd = 0.f;
  int row0 = b * 2048 + c * 64;
  if (st) {
#pragma unroll 2
    for (int i = 0; i < 64; ++i) {
      size_t row = (size_t)(row0 + i);
      float dlt = b2f(delta_bf[row * 2048 + d]);
      float uv  = b2f(ub[row * 2048 + d]);
      const float* bp = bc + row * 32;
      f4_t Bv[4];
#pragma unroll
      for (int nq = 0; nq < 4; ++nq) Bv[nq] = *(const f4_t*)(bp + nq * 4);
      float du = dlt * uv;
      float e1 = __expf(dlt * Av0);
      float a = e1;
      Sd += dlt;
#pragma unroll
      for (int n = 0; n < 16; ++n) {
        Qr[n >> 2][n & 3] = a * Qr[n >> 2][n & 3] + du * Bv[n >> 2][n & 3];
        a *= e1;
      }
    }
  } else {
#pragma unroll 2
    for (int i = 0; i < 64; ++i) {
      size_t row = (size_t)(row0 + i);
      float dlt = b2f(delta_bf[row * 2048 + d]);
      float uv  = b2f(ub[row * 2048 + d]);
      const float* bp = bc + row * 32;
      f4_t Bv[4];
#pragma unroll
      for (int nq = 0; nq < 4; ++nq) Bv[nq] = *(const f4_t*)(bp + nq * 4);
      float du = dlt * uv;
      Sd += dlt;
#pragma unroll
      for (int n = 0; n < 16; ++n) {
        float a = __expf(dlt * Av[n]);
        Qr[n >> 2][n & 3] = a * Qr[n >> 2][n & 3] + du * Bv[n >> 2][n & 3];
      }
    }
  }
  S[(size_t)(b * 32 + c) * 2048 + d] = f2b(Sd);
  size_t o = ((size_t)((b * 32 + c) * 2048 + d)) * 16;
#pragma unroll
  for (int nq = 0; nq < 4; ++nq)
    *(f4_t*)(Q + o + nq * 4) = Qr[nq];
}

// S2: serial prefix over 32 chunks per (b,d,n)
__global__ __launch_bounds__(256)
void scan_comb(const u16* __restrict__ S16, float* __restrict__ Q,
               const float* __restrict__ alog)
{
  int idx = blockIdx.x * 256 + threadIdx.x;   // b*32768 + d*16+n
  int b = idx >> 15, dn = idx & 32767;
  int d = dn >> 4;
  float Av = -__expf(alog[dn]);
  size_t qbase = (size_t)b * 1048576 + dn;
  size_t sbase = (size_t)b * 65536 + d;
  float H = 0.f;
#pragma unroll
  for (int cg = 0; cg < 2; ++cg) {
    float sv[16], qv[16];
#pragma unroll
    for (int j = 0; j < 16; ++j) {
      int c = cg * 16 + j;
      qv[j] = Q[qbase + (size_t)c * 32768];
      sv[j] = b2f(S16[sbase + (size_t)c * 2048]);
    }
#pragma unroll
    for (int j = 0; j < 16; ++j) {
      int c = cg * 16 + j;
      Q[qbase + (size_t)c * 32768] = H;
      H = __expf(Av * sv[j]) * H + qv[j];
    }
  }
}

// S3: re-scan with correct h_in; fused D-skip + silu(z) gate; y overwrites z
__global__ __launch_bounds__(256)
void scan_s3(const u16* __restrict__ delta_bf, const u16* __restrict__ ub,
             const float* __restrict__ bc, const float* __restrict__ alog,
             const float* __restrict__ Q, const float* __restrict__ Dw,
             u16* __restrict__ zy)
{
  int blk = blockIdx.x;                // 512 blocks
  int g = blk & 7, c = (blk >> 3) & 31, b = blk >> 8;
  int d = g * 256 + threadIdx.x;
  float Av[16];
#pragma unroll
  for (int nq = 0; nq < 4; ++nq) {
    f4_t al = *(const f4_t*)(alog + (size_t)d * 16 + nq * 4);
#pragma unroll
    for (int j = 0; j < 4; ++j) Av[nq * 4 + j] = -__expf(al[j]);
  }
  float Av0 = Av[0];
  bool st = true;
#pragma unroll
  for (int n = 1; n < 16; ++n)
    st = st && (fabsf(Av[n] - (float)(n + 1) * Av0) <= 1e-3f * (float)(n + 1));
  f4_t h4[4];
  size_t o = ((size_t)((b * 32 + c) * 2048 + d)) * 16;
#pragma unroll
  for (int nq = 0; nq < 4; ++nq) h4[nq] = *(const f4_t*)(Q + o + nq * 4);
  float Dv = Dw[d];
  int row0 = b * 2048 + c * 64;
  if (st) {
#pragma unroll 2
    for (int i = 0; i < 64; ++i) {
      size_t row = (size_t)(row0 + i);
      float dlt = b2f(delta_bf[row * 2048 + d]);
      float uv  = b2f(ub[row * 2048 + d]);
      const float* bp = bc + row * 32;
      f4_t Bv[4], Cv[4];
#pragma unroll
      for (int nq = 0; nq < 4; ++nq) { Bv[nq] = *(const f4_t*)(bp + nq * 4); Cv[nq] = *(const f4_t*)(bp + 16 + nq * 4); }
      float du = dlt * uv;
      float e1 = __expf(dlt * Av0);
      float a = e1;
      float y = 0.f;
#pragma unroll
      for (int n = 0; n < 16; ++n) {
        float hn = a * h4[n >> 2][n & 3] + du * Bv[n >> 2][n & 3];
        h4[n >> 2][n & 3] = hn;
        y += hn * Cv[n >> 2][n & 3];
        a *= e1;
      }
      float zv = b2f(zy[row * 2048 + d]);
      float ov = (y + Dv * uv) * (zv / (1.f + __expf(-zv)));
      zy[row * 2048 + d] = f2b(ov);
    }
  } else {
#pragma unroll 2
    for (int i = 0; i < 64; ++i) {
      size_t row = (size_t)(row0 + i);
      float dlt = b2f(delta_bf[row * 2048 + d]);
      float uv  = b2f(ub[row * 2048 + d]);
      const float* bp = bc + row * 32;
      f4_t Bv[4], Cv[4];
#pragma unroll
      for (int nq = 0; nq < 4; ++nq) { Bv[nq] = *(const f4_t*)(bp + nq * 4); Cv[nq] = *(const f4_t*)(bp + 16 + nq * 4); }
      float du = dlt * uv;
      float y = 0.f;
#pragma unroll
      for (int n = 0; n < 16; ++n) {
        float a = __expf(dlt * Av[n]);
        float hn = a * h4[n >> 2][n & 3] + du * Bv[n >> 2][n & 3];
        h4[n >> 2][n & 3] = hn;
        y += hn * Cv[n >> 2][n & 3];
      }
      float zv = b2f(zy[row * 2048 + d]);
      float ov = (y + Dv * uv) * (zv / (1.f + __expf(-zv)));
      zy[row * 2048 + d] = f2b(ov);
    }
  }
}

// residual + LayerNorm over two out_proj partials, f32 in/out.
__global__ __launch_bounds__(256)
void ln_kernel(const float* __restrict__ hp0, const float* __restrict__ hp1,
               const float* __restrict__ xin,
               const float* __restrict__ lnw, const float* __restrict__ lnb,
               float* __restrict__ outp)
{
  __shared__ float ssum[4], ssq[4];
  int row = blockIdx.x, t = threadIdx.x;
  f4_t h0 = *(const f4_t*)(hp0 + (size_t)row * 1024 + t * 4);
  f4_t h1 = *(const f4_t*)(hp1 + (size_t)row * 1024 + t * 4);
  f4_t xv = *(const f4_t*)(xin + (size_t)row * 1024 + t * 4);
  float v[4], s = 0.f, q = 0.f;
#pragma unroll
  for (int j = 0; j < 4; ++j) { v[j] = h0[j] + h1[j] + xv[j]; s += v[j]; q += v[j] * v[j]; }
#pragma unroll
  for (int m = 32; m; m >>= 1) { s += __shfl_xor(s, m, 64); q += __shfl_xor(q, m, 64); }
  int wv = t >> 6;
  if ((t & 63) == 0) { ssum[wv] = s; ssq[wv] = q; }
  __syncthreads();
  s = ssum[0] + ssum[1] + ssum[2] + ssum[3];
  q = ssq[0] + ssq[1] + ssq[2] + ssq[3];
  float mu = s * (1.f / 1024.f);
  float var = q * (1.f / 1024.f) - mu * mu;
  float rs = rsqrtf(var + 1e-5f);
  f4_t o;
#pragma unroll
  for (int j = 0; j < 4; ++j)
    o[j] = (v[j] - mu) * rs * lnw[t * 4 + j] + lnb[t * 4 + j];
  *(f4_t*)(outp + (size_t)row * 1024 + t * 4) = o;
}

extern "C" void kernel_launch(void* const* d_in, const int* in_sizes, int n_in,
                              void* d_out, int out_size, void* d_ws, size_t ws_size,
                              hipStream_t stream)
{
  const float* x      = (const float*)d_in[0];   // [2,2048,1024]
  const float* inW    = (const float*)d_in[1];   // [4096,1024]
  const float* convW  = (const float*)d_in[2];   // [2048,1,4]
  const float* convB  = (const float*)d_in[3];   // [2048]
  const float* xprojW = (const float*)d_in[4];   // [96,2048]
  const float* dtW    = (const float*)d_in[5];   // [2048,64]
  const float* dtB    = (const float*)d_in[6];   // [2048]
  const float* alog   = (const float*)d_in[7];   // [2048,16]
  const float* Dw     = (const float*)d_in[8];   // [2048]
  const float* outW   = (const float*)d_in[9];   // [1024,2048]
  const float* lnw    = (const float*)d_in[10];  // [1024]
  const float* lnb    = (const float*)d_in[11];  // [1024]
  float* out = (float*)d_out;                    // [2,2048,1024] f32 (16 MiB)

  char* ws = (char*)d_ws;
  u16*   xiz    = (u16*)(ws);
  u16*   zy     = xiz + 8388608;
  u16*   xb     = (u16*)(ws + 33554432);
  u16*   inWb   = xb + 4194304;
  u16*   u_bf   = (u16*)(ws + 33554432);          // overwrites xb/inWb after gemm8_in
  u16*   dtA    = (u16*)(ws + 50331648);
  float* bc     = (float*)(ws + 50855936);
  u16*   xprojWb= (u16*)(ws + 51380224);
  u16*   dtWb   = (u16*)(ws + 51773440);
  u16*   outWb  = (u16*)(ws + 52035584);
  u16*   delta  = xiz;                            // overwrites dead xi
  float* hpart1 = (float*)(ws);                   // out_proj partial1 (delta dead)
  float* hpart0 = (float*)d_out;                  // out_proj partial0
  float* xpart  = (float*)d_out;                  // x_proj partials [8][4096][96]
  u16*   Sbuf   = dtA;                            // S (dtA dead after gemm_dt; 256 KB)
  float* Qbuf   = (float*)d_out;                  // Q [2,32,2048,16] f32 = 8.39 MB

  dim3 blk(256);
  // fused f32 -> bf16 conversions (one launch)
  cvt_all<<<10560, blk, 0, stream>>>(x, inW, xprojW, dtW, outW,
                                     xb, inWb, xprojWb, dtWb, outWb);
  // in_proj: [4096,1024] x [4096,1024]^T -> xi | z (bf16); 4-phase 256^2
  gemm8_in<<<dim3(16, 16), dim3(512), 0, stream>>>(xb, inWb, xiz);
  // depthwise causal conv + silu -> u (bf16; overwrites xb/inWb)
  conv_silu<<<4096, blk, 0, stream>>>(xiz, convW, convB, u_bf);
  // x_proj split-K (8 x 256): partials into d_out
  gemm_xp<<<dim3(8, 32), blk, 0, stream>>>(u_bf, 2048, xprojWb, 2048, 256, 96, nullptr, xpart, nullptr, nullptr);
  xproj_reduce<<<1536, blk, 0, stream>>>(xpart, dtA, bc);
  // dt_proj + softplus -> delta (bf16, overwrites xi)
  gemm_dt<<<dim3(16, 32), blk, 0, stream>>>(dtA, 64, dtWb, 64, 64, 2048, delta, nullptr, nullptr, dtB);
  // chunk-parallel scan (32 chunks x 64 steps): S1 -> combine -> S3
  scan_s1<<<512, blk, 0, stream>>>(delta, u_bf, bc, alog, Sbuf, Qbuf);
  scan_comb<<<256, blk, 0, stream>>>(Sbuf, Qbuf, alog);
  scan_s3<<<512, blk, 0, stream>>>(delta, u_bf, bc, alog, Qbuf, Dw, zy);
  // out_proj 8-phase split-K (2): partial0 -> d_out, partial1 -> ws[0,16M)
  gemm8_out<<<dim3(4, 32, 2), dim3(512), 0, stream>>>(zy, outWb, hpart0, hpart1);
  // residual + LayerNorm (sums both partials) -> f32 out (in place over partial0)
  ln_kernel<<<4096, blk, 0, stream>>>(hpart0, hpart1, x, lnw, lnb, out);
}

// Round 4
// 316.598 us; speedup vs baseline: 1.0003x; 1.0003x over previous
//
#include <hip/hip_runtime.h>

typedef unsigned short u16;
typedef __attribute__((ext_vector_type(8))) short bf8_t;    // 8 x bf16 (4 VGPRs)
typedef __attribute__((ext_vector_type(4))) float f4_t;     // 4 x f32
typedef __attribute__((ext_vector_type(4))) unsigned short u16x4;
typedef __attribute__((ext_vector_type(8))) unsigned short u16x8;

__device__ __forceinline__ float b2f(u16 h) {
  union { unsigned u; float f; } v; v.u = ((unsigned)h) << 16; return v.f;
}
__device__ __forceinline__ u16 f2b(float f) {
  union { float f; unsigned u; } v; v.f = f;
  unsigned u = v.u;
  u += 0x7fffu + ((u >> 16) & 1u);   // round-nearest-even
  return (u16)(u >> 16);
}

#define AS1C(p) ((const __attribute__((address_space(1))) void*)(p))
#define AS3(p)  ((__attribute__((address_space(3))) void*)(p))

// one fused f32 -> bf16 convert over all 5 weight/input arrays
__global__ __launch_bounds__(256)
void cvt_all(const float* __restrict__ x, const float* __restrict__ inW,
             const float* __restrict__ xprojW, const float* __restrict__ dtW,
             const float* __restrict__ outW,
             u16* __restrict__ xb, u16* __restrict__ inWb, u16* __restrict__ xpb,
             u16* __restrict__ dtWb, u16* __restrict__ outWb)
{
  int i = blockIdx.x * 256 + threadIdx.x;      // float4 index, total 2703360
  if (i >= 2703360) return;
  const float* s; u16* d; int off;
  if (i < 1048576)      { s = x;      d = xb;    off = i; }
  else if (i < 2097152) { s = inW;    d = inWb;  off = i - 1048576; }
  else if (i < 2146304) { s = xprojW; d = xpb;   off = i - 2097152; }
  else if (i < 2179072) { s = dtW;    d = dtWb;  off = i - 2146304; }
  else                  { s = outW;   d = outWb; off = i - 2179072; }
  f4_t v = *(const f4_t*)(s + (size_t)off * 4);
  u16x4 o;
#pragma unroll
  for (int j = 0; j < 4; ++j) o[j] = f2b(v[j]);
  *(u16x4*)(d + (size_t)off * 4) = o;
}

// Stage one 128x64 bf16 tile (16 KB) into LDS, XOR-swizzled: granule (r,q)
// holds global colchunk q^(r&7). Staging lane i (chunk of 8 rows) fetches
// colchunk (i&7)^((i>>3)&7); reader uses granule (g ^ (row&7)). Bank-quad
// depends only on q_l -> 8 lanes per 4-bank group = 2/bank = conflict-free.
__device__ __forceinline__ void stage64(const u16* g, int ld, int row0, int rowmax,
                                        int k0, u16* lds, int wid, int lane) {
  int qg = (lane & 7) ^ ((lane >> 3) & 7);
#pragma unroll
  for (int c = 0; c < 4; ++c) {
    int chunk = wid * 4 + c;
    int r = row0 + chunk * 8 + (lane >> 3);
    if (r > rowmax) r = rowmax;                       // clamp (results discarded later)
    const u16* gp = g + (size_t)r * ld + k0 + qg * 8;
    __builtin_amdgcn_global_load_lds(AS1C(gp), AS3(lds + chunk * 512), 16, 0, 0);
  }
}

// C = A * Bt^T : A[M,K] bf16 row-major (lda), Bt[N,K] bf16 row-major (ldb).
// BK=64 (two 32-k half-steps per barrier epoch).
// EPI 1: x_proj   -> split-K partials: of32[(bx*4096+m)*96+n], n<96
// EPI 2: dt_proj  -> o16[m*2048+n] = bf16(softplus(acc + biasf[n]))
template<int EPI>
__device__ __forceinline__ void gemm_body(const u16* __restrict__ A, int lda,
             const u16* __restrict__ Bt, int ldb,
             int Kblk, int Nact,
             u16* __restrict__ o16, float* __restrict__ of32,
             float* __restrict__ of32b, const float* __restrict__ biasf)
{
  __shared__ u16 lsA[128 * 64];
  __shared__ u16 lsB[128 * 64];
  const int tid = threadIdx.x;
  const int wid = tid >> 6, lane = tid & 63;
  const int wm = wid >> 1, wn = wid & 1;          // 2x2 wave grid, 64x64 each
  const int lrow = lane & 15;
  const int kq = lane >> 4;                       // 0..3
  const int sw = lrow & 7;                        // swizzle key
  const int m0 = blockIdx.y * 128;
  const int n0 = (EPI == 1) ? 0 : blockIdx.x * 128;
  int kbase = 0;
  if (EPI == 1) kbase = blockIdx.x * Kblk;

  f4_t acc[4][4];
#pragma unroll
  for (int i = 0; i < 4; ++i)
#pragma unroll
    for (int j = 0; j < 4; ++j) acc[i][j] = {0.f, 0.f, 0.f, 0.f};

  for (int kt = kbase; kt < kbase + Kblk; kt += 64) {
    stage64(A,  lda, m0, 0x3fffffff, kt, lsA, wid, lane);
    stage64(Bt, ldb, n0, Nact - 1,   kt, lsB, wid, lane);
    __syncthreads();
#pragma unroll
    for (int h = 0; h < 2; ++h) {
      const int lk = ((h * 4 + kq) ^ sw) * 8;
      bf8_t af[4], bfr[4];
#pragma unroll
      for (int mi = 0; mi < 4; ++mi)
        af[mi] = *(const bf8_t*)&lsA[(wm * 64 + mi * 16 + lrow) * 64 + lk];
#pragma unroll
      for (int ni = 0; ni < 4; ++ni)
        bfr[ni] = *(const bf8_t*)&lsB[(wn * 64 + ni * 16 + lrow) * 64 + lk];
#pragma unroll
      for (int mi = 0; mi < 4; ++mi)
#pragma unroll
        for (int ni = 0; ni < 4; ++ni)
          acc[mi][ni] = __builtin_amdgcn_mfma_f32_16x16x32_bf16(af[mi], bfr[ni], acc[mi][ni], 0, 0, 0);
    }
    __syncthreads();
  }

  const int rq = (lane >> 4) * 4;                  // C/D: row=(lane>>4)*4+r, col=lane&15
#pragma unroll
  for (int mi = 0; mi < 4; ++mi) {
#pragma unroll
    for (int ni = 0; ni < 4; ++ni) {
#pragma unroll
      for (int r = 0; r < 4; ++r) {
        int m = m0 + wm * 64 + mi * 16 + rq + r;
        int n = n0 + wn * 64 + ni * 16 + lrow;
        float v = acc[mi][ni][r];
        if (EPI == 1) {
          if (n < 96) of32[((size_t)blockIdx.x * 4096 + m) * 96 + n] = v;
        } else if (EPI == 2) {
          float t = v + biasf[n];
          float sp = (t > 20.f) ? t : log1pf(__expf(t));
          o16[(size_t)m * 2048 + n] = f2b(sp);
        }
      }
    }
  }
}

__global__ __launch_bounds__(256)
void gemm_xp(const u16* A, int lda, const u16* Bt, int ldb, int Kblk, int Nact,
             u16* o16, float* of32, float* of32b, const float* biasf)
{ gemm_body<1>(A, lda, Bt, ldb, Kblk, Nact, o16, of32, of32b, biasf); }

__global__ __launch_bounds__(256)
void gemm_dt(const u16* A, int lda, const u16* Bt, int ldb, int Kblk, int Nact,
             u16* o16, float* of32, float* of32b, const float* biasf)
{ gemm_body<2>(A, lda, Bt, ldb, Kblk, Nact, o16, of32, of32b, biasf); }

// ---------------------------------------------------------------------------
// 4-phase 256x256 bf16 GEMM for in_proj (M=N=4096, K=1024), with:
//  - af2 fragment prefetch: Q2/Q4's A-half1 ds_reads issue in Q1/Q3 and drain
//    under Q1/Q3's MFMA cluster -> Q2/Q4 start MFMA with lgkm already clear.
//    Issue order pinned by sched_barrier(0) between read groups so the
//    lgkmcnt(8) in Q1/Q3 provably waits on the 16 own-phase reads only.
//  - XCD-chunked block swizzle (bijective, 256 blocks = 32/XCD as 4y x 8x
//    rectangles): per-XCD L2 stage working set 9 MB -> 6 MB.
// vmcnt invariant unchanged from R3 (4 loads in flight across each VM(4)).
// ---------------------------------------------------------------------------

// stage one 128x64 unit: 512 threads x 2 x 16B gload_lds. granule g = j*512 +
// wid*64 + lane -> lds row g>>3, slot g&7, global colchunk (g&7)^((g>>3)&7).
__device__ __forceinline__ void stageu(const u16* __restrict__ g, int ld,
                                       int row0, int k0, u16* ldsu,
                                       int wid, int lane) {
  int qg = (lane & 7) ^ ((lane >> 3) & 7);
#pragma unroll
  for (int j = 0; j < 2; ++j) {
    int rr = j * 64 + wid * 8 + (lane >> 3);
    const u16* gp = g + (size_t)(row0 + rr) * ld + k0 + qg * 8;
    __builtin_amdgcn_global_load_lds(AS1C(gp), AS3(ldsu + (j * 512 + wid * 64) * 8), 16, 0, 0);
  }
}

#define G8_BAR()   __builtin_amdgcn_s_barrier()
#define G8_SB()    __builtin_amdgcn_sched_barrier(0)
#define G8_LGKM0() do { asm volatile("s_waitcnt lgkmcnt(0)" ::: "memory"); \
                        __builtin_amdgcn_sched_barrier(0); } while (0)
#define G8_LGKM8() do { asm volatile("s_waitcnt lgkmcnt(8)" ::: "memory"); \
                        __builtin_amdgcn_sched_barrier(0); } while (0)
#define G8_VM(N)   do { asm volatile("s_waitcnt vmcnt(" #N ")" ::: "memory"); \
                        __builtin_amdgcn_sched_barrier(0); } while (0)

#define RD_A(base, MH) do { \
  _Pragma("unroll") \
  for (int mi_ = 0; mi_ < 4; ++mi_) { \
    af[mi_][0] = *(const bf8_t*)((base) + arow + ((MH) * 64 + mi_ * 16) * 64 + aq0); \
    af[mi_][1] = *(const bf8_t*)((base) + arow + ((MH) * 64 + mi_ * 16) * 64 + aq1); \
  } } while (0)

#define RD_A2(base) do { \
  _Pragma("unroll") \
  for (int mi_ = 0; mi_ < 4; ++mi_) { \
    af2[mi_][0] = *(const bf8_t*)((base) + arow + (64 + mi_ * 16) * 64 + aq0); \
    af2[mi_][1] = *(const bf8_t*)((base) + arow + (64 + mi_ * 16) * 64 + aq1); \
  } } while (0)

#define RD_B(base, NH) do { \
  _Pragma("unroll") \
  for (int ni_ = 0; ni_ < 2; ++ni_) { \
    bfr[NH][ni_][0] = *(const bf8_t*)((base) + brow + ((NH) * 32 + ni_ * 16) * 64 + aq0); \
    bfr[NH][ni_][1] = *(const bf8_t*)((base) + brow + ((NH) * 32 + ni_ * 16) * 64 + aq1); \
  } } while (0)

#define MMA(MH, NH) do { \
  __builtin_amdgcn_s_setprio(1); \
  _Pragma("unroll") \
  for (int mi_ = 0; mi_ < 4; ++mi_) \
    _Pragma("unroll") \
    for (int ni_ = 0; ni_ < 2; ++ni_) { \
      acc[(MH) * 4 + mi_][(NH) * 2 + ni_] = __builtin_amdgcn_mfma_f32_16x16x32_bf16( \
          af[mi_][0], bfr[NH][ni_][0], acc[(MH) * 4 + mi_][(NH) * 2 + ni_], 0, 0, 0); \
      acc[(MH) * 4 + mi_][(NH) * 2 + ni_] = __builtin_amdgcn_mfma_f32_16x16x32_bf16( \
          af[mi_][1], bfr[NH][ni_][1], acc[(MH) * 4 + mi_][(NH) * 2 + ni_], 0, 0, 0); \
    } \
  __builtin_amdgcn_s_setprio(0); \
} while (0)

// same as MMA but A operands come from the prefetched af2 bank (MH==1 rows)
#define MMA2(NH) do { \
  __builtin_amdgcn_s_setprio(1); \
  _Pragma("unroll") \
  for (int mi_ = 0; mi_ < 4; ++mi_) \
    _Pragma("unroll") \
    for (int ni_ = 0; ni_ < 2; ++ni_) { \
      acc[4 + mi_][(NH) * 2 + ni_] = __builtin_amdgcn_mfma_f32_16x16x32_bf16( \
          af2[mi_][0], bfr[NH][ni_][0], acc[4 + mi_][(NH) * 2 + ni_], 0, 0, 0); \
      acc[4 + mi_][(NH) * 2 + ni_] = __builtin_amdgcn_mfma_f32_16x16x32_bf16( \
          af2[mi_][1], bfr[NH][ni_][1], acc[4 + mi_][(NH) * 2 + ni_], 0, 0, 0); \
    } \
  __builtin_amdgcn_s_setprio(0); \
} while (0)

__global__ __launch_bounds__(512, 2)
void gemm8_in(const u16* __restrict__ A, const u16* __restrict__ Bt,
              u16* __restrict__ o16)
{
  __shared__ u16 ls[65536];                       // 128 KB: 2 buf x (A 32K + B 32K)
  const int tid = threadIdx.x;
  const int wid = tid >> 6, lane = tid & 63;
  const int wm = wid >> 2, wn = wid & 3;          // 2x4 wave grid, 128x64 per wave
  const int lrow = lane & 15;
  const int kq = lane >> 4;
  const int sw = lrow & 7;
  // XCD-chunked swizzle: linear id -> (xcd = id%8, idx = id/8); each XCD gets
  // a 4(y) x 8(x) rectangle of tiles. Bijective since 256 % 8 == 0.
  const int id  = blockIdx.y * 16 + blockIdx.x;
  const int xcd = id & 7, idx = id >> 3;
  const int m0 = ((xcd >> 1) * 4 + (idx >> 3)) * 256;
  const int n0 = ((xcd & 1) * 8 + (idx & 7)) * 256;
  u16* lsA0 = ls;
  u16* lsB0 = ls + 16384;
  u16* lsA1 = ls + 32768;
  u16* lsB1 = ls + 49152;
  const int arow = (wm * 128 + lrow) * 64;
  const int brow = (wn * 64 + lrow) * 64;
  const int aq0 = (kq ^ sw) * 8;
  const int aq1 = ((4 + kq) ^ sw) * 8;

  f4_t acc[8][4];
#pragma unroll
  for (int i = 0; i < 8; ++i)
#pragma unroll
    for (int j = 0; j < 4; ++j) acc[i][j] = {0.f, 0.f, 0.f, 0.f};
  bf8_t af[4][2];
  bf8_t af2[4][2];
  bf8_t bfr[2][2][2];

  // prologue: tile0 (A0,A1,B0,B1)->buf0, tile1 (B0,B1)->buf1; keep 4 in flight
  stageu(A,  1024, m0,        0, lsA0,        wid, lane);
  stageu(A,  1024, m0 + 128,  0, lsA0 + 8192, wid, lane);
  stageu(Bt, 1024, n0,        0, lsB0,        wid, lane);
  stageu(Bt, 1024, n0 + 128,  0, lsB0 + 8192, wid, lane);
  stageu(Bt, 1024, n0,       64, lsB1,        wid, lane);
  stageu(Bt, 1024, n0 + 128, 64, lsB1 + 8192, wid, lane);
  G8_VM(4); G8_BAR();

#pragma unroll 1
  for (int i = 0; i < 7; ++i) {                   // iterations 0..6 (tiles 0..13)
    const int ka1 = (2 * i + 1) * 64;             // A of tile 2i+1
    const int k2  = ka1 + 64;                     // tile 2i+2
    const int kb3 = ka1 + 128;                    // B of tile 2i+3
    // Q1: read buf0 {A-h0, B both} (16) + PREFETCH af2 <- buf0.A-h1 (8);
    //     stage A(t+1)->buf1. lgkmcnt(8) drains the 16, leaves af2 in flight.
    RD_A(lsA0, 0); RD_B(lsB0, 0); RD_B(lsB0, 1);
    G8_SB();
    RD_A2(lsA0);
    stageu(A, 1024, m0,       ka1, lsA1,        wid, lane);
    stageu(A, 1024, m0 + 128, ka1, lsA1 + 8192, wid, lane);
    G8_BAR(); G8_LGKM8(); MMA(0, 0); MMA(0, 1); G8_BAR();
    // Q2: af2 drained during Q1 MFMA; stage B(t+2)->buf0 (buf0.B sealed Q1)
    stageu(Bt, 1024, n0,       k2, lsB0,        wid, lane);
    stageu(Bt, 1024, n0 + 128, k2, lsB0 + 8192, wid, lane);
    G8_LGKM0(); MMA2(0); MMA2(1); G8_VM(4); G8_BAR();
    // Q3: read buf1 {A-h0, B both} + prefetch af2 <- buf1.A-h1;
    //     stage A(t+2)->buf0 (buf0.A sealed end Q2 via af2 drain)
    RD_A(lsA1, 0); RD_B(lsB1, 0); RD_B(lsB1, 1);
    G8_SB();
    RD_A2(lsA1);
    stageu(A, 1024, m0,       k2, lsA0,        wid, lane);
    stageu(A, 1024, m0 + 128, k2, lsA0 + 8192, wid, lane);
    G8_BAR(); G8_LGKM8(); MMA(0, 0); MMA(0, 1); G8_BAR();
    // Q4: stage B(t+3)->buf1 (buf1.B sealed end Q3)
    stageu(Bt, 1024, n0,       kb3, lsB1,        wid, lane);
    stageu(Bt, 1024, n0 + 128, kb3, lsB1 + 8192, wid, lane);
    G8_LGKM0(); MMA2(0); MMA2(1); G8_VM(4); G8_BAR();
  }

  {                                               // last iteration: tiles 14,15
    const int ka1 = 960;
    RD_A(lsA0, 0); RD_B(lsB0, 0); RD_B(lsB0, 1);
    G8_SB();
    RD_A2(lsA0);
    stageu(A, 1024, m0,       ka1, lsA1,        wid, lane);
    stageu(A, 1024, m0 + 128, ka1, lsA1 + 8192, wid, lane);
    G8_BAR(); G8_LGKM8(); MMA(0, 0); MMA(0, 1); G8_BAR();
    G8_LGKM0(); MMA2(0); MMA2(1); G8_VM(0); G8_BAR();
    RD_A(lsA1, 0); RD_B(lsB1, 0); RD_B(lsB1, 1);
    G8_SB();
    RD_A2(lsA1);
    G8_BAR(); G8_LGKM8(); MMA(0, 0); MMA(0, 1); G8_BAR();
    G8_LGKM0(); MMA2(0); MMA2(1);
  }

  // epilogue: xi (n<2048) | z (n>=2048, at o16+8M)
  const int rq = (lane >> 4) * 4;
#pragma unroll
  for (int mi = 0; mi < 8; ++mi) {
#pragma unroll
    for (int ni = 0; ni < 4; ++ni) {
#pragma unroll
      for (int r = 0; r < 4; ++r) {
        int m = m0 + wm * 128 + mi * 16 + rq + r;
        int n = n0 + wn * 64 + ni * 16 + lrow;
        float v = acc[mi][ni][r];
        if (n < 2048) o16[(size_t)m * 2048 + n] = f2b(v);
        else          o16[(size_t)8388608 + (size_t)m * 2048 + (n - 2048)] = f2b(v);
      }
    }
  }
}

// ---------------------------------------------------------------------------
// 8-phase out_proj GEMM (verified R2): tile 128M x 256N, split-K=2,
// grid (4,32,2) = 256 blocks. LDS 96 KB dbuf.
// ---------------------------------------------------------------------------

#define ORD_A(base, MH) do { \
  _Pragma("unroll") \
  for (int mi_ = 0; mi_ < 2; ++mi_) { \
    af[mi_][0] = *(const bf8_t*)((base) + arow + ((MH) * 32 + mi_ * 16) * 64 + aq0); \
    af[mi_][1] = *(const bf8_t*)((base) + arow + ((MH) * 32 + mi_ * 16) * 64 + aq1); \
  } } while (0)

#define OMMA(MH, NH) do { \
  __builtin_amdgcn_s_setprio(1); \
  _Pragma("unroll") \
  for (int mi_ = 0; mi_ < 2; ++mi_) \
    _Pragma("unroll") \
    for (int ni_ = 0; ni_ < 2; ++ni_) { \
      acc[(MH) * 2 + mi_][(NH) * 2 + ni_] = __builtin_amdgcn_mfma_f32_16x16x32_bf16( \
          af[mi_][0], bfr[NH][ni_][0], acc[(MH) * 2 + mi_][(NH) * 2 + ni_], 0, 0, 0); \
      acc[(MH) * 2 + mi_][(NH) * 2 + ni_] = __builtin_amdgcn_mfma_f32_16x16x32_bf16( \
          af[mi_][1], bfr[NH][ni_][1], acc[(MH) * 2 + mi_][(NH) * 2 + ni_], 0, 0, 0); \
    } \
  __builtin_amdgcn_s_setprio(0); \
} while (0)

__global__ __launch_bounds__(512, 2)
void gemm8_out(const u16* __restrict__ A, const u16* __restrict__ Bt,
               float* __restrict__ of32, float* __restrict__ of32b)
{
  __shared__ u16 ls[49152];                       // 96 KB
  const int tid = threadIdx.x;
  const int wid = tid >> 6, lane = tid & 63;
  const int wm = wid >> 2, wn = wid & 3;          // 2Mx4N, 64x64 per wave
  const int lrow = lane & 15;
  const int kq = lane >> 4;
  const int sw = lrow & 7;
  const int m0 = blockIdx.y * 128;
  const int n0 = blockIdx.x * 256;
  const int kbase = blockIdx.z * 1024;
  u16* lsA0 = ls;                                 // 8192 u16 (128x64)
  u16* lsB0 = ls + 8192;                          // 16384 u16 (2 units)
  u16* lsA1 = ls + 24576;
  u16* lsB1 = ls + 32768;
  const int arow = (wm * 64 + lrow) * 64;
  const int brow = (wn >> 1) * 8192 + ((wn & 1) * 64 + lrow) * 64;
  const int aq0 = (kq ^ sw) * 8;
  const int aq1 = ((4 + kq) ^ sw) * 8;

  f4_t acc[4][4];
#pragma unroll
  for (int i = 0; i < 4; ++i)
#pragma unroll
    for (int j = 0; j < 4; ++j) acc[i][j] = {0.f, 0.f, 0.f, 0.f};
  bf8_t af[2][2];
  bf8_t bfr[2][2][2];

  // prologue: tile0 (A,B0,B1)->buf0, tile1 (B0,B1)->buf1; keep 4 in flight
  stageu(A,  2048, m0,        kbase,      lsA0,        wid, lane);
  stageu(Bt, 2048, n0,        kbase,      lsB0,        wid, lane);
  stageu(Bt, 2048, n0 + 128,  kbase,      lsB0 + 8192, wid, lane);
  stageu(Bt, 2048, n0,        kbase + 64, lsB1,        wid, lane);
  stageu(Bt, 2048, n0 + 128,  kbase + 64, lsB1 + 8192, wid, lane);
  G8_VM(4); G8_BAR();

#pragma unroll 1
  for (int i = 0; i < 7; ++i) {                   // tiles 0..13
    const int k1 = kbase + (2 * i + 1) * 64, k2 = k1 + 64, k3 = k1 + 128;
    // P1: stage A(t+1)->buf1
    ORD_A(lsA0, 0); RD_B(lsB0, 0);
    stageu(A, 2048, m0, k1, lsA1, wid, lane);
    G8_BAR(); G8_LGKM0(); OMMA(0, 0); G8_BAR();
    // P2
    RD_B(lsB0, 1);
    G8_BAR(); G8_LGKM0(); OMMA(0, 1); G8_BAR();
    // P3: stage B0(t+2)->buf0 (B(t) reads done end P2)
    ORD_A(lsA0, 1);
    stageu(Bt, 2048, n0, k2, lsB0, wid, lane);
    G8_BAR(); G8_LGKM0(); OMMA(1, 0); G8_BAR();
    // P4: stage B1(t+2)->buf0; vmcnt(4) -> A(t+1),B(t+1) landed
    stageu(Bt, 2048, n0 + 128, k2, lsB0 + 8192, wid, lane);
    G8_BAR(); G8_LGKM0(); OMMA(1, 1); G8_VM(4); G8_BAR();
    // P5: stage A(t+2)->buf0 (A(t) reads done end P3)
    ORD_A(lsA1, 0); RD_B(lsB1, 0);
    stageu(A, 2048, m0, k2, lsA0, wid, lane);
    G8_BAR(); G8_LGKM0(); OMMA(0, 0); G8_BAR();
    // P6
    RD_B(lsB1, 1);
    G8_BAR(); G8_LGKM0(); OMMA(0, 1); G8_BAR();
    // P7: stage B0(t+3)->buf1 (B(t+1) reads done end P6)
    ORD_A(lsA1, 1);
    stageu(Bt, 2048, n0, k3, lsB1, wid, lane);
    G8_BAR(); G8_LGKM0(); OMMA(1, 0); G8_BAR();
    // P8: stage B1(t+3)->buf1; vmcnt(4) -> tile t+2 landed
    stageu(Bt, 2048, n0 + 128, k3, lsB1 + 8192, wid, lane);
    G8_BAR(); G8_LGKM0(); OMMA(1, 1); G8_VM(4); G8_BAR();
  }

  {                                               // tiles 14,15
    const int k1 = kbase + 960;
    ORD_A(lsA0, 0); RD_B(lsB0, 0);
    stageu(A, 2048, m0, k1, lsA1, wid, lane);
    G8_BAR(); G8_LGKM0(); OMMA(0, 0); G8_BAR();
    RD_B(lsB0, 1);
    G8_BAR(); G8_LGKM0(); OMMA(0, 1); G8_BAR();
    ORD_A(lsA0, 1);
    G8_BAR(); G8_LGKM0(); OMMA(1, 0); G8_BAR();
    G8_BAR(); G8_LGKM0(); OMMA(1, 1); G8_VM(0); G8_BAR();
    ORD_A(lsA1, 0); RD_B(lsB1, 0);
    G8_BAR(); G8_LGKM0(); OMMA(0, 0); G8_BAR();
    RD_B(lsB1, 1);
    G8_BAR(); G8_LGKM0(); OMMA(0, 1); G8_BAR();
    ORD_A(lsA1, 1);
    G8_BAR(); G8_LGKM0(); OMMA(1, 0); G8_BAR();
    G8_LGKM0(); OMMA(1, 1);
  }

  float* dst = blockIdx.z ? of32b : of32;
  const int rq = (lane >> 4) * 4;
#pragma unroll
  for (int mi = 0; mi < 4; ++mi) {
#pragma unroll
    for (int ni = 0; ni < 4; ++ni) {
#pragma unroll
      for (int r = 0; r < 4; ++r) {
        int m = m0 + wm * 64 + mi * 16 + rq + r;
        int n = n0 + wn * 64 + ni * 16 + lrow;
        dst[(size_t)m * 1024 + n] = acc[mi][ni][r];
      }
    }
  }
}

// reduce 8 split-K partials of x_proj; emit dtA bf16 [4096,64] + bc f32 [4096,32]
__global__ __launch_bounds__(256)
void xproj_reduce(const float* __restrict__ part, u16* __restrict__ dtA,
                  float* __restrict__ bc)
{
  int idx = blockIdx.x * 256 + threadIdx.x;   // 4096*96
  int m = idx / 96, n = idx - m * 96;
  float s = 0.f;
#pragma unroll
  for (int p = 0; p < 8; ++p) s += part[(size_t)p * 393216 + idx];
  if (n < 64) dtA[(size_t)m * 64 + n] = f2b(s);
  else        bc[(size_t)m * 32 + (n - 64)] = s;
}

// causal depthwise conv1d (window 4) + bias + silu; vectorized 8 channels/thread
__global__ __launch_bounds__(256)
void conv_silu(const u16* __restrict__ xib, const float* __restrict__ cw,
               const float* __restrict__ cb, u16* __restrict__ ub)
{
  int i = blockIdx.x * 256 + threadIdx.x;     // 1,048,576 threads
  int c8 = (i & 255) * 8;
  int row = i >> 8;                           // b*2048 + l
  int l = row & 2047;
  const u16* base = xib + (size_t)row * 2048 + c8;
  u16x8 x0 = {0,0,0,0,0,0,0,0}, x1 = x0, x2 = x0, x3;
  x3 = *(const u16x8*)(base);
  if (l >= 1) x2 = *(const u16x8*)(base - 2048);
  if (l >= 2) x1 = *(const u16x8*)(base - 2 * 2048);
  if (l >= 3) x0 = *(const u16x8*)(base - 3 * 2048);
  f4_t cb0 = *(const f4_t*)(cb + c8);
  f4_t cb1 = *(const f4_t*)(cb + c8 + 4);
  u16x8 o;
#pragma unroll
  for (int j = 0; j < 8; ++j) {
    f4_t w = *(const f4_t*)(cw + (size_t)(c8 + j) * 4);
    float a = (j < 4 ? cb0[j] : cb1[j - 4])
            + w[0] * b2f(x0[j]) + w[1] * b2f(x1[j])
            + w[2] * b2f(x2[j]) + w[3] * b2f(x3[j]);
    float s = a / (1.f + __expf(-a));
    o[j] = f2b(s);
  }
  *(u16x8*)(ub + (size_t)row * 2048 + c8) = o;
}

// ---- chunk-parallel scan, d-in-lane layout. 64 chunks x 32 steps. ----
// (R2 configuration restored: 1024 blocks = 16 waves/CU; 32x64 regressed.)
__global__ __launch_bounds__(256)
void scan_s1(const u16* __restrict__ delta_bf, const u16* __restrict__ ub,
             const float* __restrict__ bc, const float* __restrict__ alog,
             u16* __restrict__ S, float* __restrict__ Q)
{
  int blk = blockIdx.x;                // 1024 blocks: b(1) x c(6) x g(3)
  int g = blk & 7, c = (blk >> 3) & 63, b = blk >> 9;
  int d = g * 256 + threadIdx.x;
  float Av[16];
#pragma unroll
  for (int nq = 0; nq < 4; ++nq) {
    f4_t al = *(const f4_t*)(alog + (size_t)d * 16 + nq * 4);
#pragma unroll
    for (int j = 0; j < 4; ++j) Av[nq * 4 + j] = -__expf(al[j]);
  }
  float Av0 = Av[0];
  bool st = true;
#pragma unroll
  for (int n = 1; n < 16; ++n)
    st = st && (fabsf(Av[n] - (float)(n + 1) * Av0) <= 1e-3f * (float)(n + 1));
  f4_t Qr[4];
#pragma unroll
  for (int nq = 0; nq < 4; ++nq) Qr[nq] = {0.f,0.f,0.f,0.f};
  float Sd = 0.f;
  int row0 = b * 2048 + c * 32;
  if (st) {
#pragma unroll 2
    for (int i = 0; i < 32; ++i) {
      size_t row = (size_t)(row0 + i);
      float dlt = b2f(delta_bf[row * 2048 + d]);
      float uv  = b2f(ub[row * 2048 + d]);
      const float* bp = bc + row * 32;
      f4_t Bv[4];
#pragma unroll
      for (int nq = 0; nq < 4; ++nq) Bv[nq] = *(const f4_t*)(bp + nq * 4);
      float du = dlt * uv;
      float e1 = __expf(dlt * Av0);
      float a = e1;
      Sd += dlt;
#pragma unroll
      for (int n = 0; n < 16; ++n) {
        Qr[n >> 2][n & 3] = a * Qr[n >> 2][n & 3] + du * Bv[n >> 2][n & 3];
        a *= e1;
      }
    }
  } else {
#pragma unroll 2
    for (int i = 0; i < 32; ++i) {
      size_t row = (size_t)(row0 + i);
      float dlt = b2f(delta_bf[row * 2048 + d]);
      float uv  = b2f(ub[row * 2048 + d]);
      const float* bp = bc + row * 32;
      f4_t Bv[4];
#pragma unroll
      for (int nq = 0; nq < 4; ++nq) Bv[nq] = *(const f4_t*)(bp + nq * 4);
      float du = dlt * uv;
      Sd += dlt;
#pragma unroll
      for (int n = 0; n < 16; ++n) {
        float a = __expf(dlt * Av[n]);
        Qr[n >> 2][n & 3] = a * Qr[n >> 2][n & 3] + du * Bv[n >> 2][n & 3];
      }
    }
  }
  S[(size_t)(b * 64 + c) * 2048 + d] = f2b(Sd);
  size_t o = ((size_t)((b * 64 + c) * 2048 + d)) * 16;
#pragma unroll
  for (int nq = 0; nq < 4; ++nq)
    *(f4_t*)(Q + o + nq * 4) = Qr[nq];
}

// S2: serial prefix over 64 chunks per (b,d,n)
__global__ __launch_bounds__(256)
void scan_comb(const u16* __restrict__ S16, float* __restrict__ Q,
               const float* __restrict__ alog)
{
  int idx = blockIdx.x * 256 + threadIdx.x;   // b*32768 + d*16+n
  int b = idx >> 15, dn = idx & 32767;
  int d = dn >> 4;
  float Av = -__expf(alog[dn]);
  size_t qbase = (size_t)b * 2097152 + dn;
  size_t sbase = (size_t)b * 131072 + d;
  float H = 0.f;
#pragma unroll
  for (int cg = 0; cg < 4; ++cg) {
    float sv[16], qv[16];
#pragma unroll
    for (int j = 0; j < 16; ++j) {
      int c = cg * 16 + j;
      qv[j] = Q[qbase + (size_t)c * 32768];
      sv[j] = b2f(S16[sbase + (size_t)c * 2048]);
    }
#pragma unroll
    for (int j = 0; j < 16; ++j) {
      int c = cg * 16 + j;
      Q[qbase + (size_t)c * 32768] = H;
      H = __expf(Av * sv[j]) * H + qv[j];
    }
  }
}

// S3: re-scan with correct h_in; fused D-skip + silu(z) gate; y overwrites z
__global__ __launch_bounds__(256)
void scan_s3(const u16* __restrict__ delta_bf, const u16* __restrict__ ub,
             const float* __restrict__ bc, const float* __restrict__ alog,
             const float* __restrict__ Q, const float* __restrict__ Dw,
             u16* __restrict__ zy)
{
  int blk = blockIdx.x;                // 1024 blocks
  int g = blk & 7, c = (blk >> 3) & 63, b = blk >> 9;
  int d = g * 256 + threadIdx.x;
  float Av[16];
#pragma unroll
  for (int nq = 0; nq < 4; ++nq) {
    f4_t al = *(const f4_t*)(alog + (size_t)d * 16 + nq * 4);
#pragma unroll
    for (int j = 0; j < 4; ++j) Av[nq * 4 + j] = -__expf(al[j]);
  }
  float Av0 = Av[0];
  bool st = true;
#pragma unroll
  for (int n = 1; n < 16; ++n)
    st = st && (fabsf(Av[n] - (float)(n + 1) * Av0) <= 1e-3f * (float)(n + 1));
  f4_t h4[4];
  size_t o = ((size_t)((b * 64 + c) * 2048 + d)) * 16;
#pragma unroll
  for (int nq = 0; nq < 4; ++nq) h4[nq] = *(const f4_t*)(Q + o + nq * 4);
  float Dv = Dw[d];
  int row0 = b * 2048 + c * 32;
  if (st) {
#pragma unroll 2
    for (int i = 0; i < 32; ++i) {
      size_t row = (size_t)(row0 + i);
      float dlt = b2f(delta_bf[row * 2048 + d]);
      float uv  = b2f(ub[row * 2048 + d]);
      const float* bp = bc + row * 32;
      f4_t Bv[4], Cv[4];
#pragma unroll
      for (int nq = 0; nq < 4; ++nq) { Bv[nq] = *(const f4_t*)(bp + nq * 4); Cv[nq] = *(const f4_t*)(bp + 16 + nq * 4); }
      float du = dlt * uv;
      float e1 = __expf(dlt * Av0);
      float a = e1;
      float y = 0.f;
#pragma unroll
      for (int n = 0; n < 16; ++n) {
        float hn = a * h4[n >> 2][n & 3] + du * Bv[n >> 2][n & 3];
        h4[n >> 2][n & 3] = hn;
        y += hn * Cv[n >> 2][n & 3];
        a *= e1;
      }
      float zv = b2f(zy[row * 2048 + d]);
      float ov = (y + Dv * uv) * (zv / (1.f + __expf(-zv)));
      zy[row * 2048 + d] = f2b(ov);
    }
  } else {
#pragma unroll 2
    for (int i = 0; i < 32; ++i) {
      size_t row = (size_t)(row0 + i);
      float dlt = b2f(delta_bf[row * 2048 + d]);
      float uv  = b2f(ub[row * 2048 + d]);
      const float* bp = bc + row * 32;
      f4_t Bv[4], Cv[4];
#pragma unroll
      for (int nq = 0; nq < 4; ++nq) { Bv[nq] = *(const f4_t*)(bp + nq * 4); Cv[nq] = *(const f4_t*)(bp + 16 + nq * 4); }
      float du = dlt * uv;
      float y = 0.f;
#pragma unroll
      for (int n = 0; n < 16; ++n) {
        float a = __expf(dlt * Av[n]);
        float hn = a * h4[n >> 2][n & 3] + du * Bv[n >> 2][n & 3];
        h4[n >> 2][n & 3] = hn;
        y += hn * Cv[n >> 2][n & 3];
      }
      float zv = b2f(zy[row * 2048 + d]);
      float ov = (y + Dv * uv) * (zv / (1.f + __expf(-zv)));
      zy[row * 2048 + d] = f2b(ov);
    }
  }
}

// residual + LayerNorm over two out_proj partials, f32 in/out.
__global__ __launch_bounds__(256)
void ln_kernel(const float* __restrict__ hp0, const float* __restrict__ hp1,
               const float* __restrict__ xin,
               const float* __restrict__ lnw, const float* __restrict__ lnb,
               float* __restrict__ outp)
{
  __shared__ float ssum[4], ssq[4];
  int row = blockIdx.x, t = threadIdx.x;
  f4_t h0 = *(const f4_t*)(hp0 + (size_t)row * 1024 + t * 4);
  f4_t h1 = *(const f4_t*)(hp1 + (size_t)row * 1024 + t * 4);
  f4_t xv = *(const f4_t*)(xin + (size_t)row * 1024 + t * 4);
  float v[4], s = 0.f, q = 0.f;
#pragma unroll
  for (int j = 0; j < 4; ++j) { v[j] = h0[j] + h1[j] + xv[j]; s += v[j]; q += v[j] * v[j]; }
#pragma unroll
  for (int m = 32; m; m >>= 1) { s += __shfl_xor(s, m, 64); q += __shfl_xor(q, m, 64); }
  int wv = t >> 6;
  if ((t & 63) == 0) { ssum[wv] = s; ssq[wv] = q; }
  __syncthreads();
  s = ssum[0] + ssum[1] + ssum[2] + ssum[3];
  q = ssq[0] + ssq[1] + ssq[2] + ssq[3];
  float mu = s * (1.f / 1024.f);
  float var = q * (1.f / 1024.f) - mu * mu;
  float rs = rsqrtf(var + 1e-5f);
  f4_t o;
#pragma unroll
  for (int j = 0; j < 4; ++j)
    o[j] = (v[j] - mu) * rs * lnw[t * 4 + j] + lnb[t * 4 + j];
  *(f4_t*)(outp + (size_t)row * 1024 + t * 4) = o;
}

extern "C" void kernel_launch(void* const* d_in, const int* in_sizes, int n_in,
                              void* d_out, int out_size, void* d_ws, size_t ws_size,
                              hipStream_t stream)
{
  const float* x      = (const float*)d_in[0];   // [2,2048,1024]
  const float* inW    = (const float*)d_in[1];   // [4096,1024]
  const float* convW  = (const float*)d_in[2];   // [2048,1,4]
  const float* convB  = (const float*)d_in[3];   // [2048]
  const float* xprojW = (const float*)d_in[4];   // [96,2048]
  const float* dtW    = (const float*)d_in[5];   // [2048,64]
  const float* dtB    = (const float*)d_in[6];   // [2048]
  const float* alog   = (const float*)d_in[7];   // [2048,16]
  const float* Dw     = (const float*)d_in[8];   // [2048]
  const float* outW   = (const float*)d_in[9];   // [1024,2048]
  const float* lnw    = (const float*)d_in[10];  // [1024]
  const float* lnb    = (const float*)d_in[11];  // [1024]
  float* out = (float*)d_out;                    // [2,2048,1024] f32 (16 MiB)

  char* ws = (char*)d_ws;
  u16*   xiz    = (u16*)(ws);
  u16*   zy     = xiz + 8388608;
  u16*   xb     = (u16*)(ws + 33554432);
  u16*   inWb   = xb + 4194304;
  u16*   u_bf   = (u16*)(ws + 33554432);          // overwrites xb/inWb after gemm8_in
  u16*   dtA    = (u16*)(ws + 50331648);
  float* bc     = (float*)(ws + 50855936);
  u16*   xprojWb= (u16*)(ws + 51380224);
  u16*   dtWb   = (u16*)(ws + 51773440);
  u16*   outWb  = (u16*)(ws + 52035584);
  u16*   delta  = xiz;                            // overwrites dead xi
  float* hpart1 = (float*)(ws);                   // out_proj partial1 (delta dead)
  float* hpart0 = (float*)d_out;                  // out_proj partial0
  float* xpart  = (float*)d_out;                  // x_proj partials [8][4096][96]
  u16*   Sbuf   = dtA;                            // S (dtA dead after gemm_dt)
  float* Qbuf   = (float*)d_out;                  // Q fills d_out exactly (16.78 MB)

  dim3 blk(256);
  // fused f32 -> bf16 conversions (one launch)
  cvt_all<<<10560, blk, 0, stream>>>(x, inW, xprojW, dtW, outW,
                                     xb, inWb, xprojWb, dtWb, outWb);
  // in_proj: [4096,1024] x [4096,1024]^T -> xi | z (bf16); 4-phase + af2 prefetch
  gemm8_in<<<dim3(16, 16), dim3(512), 0, stream>>>(xb, inWb, xiz);
  // depthwise causal conv + silu -> u (bf16; overwrites xb/inWb)
  conv_silu<<<4096, blk, 0, stream>>>(xiz, convW, convB, u_bf);
  // x_proj split-K (8 x 256): partials into d_out
  gemm_xp<<<dim3(8, 32), blk, 0, stream>>>(u_bf, 2048, xprojWb, 2048, 256, 96, nullptr, xpart, nullptr, nullptr);
  xproj_reduce<<<1536, blk, 0, stream>>>(xpart, dtA, bc);
  // dt_proj + softplus -> delta (bf16, overwrites xi)
  gemm_dt<<<dim3(16, 32), blk, 0, stream>>>(dtA, 64, dtWb, 64, 64, 2048, delta, nullptr, nullptr, dtB);
  // chunk-parallel scan (64 chunks x 32 steps): S1 -> combine -> S3
  scan_s1<<<1024, blk, 0, stream>>>(delta, u_bf, bc, alog, Sbuf, Qbuf);
  scan_comb<<<256, blk, 0, stream>>>(Sbuf, Qbuf, alog);
  scan_s3<<<1024, blk, 0, stream>>>(delta, u_bf, bc, alog, Qbuf, Dw, zy);
  // out_proj 8-phase split-K (2): partial0 -> d_out, partial1 -> ws[0,16M)
  gemm8_out<<<dim3(4, 32, 2), dim3(512), 0, stream>>>(zy, outWb, hpart0, hpart1);
  // residual + LayerNorm (sums both partials) -> f32 out (in place over partial0)
  ln_kernel<<<4096, blk, 0, stream>>>(hpart0, hpart1, x, lnw, lnb, out);
}

// Round 5
// 305.133 us; speedup vs baseline: 1.0379x; 1.0376x over previous
//
#include <hip/hip_runtime.h>

typedef unsigned short u16;
typedef __attribute__((ext_vector_type(8))) short bf8_t;    // 8 x bf16 (4 VGPRs)
typedef __attribute__((ext_vector_type(4))) float f4_t;     // 4 x f32
typedef __attribute__((ext_vector_type(4))) unsigned short u16x4;
typedef __attribute__((ext_vector_type(8))) unsigned short u16x8;

__device__ __forceinline__ float b2f(u16 h) {
  union { unsigned u; float f; } v; v.u = ((unsigned)h) << 16; return v.f;
}
__device__ __forceinline__ u16 f2b(float f) {
  union { float f; unsigned u; } v; v.f = f;
  unsigned u = v.u;
  u += 0x7fffu + ((u >> 16) & 1u);   // round-nearest-even
  return (u16)(u >> 16);
}

#define AS1C(p) ((const __attribute__((address_space(1))) void*)(p))
#define AS3(p)  ((__attribute__((address_space(3))) void*)(p))

// one fused f32 -> bf16 convert over all 5 weight/input arrays
__global__ __launch_bounds__(256)
void cvt_all(const float* __restrict__ x, const float* __restrict__ inW,
             const float* __restrict__ xprojW, const float* __restrict__ dtW,
             const float* __restrict__ outW,
             u16* __restrict__ xb, u16* __restrict__ inWb, u16* __restrict__ xpb,
             u16* __restrict__ dtWb, u16* __restrict__ outWb)
{
  int i = blockIdx.x * 256 + threadIdx.x;      // float4 index, total 2703360
  if (i >= 2703360) return;
  const float* s; u16* d; int off;
  if (i < 1048576)      { s = x;      d = xb;    off = i; }
  else if (i < 2097152) { s = inW;    d = inWb;  off = i - 1048576; }
  else if (i < 2146304) { s = xprojW; d = xpb;   off = i - 2097152; }
  else if (i < 2179072) { s = dtW;    d = dtWb;  off = i - 2146304; }
  else                  { s = outW;   d = outWb; off = i - 2179072; }
  f4_t v = *(const f4_t*)(s + (size_t)off * 4);
  u16x4 o;
#pragma unroll
  for (int j = 0; j < 4; ++j) o[j] = f2b(v[j]);
  *(u16x4*)(d + (size_t)off * 4) = o;
}

// Stage one 128x64 bf16 tile (16 KB) into LDS, XOR-swizzled: granule (r,q)
// holds global colchunk q^(r&7). Staging lane i (chunk of 8 rows) fetches
// colchunk (i&7)^((i>>3)&7); reader uses granule (g ^ (row&7)). Bank-quad
// depends only on q_l -> 8 lanes per 4-bank group = 2/bank = conflict-free.
__device__ __forceinline__ void stage64(const u16* g, int ld, int row0, int rowmax,
                                        int k0, u16* lds, int wid, int lane) {
  int qg = (lane & 7) ^ ((lane >> 3) & 7);
#pragma unroll
  for (int c = 0; c < 4; ++c) {
    int chunk = wid * 4 + c;
    int r = row0 + chunk * 8 + (lane >> 3);
    if (r > rowmax) r = rowmax;                       // clamp (results discarded later)
    const u16* gp = g + (size_t)r * ld + k0 + qg * 8;
    __builtin_amdgcn_global_load_lds(AS1C(gp), AS3(lds + chunk * 512), 16, 0, 0);
  }
}

// C = A * Bt^T : A[M,K] bf16 row-major (lda), Bt[N,K] bf16 row-major (ldb).
// BK=64 (two 32-k half-steps per barrier epoch).
// EPI 1: x_proj   -> split-K partials: of32[(bx*4096+m)*96+n], n<96
// EPI 2: dt_proj  -> o16[m*2048+n] = bf16(softplus(acc + biasf[n]))
template<int EPI>
__device__ __forceinline__ void gemm_body(const u16* __restrict__ A, int lda,
             const u16* __restrict__ Bt, int ldb,
             int Kblk, int Nact,
             u16* __restrict__ o16, float* __restrict__ of32,
             const float* __restrict__ biasf)
{
  __shared__ u16 lsA[128 * 64];
  __shared__ u16 lsB[128 * 64];
  const int tid = threadIdx.x;
  const int wid = tid >> 6, lane = tid & 63;
  const int wm = wid >> 1, wn = wid & 1;          // 2x2 wave grid, 64x64 each
  const int lrow = lane & 15;
  const int kq = lane >> 4;                       // 0..3
  const int sw = lrow & 7;                        // swizzle key
  const int m0 = blockIdx.y * 128;
  const int n0 = (EPI == 1) ? 0 : blockIdx.x * 128;
  int kbase = 0;
  if (EPI == 1) kbase = blockIdx.x * Kblk;

  f4_t acc[4][4];
#pragma unroll
  for (int i = 0; i < 4; ++i)
#pragma unroll
    for (int j = 0; j < 4; ++j) acc[i][j] = {0.f, 0.f, 0.f, 0.f};

  for (int kt = kbase; kt < kbase + Kblk; kt += 64) {
    stage64(A,  lda, m0, 0x3fffffff, kt, lsA, wid, lane);
    stage64(Bt, ldb, n0, Nact - 1,   kt, lsB, wid, lane);
    __syncthreads();
#pragma unroll
    for (int h = 0; h < 2; ++h) {
      const int lk = ((h * 4 + kq) ^ sw) * 8;
      bf8_t af[4], bfr[4];
#pragma unroll
      for (int mi = 0; mi < 4; ++mi)
        af[mi] = *(const bf8_t*)&lsA[(wm * 64 + mi * 16 + lrow) * 64 + lk];
#pragma unroll
      for (int ni = 0; ni < 4; ++ni)
        bfr[ni] = *(const bf8_t*)&lsB[(wn * 64 + ni * 16 + lrow) * 64 + lk];
#pragma unroll
      for (int mi = 0; mi < 4; ++mi)
#pragma unroll
        for (int ni = 0; ni < 4; ++ni)
          acc[mi][ni] = __builtin_amdgcn_mfma_f32_16x16x32_bf16(af[mi], bfr[ni], acc[mi][ni], 0, 0, 0);
    }
    __syncthreads();
  }

  const int rq = (lane >> 4) * 4;                  // C/D: row=(lane>>4)*4+r, col=lane&15
#pragma unroll
  for (int mi = 0; mi < 4; ++mi) {
#pragma unroll
    for (int ni = 0; ni < 4; ++ni) {
#pragma unroll
      for (int r = 0; r < 4; ++r) {
        int m = m0 + wm * 64 + mi * 16 + rq + r;
        int n = n0 + wn * 64 + ni * 16 + lrow;
        float v = acc[mi][ni][r];
        if (EPI == 1) {
          if (n < 96) of32[((size_t)blockIdx.x * 4096 + m) * 96 + n] = v;
        } else if (EPI == 2) {
          float t = v + biasf[n];
          float sp = (t > 20.f) ? t : log1pf(__expf(t));
          o16[(size_t)m * 2048 + n] = f2b(sp);
        }
      }
    }
  }
}

__global__ __launch_bounds__(256)
void gemm_xp(const u16* A, int lda, const u16* Bt, int ldb, int Kblk, int Nact,
             u16* o16, float* of32, const float* biasf)
{ gemm_body<1>(A, lda, Bt, ldb, Kblk, Nact, o16, of32, biasf); }

__global__ __launch_bounds__(256)
void gemm_dt(const u16* A, int lda, const u16* Bt, int ldb, int Kblk, int Nact,
             u16* o16, float* of32, const float* biasf)
{ gemm_body<2>(A, lda, Bt, ldb, Kblk, Nact, o16, of32, biasf); }

// ---------------------------------------------------------------------------
// 8-phase 256x256 bf16 GEMM for in_proj (M=N=4096, K=1024): verified R1/R2
// (42.28 us). Restored verbatim after R3 (4-phase: null) and R4 (prefetch+
// swizzle: regression). 512 thr, 2Mx4N waves 128x64, BK=64, 128 KB dbuf LDS,
// counted vmcnt(4) at phases 4/8, setprio around MFMA clusters.
// ---------------------------------------------------------------------------

// stage one 128x64 unit: 512 threads x 2 x 16B gload_lds. granule g = j*512 +
// wid*64 + lane -> lds row g>>3, slot g&7, global colchunk (g&7)^((g>>3)&7).
__device__ __forceinline__ void stageu(const u16* __restrict__ g, int ld,
                                       int row0, int k0, u16* ldsu,
                                       int wid, int lane) {
  int qg = (lane & 7) ^ ((lane >> 3) & 7);
#pragma unroll
  for (int j = 0; j < 2; ++j) {
    int rr = j * 64 + wid * 8 + (lane >> 3);
    const u16* gp = g + (size_t)(row0 + rr) * ld + k0 + qg * 8;
    __builtin_amdgcn_global_load_lds(AS1C(gp), AS3(ldsu + (j * 512 + wid * 64) * 8), 16, 0, 0);
  }
}

#define G8_BAR()   __builtin_amdgcn_s_barrier()
#define G8_LGKM0() do { asm volatile("s_waitcnt lgkmcnt(0)" ::: "memory"); \
                        __builtin_amdgcn_sched_barrier(0); } while (0)
#define G8_LGKM8() asm volatile("s_waitcnt lgkmcnt(8)" ::: "memory")
#define G8_VM(N)   do { asm volatile("s_waitcnt vmcnt(" #N ")" ::: "memory"); \
                        __builtin_amdgcn_sched_barrier(0); } while (0)

#define RD_A(base, MH) do { \
  _Pragma("unroll") \
  for (int mi_ = 0; mi_ < 4; ++mi_) { \
    af[mi_][0] = *(const bf8_t*)((base) + arow + ((MH) * 64 + mi_ * 16) * 64 + aq0); \
    af[mi_][1] = *(const bf8_t*)((base) + arow + ((MH) * 64 + mi_ * 16) * 64 + aq1); \
  } } while (0)

#define RD_B(base, NH) do { \
  _Pragma("unroll") \
  for (int ni_ = 0; ni_ < 2; ++ni_) { \
    bfr[NH][ni_][0] = *(const bf8_t*)((base) + brow + ((NH) * 32 + ni_ * 16) * 64 + aq0); \
    bfr[NH][ni_][1] = *(const bf8_t*)((base) + brow + ((NH) * 32 + ni_ * 16) * 64 + aq1); \
  } } while (0)

#define MMA(MH, NH) do { \
  __builtin_amdgcn_s_setprio(1); \
  _Pragma("unroll") \
  for (int mi_ = 0; mi_ < 4; ++mi_) \
    _Pragma("unroll") \
    for (int ni_ = 0; ni_ < 2; ++ni_) { \
      acc[(MH) * 4 + mi_][(NH) * 2 + ni_] = __builtin_amdgcn_mfma_f32_16x16x32_bf16( \
          af[mi_][0], bfr[NH][ni_][0], acc[(MH) * 4 + mi_][(NH) * 2 + ni_], 0, 0, 0); \
      acc[(MH) * 4 + mi_][(NH) * 2 + ni_] = __builtin_amdgcn_mfma_f32_16x16x32_bf16( \
          af[mi_][1], bfr[NH][ni_][1], acc[(MH) * 4 + mi_][(NH) * 2 + ni_], 0, 0, 0); \
    } \
  __builtin_amdgcn_s_setprio(0); \
} while (0)

__global__ __launch_bounds__(512, 2)
void gemm8_in(const u16* __restrict__ A, const u16* __restrict__ Bt,
              u16* __restrict__ o16)
{
  __shared__ u16 ls[65536];                       // 128 KB: 2 buf x (A 32K + B 32K)
  const int tid = threadIdx.x;
  const int wid = tid >> 6, lane = tid & 63;
  const int wm = wid >> 2, wn = wid & 3;          // 2x4 wave grid, 128x64 per wave
  const int lrow = lane & 15;
  const int kq = lane >> 4;
  const int sw = lrow & 7;
  const int m0 = blockIdx.y * 256;
  const int n0 = blockIdx.x * 256;
  u16* lsA0 = ls;
  u16* lsB0 = ls + 16384;
  u16* lsA1 = ls + 32768;
  u16* lsB1 = ls + 49152;
  const int arow = (wm * 128 + lrow) * 64;
  const int brow = (wn * 64 + lrow) * 64;
  const int aq0 = (kq ^ sw) * 8;
  const int aq1 = ((4 + kq) ^ sw) * 8;

  f4_t acc[8][4];
#pragma unroll
  for (int i = 0; i < 8; ++i)
#pragma unroll
    for (int j = 0; j < 4; ++j) acc[i][j] = {0.f, 0.f, 0.f, 0.f};
  bf8_t af[4][2];
  bf8_t bfr[2][2][2];

  // prologue: tile0 (A0,A1,B0,B1)->buf0, tile1 (B0,B1)->buf1; keep 4 in flight
  stageu(A,  1024, m0,        0, lsA0,        wid, lane);
  stageu(A,  1024, m0 + 128,  0, lsA0 + 8192, wid, lane);
  stageu(Bt, 1024, n0,        0, lsB0,        wid, lane);
  stageu(Bt, 1024, n0 + 128,  0, lsB0 + 8192, wid, lane);
  stageu(Bt, 1024, n0,       64, lsB1,        wid, lane);
  stageu(Bt, 1024, n0 + 128, 64, lsB1 + 8192, wid, lane);
  G8_VM(4); G8_BAR();

#pragma unroll 1
  for (int i = 0; i < 7; ++i) {                   // iterations 0..6 (tiles 0..13)
    const int k1 = (2 * i + 1) * 64, k2 = k1 + 64, k3 = k1 + 128;
    // P1: read buf0 A-half0 + B-half0; stage (t+1).A0 -> buf1
    RD_A(lsA0, 0); RD_B(lsB0, 0);
    stageu(A, 1024, m0, k1, lsA1, wid, lane);
    G8_LGKM8(); G8_BAR(); G8_LGKM0(); MMA(0, 0); G8_BAR();
    // P2: read buf0 B-half1; stage (t+1).A1 -> buf1
    RD_B(lsB0, 1);
    stageu(A, 1024, m0 + 128, k1, lsA1 + 8192, wid, lane);
    G8_BAR(); G8_LGKM0(); MMA(0, 1); G8_BAR();
    // P3: read buf0 A-half1; stage (t+2).B0 -> buf0 (B reads done end P2)
    RD_A(lsA0, 1);
    stageu(Bt, 1024, n0, k2, lsB0, wid, lane);
    G8_BAR(); G8_LGKM0(); MMA(1, 0); G8_BAR();
    // P4: stage (t+2).B1 -> buf0; counted vmcnt -> tile t+1 landed
    stageu(Bt, 1024, n0 + 128, k2, lsB0 + 8192, wid, lane);
    G8_BAR(); G8_LGKM0(); MMA(1, 1); G8_VM(4); G8_BAR();
    // P5: read buf1 A-half0 + B-half0; stage (t+2).A0 -> buf0 (A reads done end P3)
    RD_A(lsA1, 0); RD_B(lsB1, 0);
    stageu(A, 1024, m0, k2, lsA0, wid, lane);
    G8_LGKM8(); G8_BAR(); G8_LGKM0(); MMA(0, 0); G8_BAR();
    // P6: read buf1 B-half1; stage (t+2).A1 -> buf0
    RD_B(lsB1, 1);
    stageu(A, 1024, m0 + 128, k2, lsA0 + 8192, wid, lane);
    G8_BAR(); G8_LGKM0(); MMA(0, 1); G8_BAR();
    // P7: read buf1 A-half1; stage (t+3).B0 -> buf1
    RD_A(lsA1, 1);
    stageu(Bt, 1024, n0, k3, lsB1, wid, lane);
    G8_BAR(); G8_LGKM0(); MMA(1, 0); G8_BAR();
    // P8: stage (t+3).B1 -> buf1; counted vmcnt -> tile t+2 landed
    stageu(Bt, 1024, n0 + 128, k3, lsB1 + 8192, wid, lane);
    G8_BAR(); G8_LGKM0(); MMA(1, 1); G8_VM(4); G8_BAR();
  }

  {                                               // last iteration: tiles 14,15
    const int k1 = 960;
    RD_A(lsA0, 0); RD_B(lsB0, 0);
    stageu(A, 1024, m0, k1, lsA1, wid, lane);
    G8_LGKM8(); G8_BAR(); G8_LGKM0(); MMA(0, 0); G8_BAR();
    RD_B(lsB0, 1);
    stageu(A, 1024, m0 + 128, k1, lsA1 + 8192, wid, lane);
    G8_BAR(); G8_LGKM0(); MMA(0, 1); G8_BAR();
    RD_A(lsA0, 1);
    G8_BAR(); G8_LGKM0(); MMA(1, 0); G8_BAR();
    G8_BAR(); G8_LGKM0(); MMA(1, 1); G8_VM(0); G8_BAR();
    RD_A(lsA1, 0); RD_B(lsB1, 0);
    G8_BAR(); G8_LGKM0(); MMA(0, 0); G8_BAR();
    RD_B(lsB1, 1);
    G8_BAR(); G8_LGKM0(); MMA(0, 1); G8_BAR();
    RD_A(lsA1, 1);
    G8_BAR(); G8_LGKM0(); MMA(1, 0); G8_BAR();
    G8_LGKM0(); MMA(1, 1);
  }

  // epilogue: xi (n<2048) | z (n>=2048, at o16+8M)
  const int rq = (lane >> 4) * 4;
#pragma unroll
  for (int mi = 0; mi < 8; ++mi) {
#pragma unroll
    for (int ni = 0; ni < 4; ++ni) {
#pragma unroll
      for (int r = 0; r < 4; ++r) {
        int m = m0 + wm * 128 + mi * 16 + rq + r;
        int n = n0 + wn * 64 + ni * 16 + lrow;
        float v = acc[mi][ni][r];
        if (n < 2048) o16[(size_t)m * 2048 + n] = f2b(v);
        else          o16[(size_t)8388608 + (size_t)m * 2048 + (n - 2048)] = f2b(v);
      }
    }
  }
}

// ---------------------------------------------------------------------------
// NEW R5: out_proj as single-K 4-phase GEMM. Tile 128M x 128N, K=2048
// (32 BK-tiles), grid (8,32) = 256 blocks = full GPU, NO split-K -> no f32
// partial round-trip (saves 33.6 MB HBM) and LN reads one y array.
// 512 thr, 2Mx4N waves, 64x32 per wave, acc 4x2. LDS 64 KB dbuf.
// Ledger (loads/thread, stageu=2): prologue A0,B0,B1 = 6; VM(2) -> B(t1)=2.
//  Q1: +A(t+1)2 -> 4; consume buf0.kh0
//  Q2: +B(t+2)2 -> 6; VM(2) retires B(t+1),A(t+1) -> buf1 ready
//  Q3: +A(t+2)2 -> 4; consume buf1.kh0
//  Q4: +B(t+3)2 -> 6; VM(2) retires tile t+2 -> buf0 ready. invariant.
// Region safety: Q1/Q3 read ALL of buf.B (both k-halves) -> B-stage next
// phase is sealed; buf.A fully read by end Q2/Q4 -> A-stage next Q sealed.
// ---------------------------------------------------------------------------

#define O4_RD_A(base, KH) do { \
  _Pragma("unroll") \
  for (int mi_ = 0; mi_ < 4; ++mi_) \
    af4[mi_][KH] = *(const bf8_t*)((base) + arow + mi_ * 1024 + ((KH) ? aq1 : aq0)); \
  } while (0)

#define O4_RD_B(base) do { \
  _Pragma("unroll") \
  for (int ni_ = 0; ni_ < 2; ++ni_) { \
    bf4[ni_][0] = *(const bf8_t*)((base) + brow + ni_ * 1024 + aq0); \
    bf4[ni_][1] = *(const bf8_t*)((base) + brow + ni_ * 1024 + aq1); \
  } } while (0)

#define O4_MMA(KH) do { \
  __builtin_amdgcn_s_setprio(1); \
  _Pragma("unroll") \
  for (int mi_ = 0; mi_ < 4; ++mi_) \
    _Pragma("unroll") \
    for (int ni_ = 0; ni_ < 2; ++ni_) \
      acc[mi_][ni_] = __builtin_amdgcn_mfma_f32_16x16x32_bf16( \
          af4[mi_][KH], bf4[ni_][KH], acc[mi_][ni_], 0, 0, 0); \
  __builtin_amdgcn_s_setprio(0); \
} while (0)

__global__ __launch_bounds__(512, 2)
void gemm4_out(const u16* __restrict__ A, const u16* __restrict__ Bt,
               float* __restrict__ yout)
{
  __shared__ u16 ls[32768];                       // 64 KB: 2 buf x (A 16K + B 16K)
  const int tid = threadIdx.x;
  const int wid = tid >> 6, lane = tid & 63;
  const int wm = wid >> 2, wn = wid & 3;          // 2Mx4N, 64x32 per wave
  const int lrow = lane & 15;
  const int kq = lane >> 4;
  const int sw = lrow & 7;
  const int m0 = blockIdx.y * 128;
  const int n0 = blockIdx.x * 128;
  u16* lsA0 = ls;                                 // 8192 u16 = 128x64
  u16* lsB0 = ls + 8192;
  u16* lsA1 = ls + 16384;
  u16* lsB1 = ls + 24576;
  const int arow = (wm * 64 + lrow) * 64;
  const int brow = (wn * 32 + lrow) * 64;
  const int aq0 = (kq ^ sw) * 8;
  const int aq1 = ((4 + kq) ^ sw) * 8;

  f4_t acc[4][2];
#pragma unroll
  for (int i = 0; i < 4; ++i)
#pragma unroll
    for (int j = 0; j < 2; ++j) acc[i][j] = {0.f, 0.f, 0.f, 0.f};
  bf8_t af4[4][2];
  bf8_t bf4[2][2];

  // prologue: tile0 (A,B)->buf0, tile1 B->buf1
  stageu(A,  2048, m0,  0, lsA0, wid, lane);
  stageu(Bt, 2048, n0,  0, lsB0, wid, lane);
  stageu(Bt, 2048, n0, 64, lsB1, wid, lane);
  G8_VM(2); G8_BAR();

#pragma unroll 1
  for (int i = 0; i < 15; ++i) {                  // tile pairs (0,1)..(28,29)
    const int ka1 = (2 * i + 1) * 64;             // A of odd tile t+1
    const int k2  = ka1 + 64;                     // tile t+2
    const int kb3 = ka1 + 128;                    // B of tile t+3
    // Q1: read buf0 {A-kh0, B both}; stage A(t+1)->buf1.A (sealed prev Q4)
    O4_RD_A(lsA0, 0); O4_RD_B(lsB0);
    stageu(A, 2048, m0, ka1, lsA1, wid, lane);
    G8_BAR(); G8_LGKM0(); O4_MMA(0); G8_BAR();
    // Q2: read buf0 A-kh1; stage B(t+2)->buf0.B (sealed end Q1)
    O4_RD_A(lsA0, 1);
    stageu(Bt, 2048, n0, k2, lsB0, wid, lane);
    G8_LGKM0(); O4_MMA(1); G8_VM(2); G8_BAR();
    // Q3: read buf1 {A-kh0, B both}; stage A(t+2)->buf0.A (sealed end Q2)
    O4_RD_A(lsA1, 0); O4_RD_B(lsB1);
    stageu(A, 2048, m0, k2, lsA0, wid, lane);
    G8_BAR(); G8_LGKM0(); O4_MMA(0); G8_BAR();
    // Q4: read buf1 A-kh1; stage B(t+3)->buf1.B (sealed end Q3)
    O4_RD_A(lsA1, 1);
    stageu(Bt, 2048, n0, kb3, lsB1, wid, lane);
    G8_LGKM0(); O4_MMA(1); G8_VM(2); G8_BAR();
  }

  {                                               // final: tiles 30, 31
    O4_RD_A(lsA0, 0); O4_RD_B(lsB0);
    stageu(A, 2048, m0, 1984, lsA1, wid, lane);   // A(31)
    G8_BAR(); G8_LGKM0(); O4_MMA(0); G8_BAR();
    O4_RD_A(lsA0, 1);
    G8_LGKM0(); O4_MMA(1); G8_VM(0); G8_BAR();    // drain A(31),B(31)
    O4_RD_A(lsA1, 0); O4_RD_B(lsB1);
    G8_LGKM0(); O4_MMA(0);
    O4_RD_A(lsA1, 1);
    G8_LGKM0(); O4_MMA(1);
  }

  const int rq = (lane >> 4) * 4;
#pragma unroll
  for (int mi = 0; mi < 4; ++mi) {
#pragma unroll
    for (int ni = 0; ni < 2; ++ni) {
#pragma unroll
      for (int r = 0; r < 4; ++r) {
        int m = m0 + wm * 64 + mi * 16 + rq + r;
        int n = n0 + wn * 32 + ni * 16 + lrow;
        yout[(size_t)m * 1024 + n] = acc[mi][ni][r];
      }
    }
  }
}

// reduce 8 split-K partials of x_proj; emit dtA bf16 [4096,64] + bc f32 [4096,32]
__global__ __launch_bounds__(256)
void xproj_reduce(const float* __restrict__ part, u16* __restrict__ dtA,
                  float* __restrict__ bc)
{
  int idx = blockIdx.x * 256 + threadIdx.x;   // 4096*96
  int m = idx / 96, n = idx - m * 96;
  float s = 0.f;
#pragma unroll
  for (int p = 0; p < 8; ++p) s += part[(size_t)p * 393216 + idx];
  if (n < 64) dtA[(size_t)m * 64 + n] = f2b(s);
  else        bc[(size_t)m * 32 + (n - 64)] = s;
}

// causal depthwise conv1d (window 4) + bias + silu; vectorized 8 channels/thread
__global__ __launch_bounds__(256)
void conv_silu(const u16* __restrict__ xib, const float* __restrict__ cw,
               const float* __restrict__ cb, u16* __restrict__ ub)
{
  int i = blockIdx.x * 256 + threadIdx.x;     // 1,048,576 threads
  int c8 = (i & 255) * 8;
  int row = i >> 8;                           // b*2048 + l
  int l = row & 2047;
  const u16* base = xib + (size_t)row * 2048 + c8;
  u16x8 x0 = {0,0,0,0,0,0,0,0}, x1 = x0, x2 = x0, x3;
  x3 = *(const u16x8*)(base);
  if (l >= 1) x2 = *(const u16x8*)(base - 2048);
  if (l >= 2) x1 = *(const u16x8*)(base - 2 * 2048);
  if (l >= 3) x0 = *(const u16x8*)(base - 3 * 2048);
  f4_t cb0 = *(const f4_t*)(cb + c8);
  f4_t cb1 = *(const f4_t*)(cb + c8 + 4);
  u16x8 o;
#pragma unroll
  for (int j = 0; j < 8; ++j) {
    f4_t w = *(const f4_t*)(cw + (size_t)(c8 + j) * 4);
    float a = (j < 4 ? cb0[j] : cb1[j - 4])
            + w[0] * b2f(x0[j]) + w[1] * b2f(x1[j])
            + w[2] * b2f(x2[j]) + w[3] * b2f(x3[j]);
    float s = a / (1.f + __expf(-a));
    o[j] = f2b(s);
  }
  *(u16x8*)(ub + (size_t)row * 2048 + c8) = o;
}

// ---- chunk-parallel scan, d-in-lane layout. 64 chunks x 32 steps. ----
__global__ __launch_bounds__(256)
void scan_s1(const u16* __restrict__ delta_bf, const u16* __restrict__ ub,
             const float* __restrict__ bc, const float* __restrict__ alog,
             u16* __restrict__ S, float* __restrict__ Q)
{
  int blk = blockIdx.x;                // 1024 blocks: b(1) x c(6) x g(3)
  int g = blk & 7, c = (blk >> 3) & 63, b = blk >> 9;
  int d = g * 256 + threadIdx.x;
  float Av[16];
#pragma unroll
  for (int nq = 0; nq < 4; ++nq) {
    f4_t al = *(const f4_t*)(alog + (size_t)d * 16 + nq * 4);
#pragma unroll
    for (int j = 0; j < 4; ++j) Av[nq * 4 + j] = -__expf(al[j]);
  }
  float Av0 = Av[0];
  bool st = true;
#pragma unroll
  for (int n = 1; n < 16; ++n)
    st = st && (fabsf(Av[n] - (float)(n + 1) * Av0) <= 1e-3f * (float)(n + 1));
  f4_t Qr[4];
#pragma unroll
  for (int nq = 0; nq < 4; ++nq) Qr[nq] = {0.f,0.f,0.f,0.f};
  float Sd = 0.f;
  int row0 = b * 2048 + c * 32;
  if (st) {
#pragma unroll 2
    for (int i = 0; i < 32; ++i) {
      size_t row = (size_t)(row0 + i);
      float dlt = b2f(delta_bf[row * 2048 + d]);
      float uv  = b2f(ub[row * 2048 + d]);
      const float* bp = bc + row * 32;
      f4_t Bv[4];
#pragma unroll
      for (int nq = 0; nq < 4; ++nq) Bv[nq] = *(const f4_t*)(bp + nq * 4);
      float du = dlt * uv;
      float e1 = __expf(dlt * Av0);
      float a = e1;
      Sd += dlt;
#pragma unroll
      for (int n = 0; n < 16; ++n) {
        Qr[n >> 2][n & 3] = a * Qr[n >> 2][n & 3] + du * Bv[n >> 2][n & 3];
        a *= e1;
      }
    }
  } else {
#pragma unroll 2
    for (int i = 0; i < 32; ++i) {
      size_t row = (size_t)(row0 + i);
      float dlt = b2f(delta_bf[row * 2048 + d]);
      float uv  = b2f(ub[row * 2048 + d]);
      const float* bp = bc + row * 32;
      f4_t Bv[4];
#pragma unroll
      for (int nq = 0; nq < 4; ++nq) Bv[nq] = *(const f4_t*)(bp + nq * 4);
      float du = dlt * uv;
      Sd += dlt;
#pragma unroll
      for (int n = 0; n < 16; ++n) {
        float a = __expf(dlt * Av[n]);
        Qr[n >> 2][n & 3] = a * Qr[n >> 2][n & 3] + du * Bv[n >> 2][n & 3];
      }
    }
  }
  S[(size_t)(b * 64 + c) * 2048 + d] = f2b(Sd);
  size_t o = ((size_t)((b * 64 + c) * 2048 + d)) * 16;
#pragma unroll
  for (int nq = 0; nq < 4; ++nq)
    *(f4_t*)(Q + o + nq * 4) = Qr[nq];
}

// S2: serial prefix over 64 chunks per (b,d,n)
__global__ __launch_bounds__(256)
void scan_comb(const u16* __restrict__ S16, float* __restrict__ Q,
               const float* __restrict__ alog)
{
  int idx = blockIdx.x * 256 + threadIdx.x;   // b*32768 + d*16+n
  int b = idx >> 15, dn = idx & 32767;
  int d = dn >> 4;
  float Av = -__expf(alog[dn]);
  size_t qbase = (size_t)b * 2097152 + dn;
  size_t sbase = (size_t)b * 131072 + d;
  float H = 0.f;
#pragma unroll
  for (int cg = 0; cg < 4; ++cg) {
    float sv[16], qv[16];
#pragma unroll
    for (int j = 0; j < 16; ++j) {
      int c = cg * 16 + j;
      qv[j] = Q[qbase + (size_t)c * 32768];
      sv[j] = b2f(S16[sbase + (size_t)c * 2048]);
    }
#pragma unroll
    for (int j = 0; j < 16; ++j) {
      int c = cg * 16 + j;
      Q[qbase + (size_t)c * 32768] = H;
      H = __expf(Av * sv[j]) * H + qv[j];
    }
  }
}

// S3: re-scan with correct h_in; fused D-skip + silu(z) gate; y overwrites z
__global__ __launch_bounds__(256)
void scan_s3(const u16* __restrict__ delta_bf, const u16* __restrict__ ub,
             const float* __restrict__ bc, const float* __restrict__ alog,
             const float* __restrict__ Q, const float* __restrict__ Dw,
             u16* __restrict__ zy)
{
  int blk = blockIdx.x;                // 1024 blocks
  int g = blk & 7, c = (blk >> 3) & 63, b = blk >> 9;
  int d = g * 256 + threadIdx.x;
  float Av[16];
#pragma unroll
  for (int nq = 0; nq < 4; ++nq) {
    f4_t al = *(const f4_t*)(alog + (size_t)d * 16 + nq * 4);
#pragma unroll
    for (int j = 0; j < 4; ++j) Av[nq * 4 + j] = -__expf(al[j]);
  }
  float Av0 = Av[0];
  bool st = true;
#pragma unroll
  for (int n = 1; n < 16; ++n)
    st = st && (fabsf(Av[n] - (float)(n + 1) * Av0) <= 1e-3f * (float)(n + 1));
  f4_t h4[4];
  size_t o = ((size_t)((b * 64 + c) * 2048 + d)) * 16;
#pragma unroll
  for (int nq = 0; nq < 4; ++nq) h4[nq] = *(const f4_t*)(Q + o + nq * 4);
  float Dv = Dw[d];
  int row0 = b * 2048 + c * 32;
  if (st) {
#pragma unroll 2
    for (int i = 0; i < 32; ++i) {
      size_t row = (size_t)(row0 + i);
      float dlt = b2f(delta_bf[row * 2048 + d]);
      float uv  = b2f(ub[row * 2048 + d]);
      const float* bp = bc + row * 32;
      f4_t Bv[4], Cv[4];
#pragma unroll
      for (int nq = 0; nq < 4; ++nq) { Bv[nq] = *(const f4_t*)(bp + nq * 4); Cv[nq] = *(const f4_t*)(bp + 16 + nq * 4); }
      float du = dlt * uv;
      float e1 = __expf(dlt * Av0);
      float a = e1;
      float y = 0.f;
#pragma unroll
      for (int n = 0; n < 16; ++n) {
        float hn = a * h4[n >> 2][n & 3] + du * Bv[n >> 2][n & 3];
        h4[n >> 2][n & 3] = hn;
        y += hn * Cv[n >> 2][n & 3];
        a *= e1;
      }
      float zv = b2f(zy[row * 2048 + d]);
      float ov = (y + Dv * uv) * (zv / (1.f + __expf(-zv)));
      zy[row * 2048 + d] = f2b(ov);
    }
  } else {
#pragma unroll 2
    for (int i = 0; i < 32; ++i) {
      size_t row = (size_t)(row0 + i);
      float dlt = b2f(delta_bf[row * 2048 + d]);
      float uv  = b2f(ub[row * 2048 + d]);
      const float* bp = bc + row * 32;
      f4_t Bv[4], Cv[4];
#pragma unroll
      for (int nq = 0; nq < 4; ++nq) { Bv[nq] = *(const f4_t*)(bp + nq * 4); Cv[nq] = *(const f4_t*)(bp + 16 + nq * 4); }
      float du = dlt * uv;
      float y = 0.f;
#pragma unroll
      for (int n = 0; n < 16; ++n) {
        float a = __expf(dlt * Av[n]);
        float hn = a * h4[n >> 2][n & 3] + du * Bv[n >> 2][n & 3];
        h4[n >> 2][n & 3] = hn;
        y += hn * Cv[n >> 2][n & 3];
      }
      float zv = b2f(zy[row * 2048 + d]);
      float ov = (y + Dv * uv) * (zv / (1.f + __expf(-zv)));
      zy[row * 2048 + d] = f2b(ov);
    }
  }
}

// residual + LayerNorm over single out_proj result y (f32) + residual x.
// In-place safe: y may alias outp (each thread reads then writes its 4 floats).
__global__ __launch_bounds__(256)
void ln_kernel(const float* __restrict__ yv, const float* __restrict__ xin,
               const float* __restrict__ lnw, const float* __restrict__ lnb,
               float* __restrict__ outp)
{
  __shared__ float ssum[4], ssq[4];
  int row = blockIdx.x, t = threadIdx.x;
  f4_t h0 = *(const f4_t*)(yv + (size_t)row * 1024 + t * 4);
  f4_t xv = *(const f4_t*)(xin + (size_t)row * 1024 + t * 4);
  float v[4], s = 0.f, q = 0.f;
#pragma unroll
  for (int j = 0; j < 4; ++j) { v[j] = h0[j] + xv[j]; s += v[j]; q += v[j] * v[j]; }
#pragma unroll
  for (int m = 32; m; m >>= 1) { s += __shfl_xor(s, m, 64); q += __shfl_xor(q, m, 64); }
  int wv = t >> 6;
  if ((t & 63) == 0) { ssum[wv] = s; ssq[wv] = q; }
  __syncthreads();
  s = ssum[0] + ssum[1] + ssum[2] + ssum[3];
  q = ssq[0] + ssq[1] + ssq[2] + ssq[3];
  float mu = s * (1.f / 1024.f);
  float var = q * (1.f / 1024.f) - mu * mu;
  float rs = rsqrtf(var + 1e-5f);
  f4_t o;
#pragma unroll
  for (int j = 0; j < 4; ++j)
    o[j] = (v[j] - mu) * rs * lnw[t * 4 + j] + lnb[t * 4 + j];
  *(f4_t*)(outp + (size_t)row * 1024 + t * 4) = o;
}

extern "C" void kernel_launch(void* const* d_in, const int* in_sizes, int n_in,
                              void* d_out, int out_size, void* d_ws, size_t ws_size,
                              hipStream_t stream)
{
  const float* x      = (const float*)d_in[0];   // [2,2048,1024]
  const float* inW    = (const float*)d_in[1];   // [4096,1024]
  const float* convW  = (const float*)d_in[2];   // [2048,1,4]
  const float* convB  = (const float*)d_in[3];   // [2048]
  const float* xprojW = (const float*)d_in[4];   // [96,2048]
  const float* dtW    = (const float*)d_in[5];   // [2048,64]
  const float* dtB    = (const float*)d_in[6];   // [2048]
  const float* alog   = (const float*)d_in[7];   // [2048,16]
  const float* Dw     = (const float*)d_in[8];   // [2048]
  const float* outW   = (const float*)d_in[9];   // [1024,2048]
  const float* lnw    = (const float*)d_in[10];  // [1024]
  const float* lnb    = (const float*)d_in[11];  // [1024]
  float* out = (float*)d_out;                    // [2,2048,1024] f32 (16 MiB)

  char* ws = (char*)d_ws;
  u16*   xiz    = (u16*)(ws);
  u16*   zy     = xiz + 8388608;
  u16*   xb     = (u16*)(ws + 33554432);
  u16*   inWb   = xb + 4194304;
  u16*   u_bf   = (u16*)(ws + 33554432);          // overwrites xb/inWb after gemm8_in
  u16*   dtA    = (u16*)(ws + 50331648);
  float* bc     = (float*)(ws + 50855936);
  u16*   xprojWb= (u16*)(ws + 51380224);
  u16*   dtWb   = (u16*)(ws + 51773440);
  u16*   outWb  = (u16*)(ws + 52035584);
  u16*   delta  = xiz;                            // overwrites dead xi
  float* xpart  = (float*)d_out;                  // x_proj partials [8][4096][96]
  u16*   Sbuf   = dtA;                            // S (dtA dead after gemm_dt)
  float* Qbuf   = (float*)d_out;                  // Q fills d_out exactly (16.78 MB)
  float* yout   = (float*)d_out;                  // out_proj y (Q dead after s3)

  dim3 blk(256);
  // fused f32 -> bf16 conversions (one launch)
  cvt_all<<<10560, blk, 0, stream>>>(x, inW, xprojW, dtW, outW,
                                     xb, inWb, xprojWb, dtWb, outWb);
  // in_proj: [4096,1024] x [4096,1024]^T -> xi | z (bf16); 8-phase 256^2 (R2)
  gemm8_in<<<dim3(16, 16), dim3(512), 0, stream>>>(xb, inWb, xiz);
  // depthwise causal conv + silu -> u (bf16; overwrites xb/inWb)
  conv_silu<<<4096, blk, 0, stream>>>(xiz, convW, convB, u_bf);
  // x_proj split-K (8 x 256): partials into d_out
  gemm_xp<<<dim3(8, 32), blk, 0, stream>>>(u_bf, 2048, xprojWb, 2048, 256, 96, nullptr, xpart, nullptr);
  xproj_reduce<<<1536, blk, 0, stream>>>(xpart, dtA, bc);
  // dt_proj + softplus -> delta (bf16, overwrites xi)
  gemm_dt<<<dim3(16, 32), blk, 0, stream>>>(dtA, 64, dtWb, 64, 64, 2048, delta, nullptr, dtB);
  // chunk-parallel scan (64 chunks x 32 steps): S1 -> combine -> S3
  scan_s1<<<1024, blk, 0, stream>>>(delta, u_bf, bc, alog, Sbuf, Qbuf);
  scan_comb<<<256, blk, 0, stream>>>(Sbuf, Qbuf, alog);
  scan_s3<<<1024, blk, 0, stream>>>(delta, u_bf, bc, alog, Qbuf, Dw, zy);
  // out_proj single-K 4-phase 128x128: y f32 -> d_out (Q dead)
  gemm4_out<<<dim3(8, 32), dim3(512), 0, stream>>>(zy, outWb, yout);
  // residual + LayerNorm -> f32 out (in place over y)
  ln_kernel<<<4096, blk, 0, stream>>>(yout, x, lnw, lnb, out);
}

// Round 6
// 298.612 us; speedup vs baseline: 1.0605x; 1.0218x over previous
//
#include <hip/hip_runtime.h>

typedef unsigned short u16;
typedef __attribute__((ext_vector_type(8))) short bf8_t;    // 8 x bf16 (4 VGPRs)
typedef __attribute__((ext_vector_type(4))) float f4_t;     // 4 x f32
typedef __attribute__((ext_vector_type(4))) unsigned short u16x4;
typedef __attribute__((ext_vector_type(8))) unsigned short u16x8;

__device__ __forceinline__ float b2f(u16 h) {
  union { unsigned u; float f; } v; v.u = ((unsigned)h) << 16; return v.f;
}
__device__ __forceinline__ u16 f2b(float f) {
  union { float f; unsigned u; } v; v.f = f;
  unsigned u = v.u;
  u += 0x7fffu + ((u >> 16) & 1u);   // round-nearest-even
  return (u16)(u >> 16);
}

#define AS1C(p) ((const __attribute__((address_space(1))) void*)(p))
#define AS3(p)  ((__attribute__((address_space(3))) void*)(p))

// one fused f32 -> bf16 convert over all 5 weight/input arrays
__global__ __launch_bounds__(256)
void cvt_all(const float* __restrict__ x, const float* __restrict__ inW,
             const float* __restrict__ xprojW, const float* __restrict__ dtW,
             const float* __restrict__ outW,
             u16* __restrict__ xb, u16* __restrict__ inWb, u16* __restrict__ xpb,
             u16* __restrict__ dtWb, u16* __restrict__ outWb)
{
  int i = blockIdx.x * 256 + threadIdx.x;      // float4 index, total 2703360
  if (i >= 2703360) return;
  const float* s; u16* d; int off;
  if (i < 1048576)      { s = x;      d = xb;    off = i; }
  else if (i < 2097152) { s = inW;    d = inWb;  off = i - 1048576; }
  else if (i < 2146304) { s = xprojW; d = xpb;   off = i - 2097152; }
  else if (i < 2179072) { s = dtW;    d = dtWb;  off = i - 2146304; }
  else                  { s = outW;   d = outWb; off = i - 2179072; }
  f4_t v = *(const f4_t*)(s + (size_t)off * 4);
  u16x4 o;
#pragma unroll
  for (int j = 0; j < 4; ++j) o[j] = f2b(v[j]);
  *(u16x4*)(d + (size_t)off * 4) = o;
}

// Stage one 128x64 bf16 tile (16 KB) into LDS, XOR-swizzled: granule (r,q)
// holds global colchunk q^(r&7). Staging lane i (chunk of 8 rows) fetches
// colchunk (i&7)^((i>>3)&7); reader uses granule (g ^ (row&7)). Bank-quad
// depends only on q_l -> 8 lanes per 4-bank group = 2/bank = conflict-free.
__device__ __forceinline__ void stage64(const u16* g, int ld, int row0, int rowmax,
                                        int k0, u16* lds, int wid, int lane) {
  int qg = (lane & 7) ^ ((lane >> 3) & 7);
#pragma unroll
  for (int c = 0; c < 4; ++c) {
    int chunk = wid * 4 + c;
    int r = row0 + chunk * 8 + (lane >> 3);
    if (r > rowmax) r = rowmax;                       // clamp (results discarded later)
    const u16* gp = g + (size_t)r * ld + k0 + qg * 8;
    __builtin_amdgcn_global_load_lds(AS1C(gp), AS3(lds + chunk * 512), 16, 0, 0);
  }
}

// C = A * Bt^T : A[M,K] bf16 row-major (lda), Bt[N,K] bf16 row-major (ldb).
// BK=64 (two 32-k half-steps per barrier epoch).
// EPI 1: x_proj   -> split-K partials: of32[(bx*4096+m)*96+n], n<96
// EPI 2: dt_proj  -> o16[m*2048+n] = bf16(softplus(acc + biasf[n]))
template<int EPI>
__device__ __forceinline__ void gemm_body(const u16* __restrict__ A, int lda,
             const u16* __restrict__ Bt, int ldb,
             int Kblk, int Nact,
             u16* __restrict__ o16, float* __restrict__ of32,
             const float* __restrict__ biasf)
{
  __shared__ u16 lsA[128 * 64];
  __shared__ u16 lsB[128 * 64];
  const int tid = threadIdx.x;
  const int wid = tid >> 6, lane = tid & 63;
  const int wm = wid >> 1, wn = wid & 1;          // 2x2 wave grid, 64x64 each
  const int lrow = lane & 15;
  const int kq = lane >> 4;                       // 0..3
  const int sw = lrow & 7;                        // swizzle key
  const int m0 = blockIdx.y * 128;
  const int n0 = (EPI == 1) ? 0 : blockIdx.x * 128;
  int kbase = 0;
  if (EPI == 1) kbase = blockIdx.x * Kblk;

  f4_t acc[4][4];
#pragma unroll
  for (int i = 0; i < 4; ++i)
#pragma unroll
    for (int j = 0; j < 4; ++j) acc[i][j] = {0.f, 0.f, 0.f, 0.f};

  for (int kt = kbase; kt < kbase + Kblk; kt += 64) {
    stage64(A,  lda, m0, 0x3fffffff, kt, lsA, wid, lane);
    stage64(Bt, ldb, n0, Nact - 1,   kt, lsB, wid, lane);
    __syncthreads();
#pragma unroll
    for (int h = 0; h < 2; ++h) {
      const int lk = ((h * 4 + kq) ^ sw) * 8;
      bf8_t af[4], bfr[4];
#pragma unroll
      for (int mi = 0; mi < 4; ++mi)
        af[mi] = *(const bf8_t*)&lsA[(wm * 64 + mi * 16 + lrow) * 64 + lk];
#pragma unroll
      for (int ni = 0; ni < 4; ++ni)
        bfr[ni] = *(const bf8_t*)&lsB[(wn * 64 + ni * 16 + lrow) * 64 + lk];
#pragma unroll
      for (int mi = 0; mi < 4; ++mi)
#pragma unroll
        for (int ni = 0; ni < 4; ++ni)
          acc[mi][ni] = __builtin_amdgcn_mfma_f32_16x16x32_bf16(af[mi], bfr[ni], acc[mi][ni], 0, 0, 0);
    }
    __syncthreads();
  }

  const int rq = (lane >> 4) * 4;                  // C/D: row=(lane>>4)*4+r, col=lane&15
#pragma unroll
  for (int mi = 0; mi < 4; ++mi) {
#pragma unroll
    for (int ni = 0; ni < 4; ++ni) {
#pragma unroll
      for (int r = 0; r < 4; ++r) {
        int m = m0 + wm * 64 + mi * 16 + rq + r;
        int n = n0 + wn * 64 + ni * 16 + lrow;
        float v = acc[mi][ni][r];
        if (EPI == 1) {
          if (n < 96) of32[((size_t)blockIdx.x * 4096 + m) * 96 + n] = v;
        } else if (EPI == 2) {
          float t = v + biasf[n];
          float sp = (t > 20.f) ? t : log1pf(__expf(t));
          o16[(size_t)m * 2048 + n] = f2b(sp);
        }
      }
    }
  }
}

__global__ __launch_bounds__(256)
void gemm_xp(const u16* A, int lda, const u16* Bt, int ldb, int Kblk, int Nact,
             u16* o16, float* of32, const float* biasf)
{ gemm_body<1>(A, lda, Bt, ldb, Kblk, Nact, o16, of32, biasf); }

__global__ __launch_bounds__(256)
void gemm_dt(const u16* A, int lda, const u16* Bt, int ldb, int Kblk, int Nact,
             u16* o16, float* of32, const float* biasf)
{ gemm_body<2>(A, lda, Bt, ldb, Kblk, Nact, o16, of32, biasf); }

// ---------------------------------------------------------------------------
// 8-phase 256x256 bf16 GEMM for in_proj (M=N=4096, K=1024): verified R1/R2
// (42.1-42.3 us, 826 TF). Structure ceiling analysis (R5): acc[8][4]=128 f32
// -> ~256 unified regs/wave -> hard 1 block/CU; 128^2 tiles would be LDS-BW
// bound (~38 us); intra-block schedule perturbations null (R3/R4). Final.
// ---------------------------------------------------------------------------

// stage one 128x64 unit: 512 threads x 2 x 16B gload_lds. granule g = j*512 +
// wid*64 + lane -> lds row g>>3, slot g&7, global colchunk (g&7)^((g>>3)&7).
__device__ __forceinline__ void stageu(const u16* __restrict__ g, int ld,
                                       int row0, int k0, u16* ldsu,
                                       int wid, int lane) {
  int qg = (lane & 7) ^ ((lane >> 3) & 7);
#pragma unroll
  for (int j = 0; j < 2; ++j) {
    int rr = j * 64 + wid * 8 + (lane >> 3);
    const u16* gp = g + (size_t)(row0 + rr) * ld + k0 + qg * 8;
    __builtin_amdgcn_global_load_lds(AS1C(gp), AS3(ldsu + (j * 512 + wid * 64) * 8), 16, 0, 0);
  }
}

#define G8_BAR()   __builtin_amdgcn_s_barrier()
#define G8_LGKM0() do { asm volatile("s_waitcnt lgkmcnt(0)" ::: "memory"); \
                        __builtin_amdgcn_sched_barrier(0); } while (0)
#define G8_LGKM8() asm volatile("s_waitcnt lgkmcnt(8)" ::: "memory")
#define G8_VM(N)   do { asm volatile("s_waitcnt vmcnt(" #N ")" ::: "memory"); \
                        __builtin_amdgcn_sched_barrier(0); } while (0)

#define RD_A(base, MH) do { \
  _Pragma("unroll") \
  for (int mi_ = 0; mi_ < 4; ++mi_) { \
    af[mi_][0] = *(const bf8_t*)((base) + arow + ((MH) * 64 + mi_ * 16) * 64 + aq0); \
    af[mi_][1] = *(const bf8_t*)((base) + arow + ((MH) * 64 + mi_ * 16) * 64 + aq1); \
  } } while (0)

#define RD_B(base, NH) do { \
  _Pragma("unroll") \
  for (int ni_ = 0; ni_ < 2; ++ni_) { \
    bfr[NH][ni_][0] = *(const bf8_t*)((base) + brow + ((NH) * 32 + ni_ * 16) * 64 + aq0); \
    bfr[NH][ni_][1] = *(const bf8_t*)((base) + brow + ((NH) * 32 + ni_ * 16) * 64 + aq1); \
  } } while (0)

#define MMA(MH, NH) do { \
  __builtin_amdgcn_s_setprio(1); \
  _Pragma("unroll") \
  for (int mi_ = 0; mi_ < 4; ++mi_) \
    _Pragma("unroll") \
    for (int ni_ = 0; ni_ < 2; ++ni_) { \
      acc[(MH) * 4 + mi_][(NH) * 2 + ni_] = __builtin_amdgcn_mfma_f32_16x16x32_bf16( \
          af[mi_][0], bfr[NH][ni_][0], acc[(MH) * 4 + mi_][(NH) * 2 + ni_], 0, 0, 0); \
      acc[(MH) * 4 + mi_][(NH) * 2 + ni_] = __builtin_amdgcn_mfma_f32_16x16x32_bf16( \
          af[mi_][1], bfr[NH][ni_][1], acc[(MH) * 4 + mi_][(NH) * 2 + ni_], 0, 0, 0); \
    } \
  __builtin_amdgcn_s_setprio(0); \
} while (0)

__global__ __launch_bounds__(512, 2)
void gemm8_in(const u16* __restrict__ A, const u16* __restrict__ Bt,
              u16* __restrict__ o16)
{
  __shared__ u16 ls[65536];                       // 128 KB: 2 buf x (A 32K + B 32K)
  const int tid = threadIdx.x;
  const int wid = tid >> 6, lane = tid & 63;
  const int wm = wid >> 2, wn = wid & 3;          // 2x4 wave grid, 128x64 per wave
  const int lrow = lane & 15;
  const int kq = lane >> 4;
  const int sw = lrow & 7;
  const int m0 = blockIdx.y * 256;
  const int n0 = blockIdx.x * 256;
  u16* lsA0 = ls;
  u16* lsB0 = ls + 16384;
  u16* lsA1 = ls + 32768;
  u16* lsB1 = ls + 49152;
  const int arow = (wm * 128 + lrow) * 64;
  const int brow = (wn * 64 + lrow) * 64;
  const int aq0 = (kq ^ sw) * 8;
  const int aq1 = ((4 + kq) ^ sw) * 8;

  f4_t acc[8][4];
#pragma unroll
  for (int i = 0; i < 8; ++i)
#pragma unroll
    for (int j = 0; j < 4; ++j) acc[i][j] = {0.f, 0.f, 0.f, 0.f};
  bf8_t af[4][2];
  bf8_t bfr[2][2][2];

  // prologue: tile0 (A0,A1,B0,B1)->buf0, tile1 (B0,B1)->buf1; keep 4 in flight
  stageu(A,  1024, m0,        0, lsA0,        wid, lane);
  stageu(A,  1024, m0 + 128,  0, lsA0 + 8192, wid, lane);
  stageu(Bt, 1024, n0,        0, lsB0,        wid, lane);
  stageu(Bt, 1024, n0 + 128,  0, lsB0 + 8192, wid, lane);
  stageu(Bt, 1024, n0,       64, lsB1,        wid, lane);
  stageu(Bt, 1024, n0 + 128, 64, lsB1 + 8192, wid, lane);
  G8_VM(4); G8_BAR();

#pragma unroll 1
  for (int i = 0; i < 7; ++i) {                   // iterations 0..6 (tiles 0..13)
    const int k1 = (2 * i + 1) * 64, k2 = k1 + 64, k3 = k1 + 128;
    // P1: read buf0 A-half0 + B-half0; stage (t+1).A0 -> buf1
    RD_A(lsA0, 0); RD_B(lsB0, 0);
    stageu(A, 1024, m0, k1, lsA1, wid, lane);
    G8_LGKM8(); G8_BAR(); G8_LGKM0(); MMA(0, 0); G8_BAR();
    // P2: read buf0 B-half1; stage (t+1).A1 -> buf1
    RD_B(lsB0, 1);
    stageu(A, 1024, m0 + 128, k1, lsA1 + 8192, wid, lane);
    G8_BAR(); G8_LGKM0(); MMA(0, 1); G8_BAR();
    // P3: read buf0 A-half1; stage (t+2).B0 -> buf0 (B reads done end P2)
    RD_A(lsA0, 1);
    stageu(Bt, 1024, n0, k2, lsB0, wid, lane);
    G8_BAR(); G8_LGKM0(); MMA(1, 0); G8_BAR();
    // P4: stage (t+2).B1 -> buf0; counted vmcnt -> tile t+1 landed
    stageu(Bt, 1024, n0 + 128, k2, lsB0 + 8192, wid, lane);
    G8_BAR(); G8_LGKM0(); MMA(1, 1); G8_VM(4); G8_BAR();
    // P5: read buf1 A-half0 + B-half0; stage (t+2).A0 -> buf0 (A reads done end P3)
    RD_A(lsA1, 0); RD_B(lsB1, 0);
    stageu(A, 1024, m0, k2, lsA0, wid, lane);
    G8_LGKM8(); G8_BAR(); G8_LGKM0(); MMA(0, 0); G8_BAR();
    // P6: read buf1 B-half1; stage (t+2).A1 -> buf0
    RD_B(lsB1, 1);
    stageu(A, 1024, m0 + 128, k2, lsA0 + 8192, wid, lane);
    G8_BAR(); G8_LGKM0(); MMA(0, 1); G8_BAR();
    // P7: read buf1 A-half1; stage (t+3).B0 -> buf1
    RD_A(lsA1, 1);
    stageu(Bt, 1024, n0, k3, lsB1, wid, lane);
    G8_BAR(); G8_LGKM0(); MMA(1, 0); G8_BAR();
    // P8: stage (t+3).B1 -> buf1; counted vmcnt -> tile t+2 landed
    stageu(Bt, 1024, n0 + 128, k3, lsB1 + 8192, wid, lane);
    G8_BAR(); G8_LGKM0(); MMA(1, 1); G8_VM(4); G8_BAR();
  }

  {                                               // last iteration: tiles 14,15
    const int k1 = 960;
    RD_A(lsA0, 0); RD_B(lsB0, 0);
    stageu(A, 1024, m0, k1, lsA1, wid, lane);
    G8_LGKM8(); G8_BAR(); G8_LGKM0(); MMA(0, 0); G8_BAR();
    RD_B(lsB0, 1);
    stageu(A, 1024, m0 + 128, k1, lsA1 + 8192, wid, lane);
    G8_BAR(); G8_LGKM0(); MMA(0, 1); G8_BAR();
    RD_A(lsA0, 1);
    G8_BAR(); G8_LGKM0(); MMA(1, 0); G8_BAR();
    G8_BAR(); G8_LGKM0(); MMA(1, 1); G8_VM(0); G8_BAR();
    RD_A(lsA1, 0); RD_B(lsB1, 0);
    G8_BAR(); G8_LGKM0(); MMA(0, 0); G8_BAR();
    RD_B(lsB1, 1);
    G8_BAR(); G8_LGKM0(); MMA(0, 1); G8_BAR();
    RD_A(lsA1, 1);
    G8_BAR(); G8_LGKM0(); MMA(1, 0); G8_BAR();
    G8_LGKM0(); MMA(1, 1);
  }

  // epilogue: xi (n<2048) | z (n>=2048, at o16+8M)
  const int rq = (lane >> 4) * 4;
#pragma unroll
  for (int mi = 0; mi < 8; ++mi) {
#pragma unroll
    for (int ni = 0; ni < 4; ++ni) {
#pragma unroll
      for (int r = 0; r < 4; ++r) {
        int m = m0 + wm * 128 + mi * 16 + rq + r;
        int n = n0 + wn * 64 + ni * 16 + lrow;
        float v = acc[mi][ni][r];
        if (n < 2048) o16[(size_t)m * 2048 + n] = f2b(v);
        else          o16[(size_t)8388608 + (size_t)m * 2048 + (n - 2048)] = f2b(v);
      }
    }
  }
}

// ---------------------------------------------------------------------------
// out_proj single-K 4-phase GEMM (verified R5). Tile 128M x 128N, K=2048,
// grid (8,32) = 256 blocks. NEW R6: fused residual add — epilogue writes
// h = y + x (f32), so ln_kernel no longer reads x (saves 16.8 MB).
// ---------------------------------------------------------------------------

#define O4_RD_A(base, KH) do { \
  _Pragma("unroll") \
  for (int mi_ = 0; mi_ < 4; ++mi_) \
    af4[mi_][KH] = *(const bf8_t*)((base) + arow + mi_ * 1024 + ((KH) ? aq1 : aq0)); \
  } while (0)

#define O4_RD_B(base) do { \
  _Pragma("unroll") \
  for (int ni_ = 0; ni_ < 2; ++ni_) { \
    bf4[ni_][0] = *(const bf8_t*)((base) + brow + ni_ * 1024 + aq0); \
    bf4[ni_][1] = *(const bf8_t*)((base) + brow + ni_ * 1024 + aq1); \
  } } while (0)

#define O4_MMA(KH) do { \
  __builtin_amdgcn_s_setprio(1); \
  _Pragma("unroll") \
  for (int mi_ = 0; mi_ < 4; ++mi_) \
    _Pragma("unroll") \
    for (int ni_ = 0; ni_ < 2; ++ni_) \
      acc[mi_][ni_] = __builtin_amdgcn_mfma_f32_16x16x32_bf16( \
          af4[mi_][KH], bf4[ni_][KH], acc[mi_][ni_], 0, 0, 0); \
  __builtin_amdgcn_s_setprio(0); \
} while (0)

__global__ __launch_bounds__(512, 2)
void gemm4_out(const u16* __restrict__ A, const u16* __restrict__ Bt,
               const float* __restrict__ xres, float* __restrict__ yout)
{
  __shared__ u16 ls[32768];                       // 64 KB: 2 buf x (A 16K + B 16K)
  const int tid = threadIdx.x;
  const int wid = tid >> 6, lane = tid & 63;
  const int wm = wid >> 2, wn = wid & 3;          // 2Mx4N, 64x32 per wave
  const int lrow = lane & 15;
  const int kq = lane >> 4;
  const int sw = lrow & 7;
  const int m0 = blockIdx.y * 128;
  const int n0 = blockIdx.x * 128;
  u16* lsA0 = ls;                                 // 8192 u16 = 128x64
  u16* lsB0 = ls + 8192;
  u16* lsA1 = ls + 16384;
  u16* lsB1 = ls + 24576;
  const int arow = (wm * 64 + lrow) * 64;
  const int brow = (wn * 32 + lrow) * 64;
  const int aq0 = (kq ^ sw) * 8;
  const int aq1 = ((4 + kq) ^ sw) * 8;

  f4_t acc[4][2];
#pragma unroll
  for (int i = 0; i < 4; ++i)
#pragma unroll
    for (int j = 0; j < 2; ++j) acc[i][j] = {0.f, 0.f, 0.f, 0.f};
  bf8_t af4[4][2];
  bf8_t bf4[2][2];

  // prologue: tile0 (A,B)->buf0, tile1 B->buf1
  stageu(A,  2048, m0,  0, lsA0, wid, lane);
  stageu(Bt, 2048, n0,  0, lsB0, wid, lane);
  stageu(Bt, 2048, n0, 64, lsB1, wid, lane);
  G8_VM(2); G8_BAR();

#pragma unroll 1
  for (int i = 0; i < 15; ++i) {                  // tile pairs (0,1)..(28,29)
    const int ka1 = (2 * i + 1) * 64;             // A of odd tile t+1
    const int k2  = ka1 + 64;                     // tile t+2
    const int kb3 = ka1 + 128;                    // B of tile t+3
    // Q1: read buf0 {A-kh0, B both}; stage A(t+1)->buf1.A (sealed prev Q4)
    O4_RD_A(lsA0, 0); O4_RD_B(lsB0);
    stageu(A, 2048, m0, ka1, lsA1, wid, lane);
    G8_BAR(); G8_LGKM0(); O4_MMA(0); G8_BAR();
    // Q2: read buf0 A-kh1; stage B(t+2)->buf0.B (sealed end Q1)
    O4_RD_A(lsA0, 1);
    stageu(Bt, 2048, n0, k2, lsB0, wid, lane);
    G8_LGKM0(); O4_MMA(1); G8_VM(2); G8_BAR();
    // Q3: read buf1 {A-kh0, B both}; stage A(t+2)->buf0.A (sealed end Q2)
    O4_RD_A(lsA1, 0); O4_RD_B(lsB1);
    stageu(A, 2048, m0, k2, lsA0, wid, lane);
    G8_BAR(); G8_LGKM0(); O4_MMA(0); G8_BAR();
    // Q4: read buf1 A-kh1; stage B(t+3)->buf1.B (sealed end Q3)
    O4_RD_A(lsA1, 1);
    stageu(Bt, 2048, n0, kb3, lsB1, wid, lane);
    G8_LGKM0(); O4_MMA(1); G8_VM(2); G8_BAR();
  }

  {                                               // final: tiles 30, 31
    O4_RD_A(lsA0, 0); O4_RD_B(lsB0);
    stageu(A, 2048, m0, 1984, lsA1, wid, lane);   // A(31)
    G8_BAR(); G8_LGKM0(); O4_MMA(0); G8_BAR();
    O4_RD_A(lsA0, 1);
    G8_LGKM0(); O4_MMA(1); G8_VM(0); G8_BAR();    // drain A(31),B(31)
    O4_RD_A(lsA1, 0); O4_RD_B(lsB1);
    G8_LGKM0(); O4_MMA(0);
    O4_RD_A(lsA1, 1);
    G8_LGKM0(); O4_MMA(1);
  }

  const int rq = (lane >> 4) * 4;
#pragma unroll
  for (int mi = 0; mi < 4; ++mi) {
#pragma unroll
    for (int ni = 0; ni < 2; ++ni) {
#pragma unroll
      for (int r = 0; r < 4; ++r) {
        int m = m0 + wm * 64 + mi * 16 + rq + r;
        int n = n0 + wn * 32 + ni * 16 + lrow;
        yout[(size_t)m * 1024 + n] = acc[mi][ni][r] + xres[(size_t)m * 1024 + n];
      }
    }
  }
}

// reduce 8 split-K partials of x_proj; emit dtA bf16 [4096,64] + bc f32 [4096,32]
__global__ __launch_bounds__(256)
void xproj_reduce(const float* __restrict__ part, u16* __restrict__ dtA,
                  float* __restrict__ bc)
{
  int idx = blockIdx.x * 256 + threadIdx.x;   // 4096*96
  int m = idx / 96, n = idx - m * 96;
  float s = 0.f;
#pragma unroll
  for (int p = 0; p < 8; ++p) s += part[(size_t)p * 393216 + idx];
  if (n < 64) dtA[(size_t)m * 64 + n] = f2b(s);
  else        bc[(size_t)m * 32 + (n - 64)] = s;
}

// causal depthwise conv1d (window 4) + bias + silu; vectorized 8 channels/thread
__global__ __launch_bounds__(256)
void conv_silu(const u16* __restrict__ xib, const float* __restrict__ cw,
               const float* __restrict__ cb, u16* __restrict__ ub)
{
  int i = blockIdx.x * 256 + threadIdx.x;     // 1,048,576 threads
  int c8 = (i & 255) * 8;
  int row = i >> 8;                           // b*2048 + l
  int l = row & 2047;
  const u16* base = xib + (size_t)row * 2048 + c8;
  u16x8 x0 = {0,0,0,0,0,0,0,0}, x1 = x0, x2 = x0, x3;
  x3 = *(const u16x8*)(base);
  if (l >= 1) x2 = *(const u16x8*)(base - 2048);
  if (l >= 2) x1 = *(const u16x8*)(base - 2 * 2048);
  if (l >= 3) x0 = *(const u16x8*)(base - 3 * 2048);
  f4_t cb0 = *(const f4_t*)(cb + c8);
  f4_t cb1 = *(const f4_t*)(cb + c8 + 4);
  u16x8 o;
#pragma unroll
  for (int j = 0; j < 8; ++j) {
    f4_t w = *(const f4_t*)(cw + (size_t)(c8 + j) * 4);
    float a = (j < 4 ? cb0[j] : cb1[j - 4])
            + w[0] * b2f(x0[j]) + w[1] * b2f(x1[j])
            + w[2] * b2f(x2[j]) + w[3] * b2f(x3[j]);
    float s = a / (1.f + __expf(-a));
    o[j] = f2b(s);
  }
  *(u16x8*)(ub + (size_t)row * 2048 + c8) = o;
}

// ---- chunk-parallel scan, d-in-lane layout. 64 chunks x 32 steps. ----
// R6: Q stored as bf16 (halves Q traffic across s1/comb/s3: 67 -> 34 MB).
__global__ __launch_bounds__(256)
void scan_s1(const u16* __restrict__ delta_bf, const u16* __restrict__ ub,
             const float* __restrict__ bc, const float* __restrict__ alog,
             u16* __restrict__ S, u16* __restrict__ Q)
{
  int blk = blockIdx.x;                // 1024 blocks: b(1) x c(6) x g(3)
  int g = blk & 7, c = (blk >> 3) & 63, b = blk >> 9;
  int d = g * 256 + threadIdx.x;
  float Av[16];
#pragma unroll
  for (int nq = 0; nq < 4; ++nq) {
    f4_t al = *(const f4_t*)(alog + (size_t)d * 16 + nq * 4);
#pragma unroll
    for (int j = 0; j < 4; ++j) Av[nq * 4 + j] = -__expf(al[j]);
  }
  float Av0 = Av[0];
  bool st = true;
#pragma unroll
  for (int n = 1; n < 16; ++n)
    st = st && (fabsf(Av[n] - (float)(n + 1) * Av0) <= 1e-3f * (float)(n + 1));
  f4_t Qr[4];
#pragma unroll
  for (int nq = 0; nq < 4; ++nq) Qr[nq] = {0.f,0.f,0.f,0.f};
  float Sd = 0.f;
  int row0 = b * 2048 + c * 32;
  if (st) {
#pragma unroll 2
    for (int i = 0; i < 32; ++i) {
      size_t row = (size_t)(row0 + i);
      float dlt = b2f(delta_bf[row * 2048 + d]);
      float uv  = b2f(ub[row * 2048 + d]);
      const float* bp = bc + row * 32;
      f4_t Bv[4];
#pragma unroll
      for (int nq = 0; nq < 4; ++nq) Bv[nq] = *(const f4_t*)(bp + nq * 4);
      float du = dlt * uv;
      float e1 = __expf(dlt * Av0);
      float a = e1;
      Sd += dlt;
#pragma unroll
      for (int n = 0; n < 16; ++n) {
        Qr[n >> 2][n & 3] = a * Qr[n >> 2][n & 3] + du * Bv[n >> 2][n & 3];
        a *= e1;
      }
    }
  } else {
#pragma unroll 2
    for (int i = 0; i < 32; ++i) {
      size_t row = (size_t)(row0 + i);
      float dlt = b2f(delta_bf[row * 2048 + d]);
      float uv  = b2f(ub[row * 2048 + d]);
      const float* bp = bc + row * 32;
      f4_t Bv[4];
#pragma unroll
      for (int nq = 0; nq < 4; ++nq) Bv[nq] = *(const f4_t*)(bp + nq * 4);
      float du = dlt * uv;
      Sd += dlt;
#pragma unroll
      for (int n = 0; n < 16; ++n) {
        float a = __expf(dlt * Av[n]);
        Qr[n >> 2][n & 3] = a * Qr[n >> 2][n & 3] + du * Bv[n >> 2][n & 3];
      }
    }
  }
  S[(size_t)(b * 64 + c) * 2048 + d] = f2b(Sd);
  size_t o = ((size_t)((b * 64 + c) * 2048 + d)) * 16;
  u16x8 q0, q1;
#pragma unroll
  for (int j = 0; j < 8; ++j) { q0[j] = f2b(Qr[j >> 2][j & 3]); q1[j] = f2b(Qr[(j + 8) >> 2][j & 3]); }
  *(u16x8*)(Q + o)     = q0;
  *(u16x8*)(Q + o + 8) = q1;
}

// S2: serial prefix over 64 chunks per (b,d,n); Q bf16 in/out
__global__ __launch_bounds__(256)
void scan_comb(const u16* __restrict__ S16, u16* __restrict__ Q,
               const float* __restrict__ alog)
{
  int idx = blockIdx.x * 256 + threadIdx.x;   // b*32768 + d*16+n
  int b = idx >> 15, dn = idx & 32767;
  int d = dn >> 4;
  float Av = -__expf(alog[dn]);
  size_t qbase = (size_t)b * 2097152 + dn;
  size_t sbase = (size_t)b * 131072 + d;
  float H = 0.f;
#pragma unroll
  for (int cg = 0; cg < 4; ++cg) {
    float sv[16], qv[16];
#pragma unroll
    for (int j = 0; j < 16; ++j) {
      int c = cg * 16 + j;
      qv[j] = b2f(Q[qbase + (size_t)c * 32768]);
      sv[j] = b2f(S16[sbase + (size_t)c * 2048]);
    }
#pragma unroll
    for (int j = 0; j < 16; ++j) {
      int c = cg * 16 + j;
      Q[qbase + (size_t)c * 32768] = f2b(H);
      H = __expf(Av * sv[j]) * H + qv[j];
    }
  }
}

// S3: re-scan with correct h_in (bf16 Q); fused D-skip + silu(z) gate
__global__ __launch_bounds__(256)
void scan_s3(const u16* __restrict__ delta_bf, const u16* __restrict__ ub,
             const float* __restrict__ bc, const float* __restrict__ alog,
             const u16* __restrict__ Q, const float* __restrict__ Dw,
             u16* __restrict__ zy)
{
  int blk = blockIdx.x;                // 1024 blocks
  int g = blk & 7, c = (blk >> 3) & 63, b = blk >> 9;
  int d = g * 256 + threadIdx.x;
  float Av[16];
#pragma unroll
  for (int nq = 0; nq < 4; ++nq) {
    f4_t al = *(const f4_t*)(alog + (size_t)d * 16 + nq * 4);
#pragma unroll
    for (int j = 0; j < 4; ++j) Av[nq * 4 + j] = -__expf(al[j]);
  }
  float Av0 = Av[0];
  bool st = true;
#pragma unroll
  for (int n = 1; n < 16; ++n)
    st = st && (fabsf(Av[n] - (float)(n + 1) * Av0) <= 1e-3f * (float)(n + 1));
  f4_t h4[4];
  size_t o = ((size_t)((b * 64 + c) * 2048 + d)) * 16;
  {
    u16x8 q0 = *(const u16x8*)(Q + o);
    u16x8 q1 = *(const u16x8*)(Q + o + 8);
#pragma unroll
    for (int j = 0; j < 8; ++j) { h4[j >> 2][j & 3] = b2f(q0[j]); h4[(j + 8) >> 2][j & 3] = b2f(q1[j]); }
  }
  float Dv = Dw[d];
  int row0 = b * 2048 + c * 32;
  if (st) {
#pragma unroll 2
    for (int i = 0; i < 32; ++i) {
      size_t row = (size_t)(row0 + i);
      float dlt = b2f(delta_bf[row * 2048 + d]);
      float uv  = b2f(ub[row * 2048 + d]);
      const float* bp = bc + row * 32;
      f4_t Bv[4], Cv[4];
#pragma unroll
      for (int nq = 0; nq < 4; ++nq) { Bv[nq] = *(const f4_t*)(bp + nq * 4); Cv[nq] = *(const f4_t*)(bp + 16 + nq * 4); }
      float du = dlt * uv;
      float e1 = __expf(dlt * Av0);
      float a = e1;
      float y = 0.f;
#pragma unroll
      for (int n = 0; n < 16; ++n) {
        float hn = a * h4[n >> 2][n & 3] + du * Bv[n >> 2][n & 3];
        h4[n >> 2][n & 3] = hn;
        y += hn * Cv[n >> 2][n & 3];
        a *= e1;
      }
      float zv = b2f(zy[row * 2048 + d]);
      float ov = (y + Dv * uv) * (zv / (1.f + __expf(-zv)));
      zy[row * 2048 + d] = f2b(ov);
    }
  } else {
#pragma unroll 2
    for (int i = 0; i < 32; ++i) {
      size_t row = (size_t)(row0 + i);
      float dlt = b2f(delta_bf[row * 2048 + d]);
      float uv  = b2f(ub[row * 2048 + d]);
      const float* bp = bc + row * 32;
      f4_t Bv[4], Cv[4];
#pragma unroll
      for (int nq = 0; nq < 4; ++nq) { Bv[nq] = *(const f4_t*)(bp + nq * 4); Cv[nq] = *(const f4_t*)(bp + 16 + nq * 4); }
      float du = dlt * uv;
      float y = 0.f;
#pragma unroll
      for (int n = 0; n < 16; ++n) {
        float a = __expf(dlt * Av[n]);
        float hn = a * h4[n >> 2][n & 3] + du * Bv[n >> 2][n & 3];
        h4[n >> 2][n & 3] = hn;
        y += hn * Cv[n >> 2][n & 3];
      }
      float zv = b2f(zy[row * 2048 + d]);
      float ov = (y + Dv * uv) * (zv / (1.f + __expf(-zv)));
      zy[row * 2048 + d] = f2b(ov);
    }
  }
}

// LayerNorm over h = y + x (residual already added in gemm4_out epilogue).
// In-place safe: h aliases outp (each thread reads then writes its 4 floats).
__global__ __launch_bounds__(256)
void ln_kernel(const float* __restrict__ hv,
               const float* __restrict__ lnw, const float* __restrict__ lnb,
               float* __restrict__ outp)
{
  __shared__ float ssum[4], ssq[4];
  int row = blockIdx.x, t = threadIdx.x;
  f4_t v4 = *(const f4_t*)(hv + (size_t)row * 1024 + t * 4);
  float v[4], s = 0.f, q = 0.f;
#pragma unroll
  for (int j = 0; j < 4; ++j) { v[j] = v4[j]; s += v[j]; q += v[j] * v[j]; }
#pragma unroll
  for (int m = 32; m; m >>= 1) { s += __shfl_xor(s, m, 64); q += __shfl_xor(q, m, 64); }
  int wv = t >> 6;
  if ((t & 63) == 0) { ssum[wv] = s; ssq[wv] = q; }
  __syncthreads();
  s = ssum[0] + ssum[1] + ssum[2] + ssum[3];
  q = ssq[0] + ssq[1] + ssq[2] + ssq[3];
  float mu = s * (1.f / 1024.f);
  float var = q * (1.f / 1024.f) - mu * mu;
  float rs = rsqrtf(var + 1e-5f);
  f4_t o;
#pragma unroll
  for (int j = 0; j < 4; ++j)
    o[j] = (v[j] - mu) * rs * lnw[t * 4 + j] + lnb[t * 4 + j];
  *(f4_t*)(outp + (size_t)row * 1024 + t * 4) = o;
}

extern "C" void kernel_launch(void* const* d_in, const int* in_sizes, int n_in,
                              void* d_out, int out_size, void* d_ws, size_t ws_size,
                              hipStream_t stream)
{
  const float* x      = (const float*)d_in[0];   // [2,2048,1024]
  const float* inW    = (const float*)d_in[1];   // [4096,1024]
  const float* convW  = (const float*)d_in[2];   // [2048,1,4]
  const float* convB  = (const float*)d_in[3];   // [2048]
  const float* xprojW = (const float*)d_in[4];   // [96,2048]
  const float* dtW    = (const float*)d_in[5];   // [2048,64]
  const float* dtB    = (const float*)d_in[6];   // [2048]
  const float* alog   = (const float*)d_in[7];   // [2048,16]
  const float* Dw     = (const float*)d_in[8];   // [2048]
  const float* outW   = (const float*)d_in[9];   // [1024,2048]
  const float* lnw    = (const float*)d_in[10];  // [1024]
  const float* lnb    = (const float*)d_in[11];  // [1024]
  float* out = (float*)d_out;                    // [2,2048,1024] f32 (16 MiB)

  char* ws = (char*)d_ws;
  u16*   xiz    = (u16*)(ws);
  u16*   zy     = xiz + 8388608;
  u16*   xb     = (u16*)(ws + 33554432);
  u16*   inWb   = xb + 4194304;
  u16*   u_bf   = (u16*)(ws + 33554432);          // overwrites xb/inWb after gemm8_in
  u16*   dtA    = (u16*)(ws + 50331648);
  float* bc     = (float*)(ws + 50855936);
  u16*   xprojWb= (u16*)(ws + 51380224);
  u16*   dtWb   = (u16*)(ws + 51773440);
  u16*   outWb  = (u16*)(ws + 52035584);
  u16*   delta  = xiz;                            // overwrites dead xi
  float* xpart  = (float*)d_out;                  // x_proj partials [8][4096][96]
  u16*   Sbuf   = dtA;                            // S (dtA dead after gemm_dt)
  u16*   Qbuf   = (u16*)d_out;                    // Q bf16 [2,64,2048,16] = 8.39 MB
  float* yout   = (float*)d_out;                  // h = y+x (Q dead after s3)

  dim3 blk(256);
  // fused f32 -> bf16 conversions (one launch)
  cvt_all<<<10560, blk, 0, stream>>>(x, inW, xprojW, dtW, outW,
                                     xb, inWb, xprojWb, dtWb, outWb);
  // in_proj: [4096,1024] x [4096,1024]^T -> xi | z (bf16); 8-phase 256^2 (R2)
  gemm8_in<<<dim3(16, 16), dim3(512), 0, stream>>>(xb, inWb, xiz);
  // depthwise causal conv + silu -> u (bf16; overwrites xb/inWb)
  conv_silu<<<4096, blk, 0, stream>>>(xiz, convW, convB, u_bf);
  // x_proj split-K (8 x 256): partials into d_out
  gemm_xp<<<dim3(8, 32), blk, 0, stream>>>(u_bf, 2048, xprojWb, 2048, 256, 96, nullptr, xpart, nullptr);
  xproj_reduce<<<1536, blk, 0, stream>>>(xpart, dtA, bc);
  // dt_proj + softplus -> delta (bf16, overwrites xi)
  gemm_dt<<<dim3(16, 32), blk, 0, stream>>>(dtA, 64, dtWb, 64, 64, 2048, delta, nullptr, dtB);
  // chunk-parallel scan (64 chunks x 32 steps): S1 -> combine -> S3 (Q bf16)
  scan_s1<<<1024, blk, 0, stream>>>(delta, u_bf, bc, alog, Sbuf, Qbuf);
  scan_comb<<<256, blk, 0, stream>>>(Sbuf, Qbuf, alog);
  scan_s3<<<1024, blk, 0, stream>>>(delta, u_bf, bc, alog, Qbuf, Dw, zy);
  // out_proj single-K 4-phase 128x128 + fused residual: h = y+x -> d_out
  gemm4_out<<<dim3(8, 32), dim3(512), 0, stream>>>(zy, outWb, x, yout);
  // LayerNorm -> f32 out (in place over h)
  ln_kernel<<<4096, blk, 0, stream>>>(yout, lnw, lnb, out);
}

// Round 7
// 297.482 us; speedup vs baseline: 1.0646x; 1.0038x over previous
//
#include <hip/hip_runtime.h>

typedef unsigned short u16;
typedef __attribute__((ext_vector_type(8))) short bf8_t;    // 8 x bf16 (4 VGPRs)
typedef __attribute__((ext_vector_type(4))) float f4_t;     // 4 x f32
typedef __attribute__((ext_vector_type(4))) unsigned short u16x4;
typedef __attribute__((ext_vector_type(8))) unsigned short u16x8;

__device__ __forceinline__ float b2f(u16 h) {
  union { unsigned u; float f; } v; v.u = ((unsigned)h) << 16; return v.f;
}
__device__ __forceinline__ u16 f2b(float f) {
  union { float f; unsigned u; } v; v.f = f;
  unsigned u = v.u;
  u += 0x7fffu + ((u >> 16) & 1u);   // round-nearest-even
  return (u16)(u >> 16);
}

#define AS1C(p) ((const __attribute__((address_space(1))) void*)(p))
#define AS3(p)  ((__attribute__((address_space(3))) void*)(p))

// one fused f32 -> bf16 convert over all 5 weight/input arrays
__global__ __launch_bounds__(256)
void cvt_all(const float* __restrict__ x, const float* __restrict__ inW,
             const float* __restrict__ xprojW, const float* __restrict__ dtW,
             const float* __restrict__ outW,
             u16* __restrict__ xb, u16* __restrict__ inWb, u16* __restrict__ xpb,
             u16* __restrict__ dtWb, u16* __restrict__ outWb)
{
  int i = blockIdx.x * 256 + threadIdx.x;      // float4 index, total 2703360
  if (i >= 2703360) return;
  const float* s; u16* d; int off;
  if (i < 1048576)      { s = x;      d = xb;    off = i; }
  else if (i < 2097152) { s = inW;    d = inWb;  off = i - 1048576; }
  else if (i < 2146304) { s = xprojW; d = xpb;   off = i - 2097152; }
  else if (i < 2179072) { s = dtW;    d = dtWb;  off = i - 2146304; }
  else                  { s = outW;   d = outWb; off = i - 2179072; }
  f4_t v = *(const f4_t*)(s + (size_t)off * 4);
  u16x4 o;
#pragma unroll
  for (int j = 0; j < 4; ++j) o[j] = f2b(v[j]);
  *(u16x4*)(d + (size_t)off * 4) = o;
}

// Stage one 128x64 bf16 tile (16 KB) into LDS, XOR-swizzled: granule (r,q)
// holds global colchunk q^(r&7). Staging lane i (chunk of 8 rows) fetches
// colchunk (i&7)^((i>>3)&7); reader uses granule (g ^ (row&7)). Bank-quad
// depends only on q_l -> 8 lanes per 4-bank group = 2/bank = conflict-free.
__device__ __forceinline__ void stage64(const u16* g, int ld, int row0, int rowmax,
                                        int k0, u16* lds, int wid, int lane) {
  int qg = (lane & 7) ^ ((lane >> 3) & 7);
#pragma unroll
  for (int c = 0; c < 4; ++c) {
    int chunk = wid * 4 + c;
    int r = row0 + chunk * 8 + (lane >> 3);
    if (r > rowmax) r = rowmax;                       // clamp (results discarded later)
    const u16* gp = g + (size_t)r * ld + k0 + qg * 8;
    __builtin_amdgcn_global_load_lds(AS1C(gp), AS3(lds + chunk * 512), 16, 0, 0);
  }
}

// C = A * Bt^T : A[M,K] bf16 row-major (lda), Bt[N,K] bf16 row-major (ldb).
// BK=64 (two 32-k half-steps per barrier epoch).
// EPI 1: x_proj   -> split-K partials in BF16 (R7): o16[(bx*4096+m)*96+n], n<96
// EPI 2: dt_proj  -> o16[m*2048+n] = bf16(softplus(acc + biasf[n]))
template<int EPI>
__device__ __forceinline__ void gemm_body(const u16* __restrict__ A, int lda,
             const u16* __restrict__ Bt, int ldb,
             int Kblk, int Nact,
             u16* __restrict__ o16, const float* __restrict__ biasf)
{
  __shared__ u16 lsA[128 * 64];
  __shared__ u16 lsB[128 * 64];
  const int tid = threadIdx.x;
  const int wid = tid >> 6, lane = tid & 63;
  const int wm = wid >> 1, wn = wid & 1;          // 2x2 wave grid, 64x64 each
  const int lrow = lane & 15;
  const int kq = lane >> 4;                       // 0..3
  const int sw = lrow & 7;                        // swizzle key
  const int m0 = blockIdx.y * 128;
  const int n0 = (EPI == 1) ? 0 : blockIdx.x * 128;
  int kbase = 0;
  if (EPI == 1) kbase = blockIdx.x * Kblk;

  f4_t acc[4][4];
#pragma unroll
  for (int i = 0; i < 4; ++i)
#pragma unroll
    for (int j = 0; j < 4; ++j) acc[i][j] = {0.f, 0.f, 0.f, 0.f};

  for (int kt = kbase; kt < kbase + Kblk; kt += 64) {
    stage64(A,  lda, m0, 0x3fffffff, kt, lsA, wid, lane);
    stage64(Bt, ldb, n0, Nact - 1,   kt, lsB, wid, lane);
    __syncthreads();
#pragma unroll
    for (int h = 0; h < 2; ++h) {
      const int lk = ((h * 4 + kq) ^ sw) * 8;
      bf8_t af[4], bfr[4];
#pragma unroll
      for (int mi = 0; mi < 4; ++mi)
        af[mi] = *(const bf8_t*)&lsA[(wm * 64 + mi * 16 + lrow) * 64 + lk];
#pragma unroll
      for (int ni = 0; ni < 4; ++ni)
        bfr[ni] = *(const bf8_t*)&lsB[(wn * 64 + ni * 16 + lrow) * 64 + lk];
#pragma unroll
      for (int mi = 0; mi < 4; ++mi)
#pragma unroll
        for (int ni = 0; ni < 4; ++ni)
          acc[mi][ni] = __builtin_amdgcn_mfma_f32_16x16x32_bf16(af[mi], bfr[ni], acc[mi][ni], 0, 0, 0);
    }
    __syncthreads();
  }

  const int rq = (lane >> 4) * 4;                  // C/D: row=(lane>>4)*4+r, col=lane&15
#pragma unroll
  for (int mi = 0; mi < 4; ++mi) {
#pragma unroll
    for (int ni = 0; ni < 4; ++ni) {
#pragma unroll
      for (int r = 0; r < 4; ++r) {
        int m = m0 + wm * 64 + mi * 16 + rq + r;
        int n = n0 + wn * 64 + ni * 16 + lrow;
        float v = acc[mi][ni][r];
        if (EPI == 1) {
          if (n < 96) o16[((size_t)blockIdx.x * 4096 + m) * 96 + n] = f2b(v);
        } else if (EPI == 2) {
          float t = v + biasf[n];
          float sp = (t > 20.f) ? t : log1pf(__expf(t));
          o16[(size_t)m * 2048 + n] = f2b(sp);
        }
      }
    }
  }
}

__global__ __launch_bounds__(256)
void gemm_xp(const u16* A, int lda, const u16* Bt, int ldb, int Kblk, int Nact,
             u16* o16, const float* biasf)
{ gemm_body<1>(A, lda, Bt, ldb, Kblk, Nact, o16, biasf); }

__global__ __launch_bounds__(256)
void gemm_dt(const u16* A, int lda, const u16* Bt, int ldb, int Kblk, int Nact,
             u16* o16, const float* biasf)
{ gemm_body<2>(A, lda, Bt, ldb, Kblk, Nact, o16, biasf); }

// ---------------------------------------------------------------------------
// 8-phase 256x256 bf16 GEMM for in_proj (M=N=4096, K=1024): verified R1/R2
// (42.1-42.3 us, 826 TF). Structure ceiling analysis (R5): acc[8][4]=128 f32
// -> ~256 unified regs/wave -> hard 1 block/CU; 128^2 tiles would be LDS-BW
// bound (~38 us); intra-block schedule perturbations null (R3/R4). Final.
// ---------------------------------------------------------------------------

// stage one 128x64 unit: 512 threads x 2 x 16B gload_lds. granule g = j*512 +
// wid*64 + lane -> lds row g>>3, slot g&7, global colchunk (g&7)^((g>>3)&7).
__device__ __forceinline__ void stageu(const u16* __restrict__ g, int ld,
                                       int row0, int k0, u16* ldsu,
                                       int wid, int lane) {
  int qg = (lane & 7) ^ ((lane >> 3) & 7);
#pragma unroll
  for (int j = 0; j < 2; ++j) {
    int rr = j * 64 + wid * 8 + (lane >> 3);
    const u16* gp = g + (size_t)(row0 + rr) * ld + k0 + qg * 8;
    __builtin_amdgcn_global_load_lds(AS1C(gp), AS3(ldsu + (j * 512 + wid * 64) * 8), 16, 0, 0);
  }
}

#define G8_BAR()   __builtin_amdgcn_s_barrier()
#define G8_LGKM0() do { asm volatile("s_waitcnt lgkmcnt(0)" ::: "memory"); \
                        __builtin_amdgcn_sched_barrier(0); } while (0)
#define G8_LGKM8() asm volatile("s_waitcnt lgkmcnt(8)" ::: "memory")
#define G8_VM(N)   do { asm volatile("s_waitcnt vmcnt(" #N ")" ::: "memory"); \
                        __builtin_amdgcn_sched_barrier(0); } while (0)

#define RD_A(base, MH) do { \
  _Pragma("unroll") \
  for (int mi_ = 0; mi_ < 4; ++mi_) { \
    af[mi_][0] = *(const bf8_t*)((base) + arow + ((MH) * 64 + mi_ * 16) * 64 + aq0); \
    af[mi_][1] = *(const bf8_t*)((base) + arow + ((MH) * 64 + mi_ * 16) * 64 + aq1); \
  } } while (0)

#define RD_B(base, NH) do { \
  _Pragma("unroll") \
  for (int ni_ = 0; ni_ < 2; ++ni_) { \
    bfr[NH][ni_][0] = *(const bf8_t*)((base) + brow + ((NH) * 32 + ni_ * 16) * 64 + aq0); \
    bfr[NH][ni_][1] = *(const bf8_t*)((base) + brow + ((NH) * 32 + ni_ * 16) * 64 + aq1); \
  } } while (0)

#define MMA(MH, NH) do { \
  __builtin_amdgcn_s_setprio(1); \
  _Pragma("unroll") \
  for (int mi_ = 0; mi_ < 4; ++mi_) \
    _Pragma("unroll") \
    for (int ni_ = 0; ni_ < 2; ++ni_) { \
      acc[(MH) * 4 + mi_][(NH) * 2 + ni_] = __builtin_amdgcn_mfma_f32_16x16x32_bf16( \
          af[mi_][0], bfr[NH][ni_][0], acc[(MH) * 4 + mi_][(NH) * 2 + ni_], 0, 0, 0); \
      acc[(MH) * 4 + mi_][(NH) * 2 + ni_] = __builtin_amdgcn_mfma_f32_16x16x32_bf16( \
          af[mi_][1], bfr[NH][ni_][1], acc[(MH) * 4 + mi_][(NH) * 2 + ni_], 0, 0, 0); \
    } \
  __builtin_amdgcn_s_setprio(0); \
} while (0)

__global__ __launch_bounds__(512, 2)
void gemm8_in(const u16* __restrict__ A, const u16* __restrict__ Bt,
              u16* __restrict__ o16)
{
  __shared__ u16 ls[65536];                       // 128 KB: 2 buf x (A 32K + B 32K)
  const int tid = threadIdx.x;
  const int wid = tid >> 6, lane = tid & 63;
  const int wm = wid >> 2, wn = wid & 3;          // 2x4 wave grid, 128x64 per wave
  const int lrow = lane & 15;
  const int kq = lane >> 4;
  const int sw = lrow & 7;
  const int m0 = blockIdx.y * 256;
  const int n0 = blockIdx.x * 256;
  u16* lsA0 = ls;
  u16* lsB0 = ls + 16384;
  u16* lsA1 = ls + 32768;
  u16* lsB1 = ls + 49152;
  const int arow = (wm * 128 + lrow) * 64;
  const int brow = (wn * 64 + lrow) * 64;
  const int aq0 = (kq ^ sw) * 8;
  const int aq1 = ((4 + kq) ^ sw) * 8;

  f4_t acc[8][4];
#pragma unroll
  for (int i = 0; i < 8; ++i)
#pragma unroll
    for (int j = 0; j < 4; ++j) acc[i][j] = {0.f, 0.f, 0.f, 0.f};
  bf8_t af[4][2];
  bf8_t bfr[2][2][2];

  // prologue: tile0 (A0,A1,B0,B1)->buf0, tile1 (B0,B1)->buf1; keep 4 in flight
  stageu(A,  1024, m0,        0, lsA0,        wid, lane);
  stageu(A,  1024, m0 + 128,  0, lsA0 + 8192, wid, lane);
  stageu(Bt, 1024, n0,        0, lsB0,        wid, lane);
  stageu(Bt, 1024, n0 + 128,  0, lsB0 + 8192, wid, lane);
  stageu(Bt, 1024, n0,       64, lsB1,        wid, lane);
  stageu(Bt, 1024, n0 + 128, 64, lsB1 + 8192, wid, lane);
  G8_VM(4); G8_BAR();

#pragma unroll 1
  for (int i = 0; i < 7; ++i) {                   // iterations 0..6 (tiles 0..13)
    const int k1 = (2 * i + 1) * 64, k2 = k1 + 64, k3 = k1 + 128;
    // P1: read buf0 A-half0 + B-half0; stage (t+1).A0 -> buf1
    RD_A(lsA0, 0); RD_B(lsB0, 0);
    stageu(A, 1024, m0, k1, lsA1, wid, lane);
    G8_LGKM8(); G8_BAR(); G8_LGKM0(); MMA(0, 0); G8_BAR();
    // P2: read buf0 B-half1; stage (t+1).A1 -> buf1
    RD_B(lsB0, 1);
    stageu(A, 1024, m0 + 128, k1, lsA1 + 8192, wid, lane);
    G8_BAR(); G8_LGKM0(); MMA(0, 1); G8_BAR();
    // P3: read buf0 A-half1; stage (t+2).B0 -> buf0 (B reads done end P2)
    RD_A(lsA0, 1);
    stageu(Bt, 1024, n0, k2, lsB0, wid, lane);
    G8_BAR(); G8_LGKM0(); MMA(1, 0); G8_BAR();
    // P4: stage (t+2).B1 -> buf0; counted vmcnt -> tile t+1 landed
    stageu(Bt, 1024, n0 + 128, k2, lsB0 + 8192, wid, lane);
    G8_BAR(); G8_LGKM0(); MMA(1, 1); G8_VM(4); G8_BAR();
    // P5: read buf1 A-half0 + B-half0; stage (t+2).A0 -> buf0 (A reads done end P3)
    RD_A(lsA1, 0); RD_B(lsB1, 0);
    stageu(A, 1024, m0, k2, lsA0, wid, lane);
    G8_LGKM8(); G8_BAR(); G8_LGKM0(); MMA(0, 0); G8_BAR();
    // P6: read buf1 B-half1; stage (t+2).A1 -> buf0
    RD_B(lsB1, 1);
    stageu(A, 1024, m0 + 128, k2, lsA0 + 8192, wid, lane);
    G8_BAR(); G8_LGKM0(); MMA(0, 1); G8_BAR();
    // P7: read buf1 A-half1; stage (t+3).B0 -> buf1
    RD_A(lsA1, 1);
    stageu(Bt, 1024, n0, k3, lsB1, wid, lane);
    G8_BAR(); G8_LGKM0(); MMA(1, 0); G8_BAR();
    // P8: stage (t+3).B1 -> buf1; counted vmcnt -> tile t+2 landed
    stageu(Bt, 1024, n0 + 128, k3, lsB1 + 8192, wid, lane);
    G8_BAR(); G8_LGKM0(); MMA(1, 1); G8_VM(4); G8_BAR();
  }

  {                                               // last iteration: tiles 14,15
    const int k1 = 960;
    RD_A(lsA0, 0); RD_B(lsB0, 0);
    stageu(A, 1024, m0, k1, lsA1, wid, lane);
    G8_LGKM8(); G8_BAR(); G8_LGKM0(); MMA(0, 0); G8_BAR();
    RD_B(lsB0, 1);
    stageu(A, 1024, m0 + 128, k1, lsA1 + 8192, wid, lane);
    G8_BAR(); G8_LGKM0(); MMA(0, 1); G8_BAR();
    RD_A(lsA0, 1);
    G8_BAR(); G8_LGKM0(); MMA(1, 0); G8_BAR();
    G8_BAR(); G8_LGKM0(); MMA(1, 1); G8_VM(0); G8_BAR();
    RD_A(lsA1, 0); RD_B(lsB1, 0);
    G8_BAR(); G8_LGKM0(); MMA(0, 0); G8_BAR();
    RD_B(lsB1, 1);
    G8_BAR(); G8_LGKM0(); MMA(0, 1); G8_BAR();
    RD_A(lsA1, 1);
    G8_BAR(); G8_LGKM0(); MMA(1, 0); G8_BAR();
    G8_LGKM0(); MMA(1, 1);
  }

  // epilogue: xi (n<2048) | z (n>=2048, at o16+8M)
  const int rq = (lane >> 4) * 4;
#pragma unroll
  for (int mi = 0; mi < 8; ++mi) {
#pragma unroll
    for (int ni = 0; ni < 4; ++ni) {
#pragma unroll
      for (int r = 0; r < 4; ++r) {
        int m = m0 + wm * 128 + mi * 16 + rq + r;
        int n = n0 + wn * 64 + ni * 16 + lrow;
        float v = acc[mi][ni][r];
        if (n < 2048) o16[(size_t)m * 2048 + n] = f2b(v);
        else          o16[(size_t)8388608 + (size_t)m * 2048 + (n - 2048)] = f2b(v);
      }
    }
  }
}

// ---------------------------------------------------------------------------
// R7 out_proj: single-K 4-phase GEMM, 256 threads (2x2 waves of 64x64 ->
// 16 MFMA per cluster, half the barriers/MFMA of the R5 512-thr version).
// Tile 128M x 128N, K=2048 (32 BK-tiles), grid (8,32)=256 blocks, LDS 64 KB
// -> 2 blocks/CU for cross-block overlap. Fused residual: writes h = y + x.
// Ledger (stage64 = 4 loads/thread): prologue A0,B0,B1=12, VM(4) -> B(t1)=4.
//  Q1: +A(t+1)4 -> 8;  consume buf0.kh0
//  Q2: +B(t+2)4 -> 12; VM(4) retires B(t+1),A(t+1) -> buf1 ready
//  Q3: +A(t+2)4 -> 8;  consume buf1.kh0
//  Q4: +B(t+3)4 -> 12; VM(4) retires tile t+2 -> buf0 ready. invariant.
// Region safety: buf.B fully read in Q1/Q3 (sealed by trailing BAR) before
// next-phase B-stage; buf.A fully read by end Q2/Q4 before next A-stage.
// ---------------------------------------------------------------------------

#define X4_RD_A(base, KH) do { \
  _Pragma("unroll") \
  for (int mi_ = 0; mi_ < 4; ++mi_) \
    afx[mi_] = *(const bf8_t*)((base) + (wm * 64 + mi_ * 16 + lrow) * 64 + ((KH) ? aq1 : aq0)); \
  } while (0)

#define X4_RD_B(base) do { \
  _Pragma("unroll") \
  for (int ni_ = 0; ni_ < 4; ++ni_) { \
    bfx[ni_][0] = *(const bf8_t*)((base) + (wn * 64 + ni_ * 16 + lrow) * 64 + aq0); \
    bfx[ni_][1] = *(const bf8_t*)((base) + (wn * 64 + ni_ * 16 + lrow) * 64 + aq1); \
  } } while (0)

#define X4_MMA(KH) do { \
  __builtin_amdgcn_s_setprio(1); \
  _Pragma("unroll") \
  for (int mi_ = 0; mi_ < 4; ++mi_) \
    _Pragma("unroll") \
    for (int ni_ = 0; ni_ < 4; ++ni_) \
      acc[mi_][ni_] = __builtin_amdgcn_mfma_f32_16x16x32_bf16( \
          afx[mi_], bfx[ni_][KH], acc[mi_][ni_], 0, 0, 0); \
  __builtin_amdgcn_s_setprio(0); \
} while (0)

__global__ __launch_bounds__(256, 2)
void gemm4_out(const u16* __restrict__ A, const u16* __restrict__ Bt,
               const float* __restrict__ xres, float* __restrict__ yout)
{
  __shared__ u16 ls[32768];                       // 64 KB: 2 buf x (A 16K + B 16K)
  const int tid = threadIdx.x;
  const int wid = tid >> 6, lane = tid & 63;
  const int wm = wid >> 1, wn = wid & 1;          // 2x2 waves, 64x64 each
  const int lrow = lane & 15;
  const int kq = lane >> 4;
  const int sw = lrow & 7;
  const int m0 = blockIdx.y * 128;
  const int n0 = blockIdx.x * 128;
  u16* lsA0 = ls;                                 // 8192 u16 = 128x64
  u16* lsB0 = ls + 8192;
  u16* lsA1 = ls + 16384;
  u16* lsB1 = ls + 24576;
  const int aq0 = (kq ^ sw) * 8;
  const int aq1 = ((4 + kq) ^ sw) * 8;

  f4_t acc[4][4];
#pragma unroll
  for (int i = 0; i < 4; ++i)
#pragma unroll
    for (int j = 0; j < 4; ++j) acc[i][j] = {0.f, 0.f, 0.f, 0.f};
  bf8_t afx[4];
  bf8_t bfx[4][2];

  // prologue: tile0 (A,B)->buf0, tile1 B->buf1
  stage64(A,  2048, m0, 0x3fffffff,  0, lsA0, wid, lane);
  stage64(Bt, 2048, n0, 0x3fffffff,  0, lsB0, wid, lane);
  stage64(Bt, 2048, n0, 0x3fffffff, 64, lsB1, wid, lane);
  G8_VM(4); G8_BAR();

#pragma unroll 1
  for (int i = 0; i < 15; ++i) {                  // tile pairs (0,1)..(28,29)
    const int ka1 = (2 * i + 1) * 64;             // A of odd tile t+1
    const int k2  = ka1 + 64;                     // tile t+2
    const int kb3 = ka1 + 128;                    // B of tile t+3
    // Q1: read buf0 {A-kh0, B both}; stage A(t+1)->buf1.A (sealed prev Q4)
    X4_RD_A(lsA0, 0); X4_RD_B(lsB0);
    stage64(A, 2048, m0, 0x3fffffff, ka1, lsA1, wid, lane);
    G8_BAR(); G8_LGKM0(); X4_MMA(0); G8_BAR();
    // Q2: read buf0 A-kh1; stage B(t+2)->buf0.B (sealed end Q1)
    X4_RD_A(lsA0, 1);
    stage64(Bt, 2048, n0, 0x3fffffff, k2, lsB0, wid, lane);
    G8_LGKM0(); X4_MMA(1); G8_VM(4); G8_BAR();
    // Q3: read buf1 {A-kh0, B both}; stage A(t+2)->buf0.A (sealed end Q2)
    X4_RD_A(lsA1, 0); X4_RD_B(lsB1);
    stage64(A, 2048, m0, 0x3fffffff, k2, lsA0, wid, lane);
    G8_BAR(); G8_LGKM0(); X4_MMA(0); G8_BAR();
    // Q4: read buf1 A-kh1; stage B(t+3)->buf1.B (sealed end Q3)
    X4_RD_A(lsA1, 1);
    stage64(Bt, 2048, n0, 0x3fffffff, kb3, lsB1, wid, lane);
    G8_LGKM0(); X4_MMA(1); G8_VM(4); G8_BAR();
  }

  {                                               // final: tiles 30, 31
    X4_RD_A(lsA0, 0); X4_RD_B(lsB0);
    stage64(A, 2048, m0, 0x3fffffff, 1984, lsA1, wid, lane);   // A(31)
    G8_BAR(); G8_LGKM0(); X4_MMA(0); G8_BAR();
    X4_RD_A(lsA0, 1);
    G8_LGKM0(); X4_MMA(1); G8_VM(0); G8_BAR();    // drain A(31),B(31)
    X4_RD_A(lsA1, 0); X4_RD_B(lsB1);
    G8_LGKM0(); X4_MMA(0);
    X4_RD_A(lsA1, 1);
    G8_LGKM0(); X4_MMA(1);
  }

  const int rq = (lane >> 4) * 4;
#pragma unroll
  for (int mi = 0; mi < 4; ++mi) {
#pragma unroll
    for (int ni = 0; ni < 4; ++ni) {
#pragma unroll
      for (int r = 0; r < 4; ++r) {
        int m = m0 + wm * 64 + mi * 16 + rq + r;
        int n = n0 + wn * 64 + ni * 16 + lrow;
        yout[(size_t)m * 1024 + n] = acc[mi][ni][r] + xres[(size_t)m * 1024 + n];
      }
    }
  }
}

// reduce 8 bf16 split-K partials of x_proj; emit dtA bf16 [4096,64] + bc f32 [4096,32]
__global__ __launch_bounds__(256)
void xproj_reduce(const u16* __restrict__ part, u16* __restrict__ dtA,
                  float* __restrict__ bc)
{
  int idx = blockIdx.x * 256 + threadIdx.x;   // 4096*96
  int m = idx / 96, n = idx - m * 96;
  float s = 0.f;
#pragma unroll
  for (int p = 0; p < 8; ++p) s += b2f(part[(size_t)p * 393216 + idx]);
  if (n < 64) dtA[(size_t)m * 64 + n] = f2b(s);
  else        bc[(size_t)m * 32 + (n - 64)] = s;
}

// causal depthwise conv1d (window 4) + bias + silu; vectorized 8 channels/thread
__global__ __launch_bounds__(256)
void conv_silu(const u16* __restrict__ xib, const float* __restrict__ cw,
               const float* __restrict__ cb, u16* __restrict__ ub)
{
  int i = blockIdx.x * 256 + threadIdx.x;     // 1,048,576 threads
  int c8 = (i & 255) * 8;
  int row = i >> 8;                           // b*2048 + l
  int l = row & 2047;
  const u16* base = xib + (size_t)row * 2048 + c8;
  u16x8 x0 = {0,0,0,0,0,0,0,0}, x1 = x0, x2 = x0, x3;
  x3 = *(const u16x8*)(base);
  if (l >= 1) x2 = *(const u16x8*)(base - 2048);
  if (l >= 2) x1 = *(const u16x8*)(base - 2 * 2048);
  if (l >= 3) x0 = *(const u16x8*)(base - 3 * 2048);
  f4_t cb0 = *(const f4_t*)(cb + c8);
  f4_t cb1 = *(const f4_t*)(cb + c8 + 4);
  u16x8 o;
#pragma unroll
  for (int j = 0; j < 8; ++j) {
    f4_t w = *(const f4_t*)(cw + (size_t)(c8 + j) * 4);
    float a = (j < 4 ? cb0[j] : cb1[j - 4])
            + w[0] * b2f(x0[j]) + w[1] * b2f(x1[j])
            + w[2] * b2f(x2[j]) + w[3] * b2f(x3[j]);
    float s = a / (1.f + __expf(-a));
    o[j] = f2b(s);
  }
  *(u16x8*)(ub + (size_t)row * 2048 + c8) = o;
}

// ---- chunk-parallel scan, d-in-lane layout. 64 chunks x 32 steps. ----
// Q stored as bf16 (R6, verified: absmax unchanged).
__global__ __launch_bounds__(256)
void scan_s1(const u16* __restrict__ delta_bf, const u16* __restrict__ ub,
             const float* __restrict__ bc, const float* __restrict__ alog,
             u16* __restrict__ S, u16* __restrict__ Q)
{
  int blk = blockIdx.x;                // 1024 blocks: b(1) x c(6) x g(3)
  int g = blk & 7, c = (blk >> 3) & 63, b = blk >> 9;
  int d = g * 256 + threadIdx.x;
  float Av[16];
#pragma unroll
  for (int nq = 0; nq < 4; ++nq) {
    f4_t al = *(const f4_t*)(alog + (size_t)d * 16 + nq * 4);
#pragma unroll
    for (int j = 0; j < 4; ++j) Av[nq * 4 + j] = -__expf(al[j]);
  }
  float Av0 = Av[0];
  bool st = true;
#pragma unroll
  for (int n = 1; n < 16; ++n)
    st = st && (fabsf(Av[n] - (float)(n + 1) * Av0) <= 1e-3f * (float)(n + 1));
  f4_t Qr[4];
#pragma unroll
  for (int nq = 0; nq < 4; ++nq) Qr[nq] = {0.f,0.f,0.f,0.f};
  float Sd = 0.f;
  int row0 = b * 2048 + c * 32;
  if (st) {
#pragma unroll 2
    for (int i = 0; i < 32; ++i) {
      size_t row = (size_t)(row0 + i);
      float dlt = b2f(delta_bf[row * 2048 + d]);
      float uv  = b2f(ub[row * 2048 + d]);
      const float* bp = bc + row * 32;
      f4_t Bv[4];
#pragma unroll
      for (int nq = 0; nq < 4; ++nq) Bv[nq] = *(const f4_t*)(bp + nq * 4);
      float du = dlt * uv;
      float e1 = __expf(dlt * Av0);
      float a = e1;
      Sd += dlt;
#pragma unroll
      for (int n = 0; n < 16; ++n) {
        Qr[n >> 2][n & 3] = a * Qr[n >> 2][n & 3] + du * Bv[n >> 2][n & 3];
        a *= e1;
      }
    }
  } else {
#pragma unroll 2
    for (int i = 0; i < 32; ++i) {
      size_t row = (size_t)(row0 + i);
      float dlt = b2f(delta_bf[row * 2048 + d]);
      float uv  = b2f(ub[row * 2048 + d]);
      const float* bp = bc + row * 32;
      f4_t Bv[4];
#pragma unroll
      for (int nq = 0; nq < 4; ++nq) Bv[nq] = *(const f4_t*)(bp + nq * 4);
      float du = dlt * uv;
      Sd += dlt;
#pragma unroll
      for (int n = 0; n < 16; ++n) {
        float a = __expf(dlt * Av[n]);
        Qr[n >> 2][n & 3] = a * Qr[n >> 2][n & 3] + du * Bv[n >> 2][n & 3];
      }
    }
  }
  S[(size_t)(b * 64 + c) * 2048 + d] = f2b(Sd);
  size_t o = ((size_t)((b * 64 + c) * 2048 + d)) * 16;
  u16x8 q0, q1;
#pragma unroll
  for (int j = 0; j < 8; ++j) { q0[j] = f2b(Qr[j >> 2][j & 3]); q1[j] = f2b(Qr[(j + 8) >> 2][j & 3]); }
  *(u16x8*)(Q + o)     = q0;
  *(u16x8*)(Q + o + 8) = q1;
}

// S2: serial prefix over 64 chunks per (b,d,n); Q bf16 in/out
__global__ __launch_bounds__(256)
void scan_comb(const u16* __restrict__ S16, u16* __restrict__ Q,
               const float* __restrict__ alog)
{
  int idx = blockIdx.x * 256 + threadIdx.x;   // b*32768 + d*16+n
  int b = idx >> 15, dn = idx & 32767;
  int d = dn >> 4;
  float Av = -__expf(alog[dn]);
  size_t qbase = (size_t)b * 2097152 + dn;
  size_t sbase = (size_t)b * 131072 + d;
  float H = 0.f;
#pragma unroll
  for (int cg = 0; cg < 4; ++cg) {
    float sv[16], qv[16];
#pragma unroll
    for (int j = 0; j < 16; ++j) {
      int c = cg * 16 + j;
      qv[j] = b2f(Q[qbase + (size_t)c * 32768]);
      sv[j] = b2f(S16[sbase + (size_t)c * 2048]);
    }
#pragma unroll
    for (int j = 0; j < 16; ++j) {
      int c = cg * 16 + j;
      Q[qbase + (size_t)c * 32768] = f2b(H);
      H = __expf(Av * sv[j]) * H + qv[j];
    }
  }
}

// S3: re-scan with correct h_in (bf16 Q); fused D-skip + silu(z) gate
__global__ __launch_bounds__(256)
void scan_s3(const u16* __restrict__ delta_bf, const u16* __restrict__ ub,
             const float* __restrict__ bc, const float* __restrict__ alog,
             const u16* __restrict__ Q, const float* __restrict__ Dw,
             u16* __restrict__ zy)
{
  int blk = blockIdx.x;                // 1024 blocks
  int g = blk & 7, c = (blk >> 3) & 63, b = blk >> 9;
  int d = g * 256 + threadIdx.x;
  float Av[16];
#pragma unroll
  for (int nq = 0; nq < 4; ++nq) {
    f4_t al = *(const f4_t*)(alog + (size_t)d * 16 + nq * 4);
#pragma unroll
    for (int j = 0; j < 4; ++j) Av[nq * 4 + j] = -__expf(al[j]);
  }
  float Av0 = Av[0];
  bool st = true;
#pragma unroll
  for (int n = 1; n < 16; ++n)
    st = st && (fabsf(Av[n] - (float)(n + 1) * Av0) <= 1e-3f * (float)(n + 1));
  f4_t h4[4];
  size_t o = ((size_t)((b * 64 + c) * 2048 + d)) * 16;
  {
    u16x8 q0 = *(const u16x8*)(Q + o);
    u16x8 q1 = *(const u16x8*)(Q + o + 8);
#pragma unroll
    for (int j = 0; j < 8; ++j) { h4[j >> 2][j & 3] = b2f(q0[j]); h4[(j + 8) >> 2][j & 3] = b2f(q1[j]); }
  }
  float Dv = Dw[d];
  int row0 = b * 2048 + c * 32;
  if (st) {
#pragma unroll 2
    for (int i = 0; i < 32; ++i) {
      size_t row = (size_t)(row0 + i);
      float dlt = b2f(delta_bf[row * 2048 + d]);
      float uv  = b2f(ub[row * 2048 + d]);
      const float* bp = bc + row * 32;
      f4_t Bv[4], Cv[4];
#pragma unroll
      for (int nq = 0; nq < 4; ++nq) { Bv[nq] = *(const f4_t*)(bp + nq * 4); Cv[nq] = *(const f4_t*)(bp + 16 + nq * 4); }
      float du = dlt * uv;
      float e1 = __expf(dlt * Av0);
      float a = e1;
      float y = 0.f;
#pragma unroll
      for (int n = 0; n < 16; ++n) {
        float hn = a * h4[n >> 2][n & 3] + du * Bv[n >> 2][n & 3];
        h4[n >> 2][n & 3] = hn;
        y += hn * Cv[n >> 2][n & 3];
        a *= e1;
      }
      float zv = b2f(zy[row * 2048 + d]);
      float ov = (y + Dv * uv) * (zv / (1.f + __expf(-zv)));
      zy[row * 2048 + d] = f2b(ov);
    }
  } else {
#pragma unroll 2
    for (int i = 0; i < 32; ++i) {
      size_t row = (size_t)(row0 + i);
      float dlt = b2f(delta_bf[row * 2048 + d]);
      float uv  = b2f(ub[row * 2048 + d]);
      const float* bp = bc + row * 32;
      f4_t Bv[4], Cv[4];
#pragma unroll
      for (int nq = 0; nq < 4; ++nq) { Bv[nq] = *(const f4_t*)(bp + nq * 4); Cv[nq] = *(const f4_t*)(bp + 16 + nq * 4); }
      float du = dlt * uv;
      float y = 0.f;
#pragma unroll
      for (int n = 0; n < 16; ++n) {
        float a = __expf(dlt * Av[n]);
        float hn = a * h4[n >> 2][n & 3] + du * Bv[n >> 2][n & 3];
        h4[n >> 2][n & 3] = hn;
        y += hn * Cv[n >> 2][n & 3];
      }
      float zv = b2f(zy[row * 2048 + d]);
      float ov = (y + Dv * uv) * (zv / (1.f + __expf(-zv)));
      zy[row * 2048 + d] = f2b(ov);
    }
  }
}

// LayerNorm over h = y + x (residual already added in gemm4_out epilogue).
// In-place safe: h aliases outp (each thread reads then writes its 4 floats).
__global__ __launch_bounds__(256)
void ln_kernel(const float* __restrict__ hv,
               const float* __restrict__ lnw, const float* __restrict__ lnb,
               float* __restrict__ outp)
{
  __shared__ float ssum[4], ssq[4];
  int row = blockIdx.x, t = threadIdx.x;
  f4_t v4 = *(const f4_t*)(hv + (size_t)row * 1024 + t * 4);
  float v[4], s = 0.f, q = 0.f;
#pragma unroll
  for (int j = 0; j < 4; ++j) { v[j] = v4[j]; s += v[j]; q += v[j] * v[j]; }
#pragma unroll
  for (int m = 32; m; m >>= 1) { s += __shfl_xor(s, m, 64); q += __shfl_xor(q, m, 64); }
  int wv = t >> 6;
  if ((t & 63) == 0) { ssum[wv] = s; ssq[wv] = q; }
  __syncthreads();
  s = ssum[0] + ssum[1] + ssum[2] + ssum[3];
  q = ssq[0] + ssq[1] + ssq[2] + ssq[3];
  float mu = s * (1.f / 1024.f);
  float var = q * (1.f / 1024.f) - mu * mu;
  float rs = rsqrtf(var + 1e-5f);
  f4_t o;
#pragma unroll
  for (int j = 0; j < 4; ++j)
    o[j] = (v[j] - mu) * rs * lnw[t * 4 + j] + lnb[t * 4 + j];
  *(f4_t*)(outp + (size_t)row * 1024 + t * 4) = o;
}

extern "C" void kernel_launch(void* const* d_in, const int* in_sizes, int n_in,
                              void* d_out, int out_size, void* d_ws, size_t ws_size,
                              hipStream_t stream)
{
  const float* x      = (const float*)d_in[0];   // [2,2048,1024]
  const float* inW    = (const float*)d_in[1];   // [4096,1024]
  const float* convW  = (const float*)d_in[2];   // [2048,1,4]
  const float* convB  = (const float*)d_in[3];   // [2048]
  const float* xprojW = (const float*)d_in[4];   // [96,2048]
  const float* dtW    = (const float*)d_in[5];   // [2048,64]
  const float* dtB    = (const float*)d_in[6];   // [2048]
  const float* alog   = (const float*)d_in[7];   // [2048,16]
  const float* Dw     = (const float*)d_in[8];   // [2048]
  const float* outW   = (const float*)d_in[9];   // [1024,2048]
  const float* lnw    = (const float*)d_in[10];  // [1024]
  const float* lnb    = (const float*)d_in[11];  // [1024]
  float* out = (float*)d_out;                    // [2,2048,1024] f32 (16 MiB)

  char* ws = (char*)d_ws;
  u16*   xiz    = (u16*)(ws);
  u16*   zy     = xiz + 8388608;
  u16*   xb     = (u16*)(ws + 33554432);
  u16*   inWb   = xb + 4194304;
  u16*   u_bf   = (u16*)(ws + 33554432);          // overwrites xb/inWb after gemm8_in
  u16*   dtA    = (u16*)(ws + 50331648);
  float* bc     = (float*)(ws + 50855936);
  u16*   xprojWb= (u16*)(ws + 51380224);
  u16*   dtWb   = (u16*)(ws + 51773440);
  u16*   outWb  = (u16*)(ws + 52035584);
  u16*   delta  = xiz;                            // overwrites dead xi
  u16*   xpart  = (u16*)d_out;                    // x_proj bf16 partials [8][4096][96] = 6.3 MB
  u16*   Sbuf   = dtA;                            // S (dtA dead after gemm_dt)
  u16*   Qbuf   = (u16*)d_out;                    // Q bf16 [2,64,2048,16] = 8.39 MB
  float* yout   = (float*)d_out;                  // h = y+x (Q dead after s3)

  dim3 blk(256);
  // fused f32 -> bf16 conversions (one launch)
  cvt_all<<<10560, blk, 0, stream>>>(x, inW, xprojW, dtW, outW,
                                     xb, inWb, xprojWb, dtWb, outWb);
  // in_proj: [4096,1024] x [4096,1024]^T -> xi | z (bf16); 8-phase 256^2 (R2)
  gemm8_in<<<dim3(16, 16), dim3(512), 0, stream>>>(xb, inWb, xiz);
  // depthwise causal conv + silu -> u (bf16; overwrites xb/inWb)
  conv_silu<<<4096, blk, 0, stream>>>(xiz, convW, convB, u_bf);
  // x_proj split-K (8 x 256): bf16 partials into d_out
  gemm_xp<<<dim3(8, 32), blk, 0, stream>>>(u_bf, 2048, xprojWb, 2048, 256, 96, xpart, nullptr);
  xproj_reduce<<<1536, blk, 0, stream>>>(xpart, dtA, bc);
  // dt_proj + softplus -> delta (bf16, overwrites xi)
  gemm_dt<<<dim3(16, 32), blk, 0, stream>>>(dtA, 64, dtWb, 64, 64, 2048, delta, dtB);
  // chunk-parallel scan (64 chunks x 32 steps): S1 -> combine -> S3 (Q bf16)
  scan_s1<<<1024, blk, 0, stream>>>(delta, u_bf, bc, alog, Sbuf, Qbuf);
  scan_comb<<<256, blk, 0, stream>>>(Sbuf, Qbuf, alog);
  scan_s3<<<1024, blk, 0, stream>>>(delta, u_bf, bc, alog, Qbuf, Dw, zy);
  // out_proj single-K 4-phase 128x128 (256 thr, 2 blk/CU) + fused residual
  gemm4_out<<<dim3(8, 32), blk, 0, stream>>>(zy, outWb, x, yout);
  // LayerNorm -> f32 out (in place over h)
  ln_kernel<<<4096, blk, 0, stream>>>(yout, lnw, lnb, out);
}

// Round 8
// 283.076 us; speedup vs baseline: 1.1187x; 1.0509x over previous
//
#include <hip/hip_runtime.h>

typedef unsigned short u16;
typedef __attribute__((ext_vector_type(8))) short bf8_t;    // 8 x bf16 (4 VGPRs)
typedef __attribute__((ext_vector_type(4))) float f4_t;     // 4 x f32
typedef __attribute__((ext_vector_type(4))) unsigned short u16x4;
typedef __attribute__((ext_vector_type(8))) unsigned short u16x8;

__device__ __forceinline__ float b2f(u16 h) {
  union { unsigned u; float f; } v; v.u = ((unsigned)h) << 16; return v.f;
}
__device__ __forceinline__ u16 f2b(float f) {
  union { float f; unsigned u; } v; v.f = f;
  unsigned u = v.u;
  u += 0x7fffu + ((u >> 16) & 1u);   // round-nearest-even
  return (u16)(u >> 16);
}

#define AS1C(p) ((const __attribute__((address_space(1))) void*)(p))
#define AS3(p)  ((__attribute__((address_space(3))) void*)(p))

// one fused f32 -> bf16 convert over all 5 weight/input arrays
__global__ __launch_bounds__(256)
void cvt_all(const float* __restrict__ x, const float* __restrict__ inW,
             const float* __restrict__ xprojW, const float* __restrict__ dtW,
             const float* __restrict__ outW,
             u16* __restrict__ xb, u16* __restrict__ inWb, u16* __restrict__ xpb,
             u16* __restrict__ dtWb, u16* __restrict__ outWb)
{
  int i = blockIdx.x * 256 + threadIdx.x;      // float4 index, total 2703360
  if (i >= 2703360) return;
  const float* s; u16* d; int off;
  if (i < 1048576)      { s = x;      d = xb;    off = i; }
  else if (i < 2097152) { s = inW;    d = inWb;  off = i - 1048576; }
  else if (i < 2146304) { s = xprojW; d = xpb;   off = i - 2097152; }
  else if (i < 2179072) { s = dtW;    d = dtWb;  off = i - 2146304; }
  else                  { s = outW;   d = outWb; off = i - 2179072; }
  f4_t v = *(const f4_t*)(s + (size_t)off * 4);
  u16x4 o;
#pragma unroll
  for (int j = 0; j < 4; ++j) o[j] = f2b(v[j]);
  *(u16x4*)(d + (size_t)off * 4) = o;
}

// Stage one 128x64 bf16 tile (16 KB) into LDS, XOR-swizzled: granule (r,q)
// holds global colchunk q^(r&7). Staging lane i (chunk of 8 rows) fetches
// colchunk (i&7)^((i>>3)&7); reader uses granule (g ^ (row&7)). Bank-quad
// depends only on q_l -> 8 lanes per 4-bank group = 2/bank = conflict-free.
__device__ __forceinline__ void stage64(const u16* g, int ld, int row0, int rowmax,
                                        int k0, u16* lds, int wid, int lane) {
  int qg = (lane & 7) ^ ((lane >> 3) & 7);
#pragma unroll
  for (int c = 0; c < 4; ++c) {
    int chunk = wid * 4 + c;
    int r = row0 + chunk * 8 + (lane >> 3);
    if (r > rowmax) r = rowmax;                       // clamp (results discarded later)
    const u16* gp = g + (size_t)r * ld + k0 + qg * 8;
    __builtin_amdgcn_global_load_lds(AS1C(gp), AS3(lds + chunk * 512), 16, 0, 0);
  }
}

// C = A * Bt^T : A[M,K] bf16 row-major (lda), Bt[N,K] bf16 row-major (ldb).
// BK=64 (two 32-k half-steps per barrier epoch).
// EPI 1: x_proj   -> split-K partials in BF16: o16[(bx*4096+m)*96+n], n<96
// EPI 2: dt_proj  -> o16[m*2048+n] = bf16(softplus(acc + biasf[n]))
template<int EPI>
__device__ __forceinline__ void gemm_body(const u16* __restrict__ A, int lda,
             const u16* __restrict__ Bt, int ldb,
             int Kblk, int Nact,
             u16* __restrict__ o16, const float* __restrict__ biasf)
{
  __shared__ u16 lsA[128 * 64];
  __shared__ u16 lsB[128 * 64];
  const int tid = threadIdx.x;
  const int wid = tid >> 6, lane = tid & 63;
  const int wm = wid >> 1, wn = wid & 1;          // 2x2 wave grid, 64x64 each
  const int lrow = lane & 15;
  const int kq = lane >> 4;                       // 0..3
  const int sw = lrow & 7;                        // swizzle key
  const int m0 = blockIdx.y * 128;
  const int n0 = (EPI == 1) ? 0 : blockIdx.x * 128;
  int kbase = 0;
  if (EPI == 1) kbase = blockIdx.x * Kblk;

  f4_t acc[4][4];
#pragma unroll
  for (int i = 0; i < 4; ++i)
#pragma unroll
    for (int j = 0; j < 4; ++j) acc[i][j] = {0.f, 0.f, 0.f, 0.f};

  for (int kt = kbase; kt < kbase + Kblk; kt += 64) {
    stage64(A,  lda, m0, 0x3fffffff, kt, lsA, wid, lane);
    stage64(Bt, ldb, n0, Nact - 1,   kt, lsB, wid, lane);
    __syncthreads();
#pragma unroll
    for (int h = 0; h < 2; ++h) {
      const int lk = ((h * 4 + kq) ^ sw) * 8;
      bf8_t af[4], bfr[4];
#pragma unroll
      for (int mi = 0; mi < 4; ++mi)
        af[mi] = *(const bf8_t*)&lsA[(wm * 64 + mi * 16 + lrow) * 64 + lk];
#pragma unroll
      for (int ni = 0; ni < 4; ++ni)
        bfr[ni] = *(const bf8_t*)&lsB[(wn * 64 + ni * 16 + lrow) * 64 + lk];
#pragma unroll
      for (int mi = 0; mi < 4; ++mi)
#pragma unroll
        for (int ni = 0; ni < 4; ++ni)
          acc[mi][ni] = __builtin_amdgcn_mfma_f32_16x16x32_bf16(af[mi], bfr[ni], acc[mi][ni], 0, 0, 0);
    }
    __syncthreads();
  }

  const int rq = (lane >> 4) * 4;                  // C/D: row=(lane>>4)*4+r, col=lane&15
#pragma unroll
  for (int mi = 0; mi < 4; ++mi) {
#pragma unroll
    for (int ni = 0; ni < 4; ++ni) {
#pragma unroll
      for (int r = 0; r < 4; ++r) {
        int m = m0 + wm * 64 + mi * 16 + rq + r;
        int n = n0 + wn * 64 + ni * 16 + lrow;
        float v = acc[mi][ni][r];
        if (EPI == 1) {
          if (n < 96) o16[((size_t)blockIdx.x * 4096 + m) * 96 + n] = f2b(v);
        } else if (EPI == 2) {
          float t = v + biasf[n];
          float sp = (t > 20.f) ? t : log1pf(__expf(t));
          o16[(size_t)m * 2048 + n] = f2b(sp);
        }
      }
    }
  }
}

__global__ __launch_bounds__(256)
void gemm_xp(const u16* A, int lda, const u16* Bt, int ldb, int Kblk, int Nact,
             u16* o16, const float* biasf)
{ gemm_body<1>(A, lda, Bt, ldb, Kblk, Nact, o16, biasf); }

__global__ __launch_bounds__(256)
void gemm_dt(const u16* A, int lda, const u16* Bt, int ldb, int Kblk, int Nact,
             u16* o16, const float* biasf)
{ gemm_body<2>(A, lda, Bt, ldb, Kblk, Nact, o16, biasf); }

// ---------------------------------------------------------------------------
// 8-phase 256x256 bf16 GEMM for in_proj (M=N=4096, K=1024): verified R1/R2
// (42.1-42.3 us, 826 TF). Structure ceiling analysis (R5): acc[8][4]=128 f32
// -> ~256 unified regs/wave -> hard 1 block/CU; 128^2 tiles would be LDS-BW
// bound (~38 us); intra-block schedule perturbations null (R3/R4). Final.
// ---------------------------------------------------------------------------

// stage one 128x64 unit: 512 threads x 2 x 16B gload_lds. granule g = j*512 +
// wid*64 + lane -> lds row g>>3, slot g&7, global colchunk (g&7)^((g>>3)&7).
__device__ __forceinline__ void stageu(const u16* __restrict__ g, int ld,
                                       int row0, int k0, u16* ldsu,
                                       int wid, int lane) {
  int qg = (lane & 7) ^ ((lane >> 3) & 7);
#pragma unroll
  for (int j = 0; j < 2; ++j) {
    int rr = j * 64 + wid * 8 + (lane >> 3);
    const u16* gp = g + (size_t)(row0 + rr) * ld + k0 + qg * 8;
    __builtin_amdgcn_global_load_lds(AS1C(gp), AS3(ldsu + (j * 512 + wid * 64) * 8), 16, 0, 0);
  }
}

#define G8_BAR()   __builtin_amdgcn_s_barrier()
#define G8_LGKM0() do { asm volatile("s_waitcnt lgkmcnt(0)" ::: "memory"); \
                        __builtin_amdgcn_sched_barrier(0); } while (0)
#define G8_LGKM8() asm volatile("s_waitcnt lgkmcnt(8)" ::: "memory")
#define G8_VM(N)   do { asm volatile("s_waitcnt vmcnt(" #N ")" ::: "memory"); \
                        __builtin_amdgcn_sched_barrier(0); } while (0)

#define RD_A(base, MH) do { \
  _Pragma("unroll") \
  for (int mi_ = 0; mi_ < 4; ++mi_) { \
    af[mi_][0] = *(const bf8_t*)((base) + arow + ((MH) * 64 + mi_ * 16) * 64 + aq0); \
    af[mi_][1] = *(const bf8_t*)((base) + arow + ((MH) * 64 + mi_ * 16) * 64 + aq1); \
  } } while (0)

#define RD_B(base, NH) do { \
  _Pragma("unroll") \
  for (int ni_ = 0; ni_ < 2; ++ni_) { \
    bfr[NH][ni_][0] = *(const bf8_t*)((base) + brow + ((NH) * 32 + ni_ * 16) * 64 + aq0); \
    bfr[NH][ni_][1] = *(const bf8_t*)((base) + brow + ((NH) * 32 + ni_ * 16) * 64 + aq1); \
  } } while (0)

#define MMA(MH, NH) do { \
  __builtin_amdgcn_s_setprio(1); \
  _Pragma("unroll") \
  for (int mi_ = 0; mi_ < 4; ++mi_) \
    _Pragma("unroll") \
    for (int ni_ = 0; ni_ < 2; ++ni_) { \
      acc[(MH) * 4 + mi_][(NH) * 2 + ni_] = __builtin_amdgcn_mfma_f32_16x16x32_bf16( \
          af[mi_][0], bfr[NH][ni_][0], acc[(MH) * 4 + mi_][(NH) * 2 + ni_], 0, 0, 0); \
      acc[(MH) * 4 + mi_][(NH) * 2 + ni_] = __builtin_amdgcn_mfma_f32_16x16x32_bf16( \
          af[mi_][1], bfr[NH][ni_][1], acc[(MH) * 4 + mi_][(NH) * 2 + ni_], 0, 0, 0); \
    } \
  __builtin_amdgcn_s_setprio(0); \
} while (0)

__global__ __launch_bounds__(512, 2)
void gemm8_in(const u16* __restrict__ A, const u16* __restrict__ Bt,
              u16* __restrict__ o16)
{
  __shared__ u16 ls[65536];                       // 128 KB: 2 buf x (A 32K + B 32K)
  const int tid = threadIdx.x;
  const int wid = tid >> 6, lane = tid & 63;
  const int wm = wid >> 2, wn = wid & 3;          // 2x4 wave grid, 128x64 per wave
  const int lrow = lane & 15;
  const int kq = lane >> 4;
  const int sw = lrow & 7;
  const int m0 = blockIdx.y * 256;
  const int n0 = blockIdx.x * 256;
  u16* lsA0 = ls;
  u16* lsB0 = ls + 16384;
  u16* lsA1 = ls + 32768;
  u16* lsB1 = ls + 49152;
  const int arow = (wm * 128 + lrow) * 64;
  const int brow = (wn * 64 + lrow) * 64;
  const int aq0 = (kq ^ sw) * 8;
  const int aq1 = ((4 + kq) ^ sw) * 8;

  f4_t acc[8][4];
#pragma unroll
  for (int i = 0; i < 8; ++i)
#pragma unroll
    for (int j = 0; j < 4; ++j) acc[i][j] = {0.f, 0.f, 0.f, 0.f};
  bf8_t af[4][2];
  bf8_t bfr[2][2][2];

  // prologue: tile0 (A0,A1,B0,B1)->buf0, tile1 (B0,B1)->buf1; keep 4 in flight
  stageu(A,  1024, m0,        0, lsA0,        wid, lane);
  stageu(A,  1024, m0 + 128,  0, lsA0 + 8192, wid, lane);
  stageu(Bt, 1024, n0,        0, lsB0,        wid, lane);
  stageu(Bt, 1024, n0 + 128,  0, lsB0 + 8192, wid, lane);
  stageu(Bt, 1024, n0,       64, lsB1,        wid, lane);
  stageu(Bt, 1024, n0 + 128, 64, lsB1 + 8192, wid, lane);
  G8_VM(4); G8_BAR();

#pragma unroll 1
  for (int i = 0; i < 7; ++i) {                   // iterations 0..6 (tiles 0..13)
    const int k1 = (2 * i + 1) * 64, k2 = k1 + 64, k3 = k1 + 128;
    // P1: read buf0 A-half0 + B-half0; stage (t+1).A0 -> buf1
    RD_A(lsA0, 0); RD_B(lsB0, 0);
    stageu(A, 1024, m0, k1, lsA1, wid, lane);
    G8_LGKM8(); G8_BAR(); G8_LGKM0(); MMA(0, 0); G8_BAR();
    // P2: read buf0 B-half1; stage (t+1).A1 -> buf1
    RD_B(lsB0, 1);
    stageu(A, 1024, m0 + 128, k1, lsA1 + 8192, wid, lane);
    G8_BAR(); G8_LGKM0(); MMA(0, 1); G8_BAR();
    // P3: read buf0 A-half1; stage (t+2).B0 -> buf0 (B reads done end P2)
    RD_A(lsA0, 1);
    stageu(Bt, 1024, n0, k2, lsB0, wid, lane);
    G8_BAR(); G8_LGKM0(); MMA(1, 0); G8_BAR();
    // P4: stage (t+2).B1 -> buf0; counted vmcnt -> tile t+1 landed
    stageu(Bt, 1024, n0 + 128, k2, lsB0 + 8192, wid, lane);
    G8_BAR(); G8_LGKM0(); MMA(1, 1); G8_VM(4); G8_BAR();
    // P5: read buf1 A-half0 + B-half0; stage (t+2).A0 -> buf0 (A reads done end P3)
    RD_A(lsA1, 0); RD_B(lsB1, 0);
    stageu(A, 1024, m0, k2, lsA0, wid, lane);
    G8_LGKM8(); G8_BAR(); G8_LGKM0(); MMA(0, 0); G8_BAR();
    // P6: read buf1 B-half1; stage (t+2).A1 -> buf0
    RD_B(lsB1, 1);
    stageu(A, 1024, m0 + 128, k2, lsA0 + 8192, wid, lane);
    G8_BAR(); G8_LGKM0(); MMA(0, 1); G8_BAR();
    // P7: read buf1 A-half1; stage (t+3).B0 -> buf1
    RD_A(lsA1, 1);
    stageu(Bt, 1024, n0, k3, lsB1, wid, lane);
    G8_BAR(); G8_LGKM0(); MMA(1, 0); G8_BAR();
    // P8: stage (t+3).B1 -> buf1; counted vmcnt -> tile t+2 landed
    stageu(Bt, 1024, n0 + 128, k3, lsB1 + 8192, wid, lane);
    G8_BAR(); G8_LGKM0(); MMA(1, 1); G8_VM(4); G8_BAR();
  }

  {                                               // last iteration: tiles 14,15
    const int k1 = 960;
    RD_A(lsA0, 0); RD_B(lsB0, 0);
    stageu(A, 1024, m0, k1, lsA1, wid, lane);
    G8_LGKM8(); G8_BAR(); G8_LGKM0(); MMA(0, 0); G8_BAR();
    RD_B(lsB0, 1);
    stageu(A, 1024, m0 + 128, k1, lsA1 + 8192, wid, lane);
    G8_BAR(); G8_LGKM0(); MMA(0, 1); G8_BAR();
    RD_A(lsA0, 1);
    G8_BAR(); G8_LGKM0(); MMA(1, 0); G8_BAR();
    G8_BAR(); G8_LGKM0(); MMA(1, 1); G8_VM(0); G8_BAR();
    RD_A(lsA1, 0); RD_B(lsB1, 0);
    G8_BAR(); G8_LGKM0(); MMA(0, 0); G8_BAR();
    RD_B(lsB1, 1);
    G8_BAR(); G8_LGKM0(); MMA(0, 1); G8_BAR();
    RD_A(lsA1, 1);
    G8_BAR(); G8_LGKM0(); MMA(1, 0); G8_BAR();
    G8_LGKM0(); MMA(1, 1);
  }

  // epilogue: xi (n<2048) | z (n>=2048, at o16+8M)
  const int rq = (lane >> 4) * 4;
#pragma unroll
  for (int mi = 0; mi < 8; ++mi) {
#pragma unroll
    for (int ni = 0; ni < 4; ++ni) {
#pragma unroll
      for (int r = 0; r < 4; ++r) {
        int m = m0 + wm * 128 + mi * 16 + rq + r;
        int n = n0 + wn * 64 + ni * 16 + lrow;
        float v = acc[mi][ni][r];
        if (n < 2048) o16[(size_t)m * 2048 + n] = f2b(v);
        else          o16[(size_t)8388608 + (size_t)m * 2048 + (n - 2048)] = f2b(v);
      }
    }
  }
}

// ---------------------------------------------------------------------------
// out_proj: single-K 4-phase GEMM, 256 threads (2x2 waves of 64x64, 16 MFMA
// per cluster), tile 128M x 128N, K=2048, grid (8,32)=256 blocks, 2 blk/CU.
// R8: fused residual + BF16 h output — epilogue writes h = bf16(y + x),
// halving the h round-trip (16.8 MB f32 -> 8.4 MB bf16 each way).
// vmcnt ledger and region safety as verified in R7.
// ---------------------------------------------------------------------------

#define X4_RD_A(base, KH) do { \
  _Pragma("unroll") \
  for (int mi_ = 0; mi_ < 4; ++mi_) \
    afx[mi_] = *(const bf8_t*)((base) + (wm * 64 + mi_ * 16 + lrow) * 64 + ((KH) ? aq1 : aq0)); \
  } while (0)

#define X4_RD_B(base) do { \
  _Pragma("unroll") \
  for (int ni_ = 0; ni_ < 4; ++ni_) { \
    bfx[ni_][0] = *(const bf8_t*)((base) + (wn * 64 + ni_ * 16 + lrow) * 64 + aq0); \
    bfx[ni_][1] = *(const bf8_t*)((base) + (wn * 64 + ni_ * 16 + lrow) * 64 + aq1); \
  } } while (0)

#define X4_MMA(KH) do { \
  __builtin_amdgcn_s_setprio(1); \
  _Pragma("unroll") \
  for (int mi_ = 0; mi_ < 4; ++mi_) \
    _Pragma("unroll") \
    for (int ni_ = 0; ni_ < 4; ++ni_) \
      acc[mi_][ni_] = __builtin_amdgcn_mfma_f32_16x16x32_bf16( \
          afx[mi_], bfx[ni_][KH], acc[mi_][ni_], 0, 0, 0); \
  __builtin_amdgcn_s_setprio(0); \
} while (0)

__global__ __launch_bounds__(256, 2)
void gemm4_out(const u16* __restrict__ A, const u16* __restrict__ Bt,
               const float* __restrict__ xres, u16* __restrict__ hout)
{
  __shared__ u16 ls[32768];                       // 64 KB: 2 buf x (A 16K + B 16K)
  const int tid = threadIdx.x;
  const int wid = tid >> 6, lane = tid & 63;
  const int wm = wid >> 1, wn = wid & 1;          // 2x2 waves, 64x64 each
  const int lrow = lane & 15;
  const int kq = lane >> 4;
  const int sw = lrow & 7;
  const int m0 = blockIdx.y * 128;
  const int n0 = blockIdx.x * 128;
  u16* lsA0 = ls;                                 // 8192 u16 = 128x64
  u16* lsB0 = ls + 8192;
  u16* lsA1 = ls + 16384;
  u16* lsB1 = ls + 24576;
  const int aq0 = (kq ^ sw) * 8;
  const int aq1 = ((4 + kq) ^ sw) * 8;

  f4_t acc[4][4];
#pragma unroll
  for (int i = 0; i < 4; ++i)
#pragma unroll
    for (int j = 0; j < 4; ++j) acc[i][j] = {0.f, 0.f, 0.f, 0.f};
  bf8_t afx[4];
  bf8_t bfx[4][2];

  // prologue: tile0 (A,B)->buf0, tile1 B->buf1
  stage64(A,  2048, m0, 0x3fffffff,  0, lsA0, wid, lane);
  stage64(Bt, 2048, n0, 0x3fffffff,  0, lsB0, wid, lane);
  stage64(Bt, 2048, n0, 0x3fffffff, 64, lsB1, wid, lane);
  G8_VM(4); G8_BAR();

#pragma unroll 1
  for (int i = 0; i < 15; ++i) {                  // tile pairs (0,1)..(28,29)
    const int ka1 = (2 * i + 1) * 64;             // A of odd tile t+1
    const int k2  = ka1 + 64;                     // tile t+2
    const int kb3 = ka1 + 128;                    // B of tile t+3
    // Q1: read buf0 {A-kh0, B both}; stage A(t+1)->buf1.A (sealed prev Q4)
    X4_RD_A(lsA0, 0); X4_RD_B(lsB0);
    stage64(A, 2048, m0, 0x3fffffff, ka1, lsA1, wid, lane);
    G8_BAR(); G8_LGKM0(); X4_MMA(0); G8_BAR();
    // Q2: read buf0 A-kh1; stage B(t+2)->buf0.B (sealed end Q1)
    X4_RD_A(lsA0, 1);
    stage64(Bt, 2048, n0, 0x3fffffff, k2, lsB0, wid, lane);
    G8_LGKM0(); X4_MMA(1); G8_VM(4); G8_BAR();
    // Q3: read buf1 {A-kh0, B both}; stage A(t+2)->buf0.A (sealed end Q2)
    X4_RD_A(lsA1, 0); X4_RD_B(lsB1);
    stage64(A, 2048, m0, 0x3fffffff, k2, lsA0, wid, lane);
    G8_BAR(); G8_LGKM0(); X4_MMA(0); G8_BAR();
    // Q4: read buf1 A-kh1; stage B(t+3)->buf1.B (sealed end Q3)
    X4_RD_A(lsA1, 1);
    stage64(Bt, 2048, n0, 0x3fffffff, kb3, lsB1, wid, lane);
    G8_LGKM0(); X4_MMA(1); G8_VM(4); G8_BAR();
  }

  {                                               // final: tiles 30, 31
    X4_RD_A(lsA0, 0); X4_RD_B(lsB0);
    stage64(A, 2048, m0, 0x3fffffff, 1984, lsA1, wid, lane);   // A(31)
    G8_BAR(); G8_LGKM0(); X4_MMA(0); G8_BAR();
    X4_RD_A(lsA0, 1);
    G8_LGKM0(); X4_MMA(1); G8_VM(0); G8_BAR();    // drain A(31),B(31)
    X4_RD_A(lsA1, 0); X4_RD_B(lsB1);
    G8_LGKM0(); X4_MMA(0);
    X4_RD_A(lsA1, 1);
    G8_LGKM0(); X4_MMA(1);
  }

  const int rq = (lane >> 4) * 4;
#pragma unroll
  for (int mi = 0; mi < 4; ++mi) {
#pragma unroll
    for (int ni = 0; ni < 4; ++ni) {
#pragma unroll
      for (int r = 0; r < 4; ++r) {
        int m = m0 + wm * 64 + mi * 16 + rq + r;
        int n = n0 + wn * 64 + ni * 16 + lrow;
        hout[(size_t)m * 1024 + n] = f2b(acc[mi][ni][r] + xres[(size_t)m * 1024 + n]);
      }
    }
  }
}

// reduce 8 bf16 split-K partials of x_proj; emit dtA bf16 [4096,64] + bc f32 [4096,32]
__global__ __launch_bounds__(256)
void xproj_reduce(const u16* __restrict__ part, u16* __restrict__ dtA,
                  float* __restrict__ bc)
{
  int idx = blockIdx.x * 256 + threadIdx.x;   // 4096*96
  int m = idx / 96, n = idx - m * 96;
  float s = 0.f;
#pragma unroll
  for (int p = 0; p < 8; ++p) s += b2f(part[(size_t)p * 393216 + idx]);
  if (n < 64) dtA[(size_t)m * 64 + n] = f2b(s);
  else        bc[(size_t)m * 32 + (n - 64)] = s;
}

// causal depthwise conv1d (window 4) + bias + silu.
// R8: 4 output rows per thread -> 7 row-loads per 4 outputs (reads 14.7 MB
// vs 33.6 MB for the 1-row/thread version). Row-groups of 4 never straddle
// the batch edge (4 | 2048); only l0==0 groups zero their 3 halo rows.
__global__ __launch_bounds__(256)
void conv_silu(const u16* __restrict__ xib, const float* __restrict__ cw,
               const float* __restrict__ cb, u16* __restrict__ ub)
{
  int i = blockIdx.x * 256 + threadIdx.x;     // 262,144 threads
  int c8 = (i & 255) * 8;
  int r0 = (i >> 8) * 4;                      // rows r0..r0+3 (same batch)
  int l0 = r0 & 2047;
  const u16* base = xib + (size_t)r0 * 2048 + c8;
  u16x8 xr[7];
  u16x8 z8 = {0,0,0,0,0,0,0,0};
#pragma unroll
  for (int j = 0; j < 3; ++j)
    xr[j] = (l0 != 0) ? *(const u16x8*)(base + (j - 3) * 2048) : z8;
#pragma unroll
  for (int j = 3; j < 7; ++j)
    xr[j] = *(const u16x8*)(base + (j - 3) * 2048);
  f4_t cb0 = *(const f4_t*)(cb + c8);
  f4_t cb1 = *(const f4_t*)(cb + c8 + 4);
  f4_t w[8];
#pragma unroll
  for (int j = 0; j < 8; ++j) w[j] = *(const f4_t*)(cw + (size_t)(c8 + j) * 4);
#pragma unroll
  for (int k = 0; k < 4; ++k) {
    u16x8 o;
#pragma unroll
    for (int j = 0; j < 8; ++j) {
      float a = (j < 4 ? cb0[j] : cb1[j - 4])
              + w[j][0] * b2f(xr[k][j])     + w[j][1] * b2f(xr[k + 1][j])
              + w[j][2] * b2f(xr[k + 2][j]) + w[j][3] * b2f(xr[k + 3][j]);
      float s = a / (1.f + __expf(-a));
      o[j] = f2b(s);
    }
    *(u16x8*)(ub + (size_t)(r0 + k) * 2048 + c8) = o;
  }
}

// ---- chunk-parallel scan, d-in-lane layout. 64 chunks x 32 steps. ----
// Q stored as bf16 (R6, verified: absmax unchanged).
__global__ __launch_bounds__(256)
void scan_s1(const u16* __restrict__ delta_bf, const u16* __restrict__ ub,
             const float* __restrict__ bc, const float* __restrict__ alog,
             u16* __restrict__ S, u16* __restrict__ Q)
{
  int blk = blockIdx.x;                // 1024 blocks: b(1) x c(6) x g(3)
  int g = blk & 7, c = (blk >> 3) & 63, b = blk >> 9;
  int d = g * 256 + threadIdx.x;
  float Av[16];
#pragma unroll
  for (int nq = 0; nq < 4; ++nq) {
    f4_t al = *(const f4_t*)(alog + (size_t)d * 16 + nq * 4);
#pragma unroll
    for (int j = 0; j < 4; ++j) Av[nq * 4 + j] = -__expf(al[j]);
  }
  float Av0 = Av[0];
  bool st = true;
#pragma unroll
  for (int n = 1; n < 16; ++n)
    st = st && (fabsf(Av[n] - (float)(n + 1) * Av0) <= 1e-3f * (float)(n + 1));
  f4_t Qr[4];
#pragma unroll
  for (int nq = 0; nq < 4; ++nq) Qr[nq] = {0.f,0.f,0.f,0.f};
  float Sd = 0.f;
  int row0 = b * 2048 + c * 32;
  if (st) {
#pragma unroll 2
    for (int i = 0; i < 32; ++i) {
      size_t row = (size_t)(row0 + i);
      float dlt = b2f(delta_bf[row * 2048 + d]);
      float uv  = b2f(ub[row * 2048 + d]);
      const float* bp = bc + row * 32;
      f4_t Bv[4];
#pragma unroll
      for (int nq = 0; nq < 4; ++nq) Bv[nq] = *(const f4_t*)(bp + nq * 4);
      float du = dlt * uv;
      float e1 = __expf(dlt * Av0);
      float a = e1;
      Sd += dlt;
#pragma unroll
      for (int n = 0; n < 16; ++n) {
        Qr[n >> 2][n & 3] = a * Qr[n >> 2][n & 3] + du * Bv[n >> 2][n & 3];
        a *= e1;
      }
    }
  } else {
#pragma unroll 2
    for (int i = 0; i < 32; ++i) {
      size_t row = (size_t)(row0 + i);
      float dlt = b2f(delta_bf[row * 2048 + d]);
      float uv  = b2f(ub[row * 2048 + d]);
      const float* bp = bc + row * 32;
      f4_t Bv[4];
#pragma unroll
      for (int nq = 0; nq < 4; ++nq) Bv[nq] = *(const f4_t*)(bp + nq * 4);
      float du = dlt * uv;
      Sd += dlt;
#pragma unroll
      for (int n = 0; n < 16; ++n) {
        float a = __expf(dlt * Av[n]);
        Qr[n >> 2][n & 3] = a * Qr[n >> 2][n & 3] + du * Bv[n >> 2][n & 3];
      }
    }
  }
  S[(size_t)(b * 64 + c) * 2048 + d] = f2b(Sd);
  size_t o = ((size_t)((b * 64 + c) * 2048 + d)) * 16;
  u16x8 q0, q1;
#pragma unroll
  for (int j = 0; j < 8; ++j) { q0[j] = f2b(Qr[j >> 2][j & 3]); q1[j] = f2b(Qr[(j + 8) >> 2][j & 3]); }
  *(u16x8*)(Q + o)     = q0;
  *(u16x8*)(Q + o + 8) = q1;
}

// S2: serial prefix over 64 chunks per (b,d,n); Q bf16 in/out
__global__ __launch_bounds__(256)
void scan_comb(const u16* __restrict__ S16, u16* __restrict__ Q,
               const float* __restrict__ alog)
{
  int idx = blockIdx.x * 256 + threadIdx.x;   // b*32768 + d*16+n
  int b = idx >> 15, dn = idx & 32767;
  int d = dn >> 4;
  float Av = -__expf(alog[dn]);
  size_t qbase = (size_t)b * 2097152 + dn;
  size_t sbase = (size_t)b * 131072 + d;
  float H = 0.f;
#pragma unroll
  for (int cg = 0; cg < 4; ++cg) {
    float sv[16], qv[16];
#pragma unroll
    for (int j = 0; j < 16; ++j) {
      int c = cg * 16 + j;
      qv[j] = b2f(Q[qbase + (size_t)c * 32768]);
      sv[j] = b2f(S16[sbase + (size_t)c * 2048]);
    }
#pragma unroll
    for (int j = 0; j < 16; ++j) {
      int c = cg * 16 + j;
      Q[qbase + (size_t)c * 32768] = f2b(H);
      H = __expf(Av * sv[j]) * H + qv[j];
    }
  }
}

// S3: re-scan with correct h_in (bf16 Q); fused D-skip + silu(z) gate
__global__ __launch_bounds__(256)
void scan_s3(const u16* __restrict__ delta_bf, const u16* __restrict__ ub,
             const float* __restrict__ bc, const float* __restrict__ alog,
             const u16* __restrict__ Q, const float* __restrict__ Dw,
             u16* __restrict__ zy)
{
  int blk = blockIdx.x;                // 1024 blocks
  int g = blk & 7, c = (blk >> 3) & 63, b = blk >> 9;
  int d = g * 256 + threadIdx.x;
  float Av[16];
#pragma unroll
  for (int nq = 0; nq < 4; ++nq) {
    f4_t al = *(const f4_t*)(alog + (size_t)d * 16 + nq * 4);
#pragma unroll
    for (int j = 0; j < 4; ++j) Av[nq * 4 + j] = -__expf(al[j]);
  }
  float Av0 = Av[0];
  bool st = true;
#pragma unroll
  for (int n = 1; n < 16; ++n)
    st = st && (fabsf(Av[n] - (float)(n + 1) * Av0) <= 1e-3f * (float)(n + 1));
  f4_t h4[4];
  size_t o = ((size_t)((b * 64 + c) * 2048 + d)) * 16;
  {
    u16x8 q0 = *(const u16x8*)(Q + o);
    u16x8 q1 = *(const u16x8*)(Q + o + 8);
#pragma unroll
    for (int j = 0; j < 8; ++j) { h4[j >> 2][j & 3] = b2f(q0[j]); h4[(j + 8) >> 2][j & 3] = b2f(q1[j]); }
  }
  float Dv = Dw[d];
  int row0 = b * 2048 + c * 32;
  if (st) {
#pragma unroll 2
    for (int i = 0; i < 32; ++i) {
      size_t row = (size_t)(row0 + i);
      float dlt = b2f(delta_bf[row * 2048 + d]);
      float uv  = b2f(ub[row * 2048 + d]);
      const float* bp = bc + row * 32;
      f4_t Bv[4], Cv[4];
#pragma unroll
      for (int nq = 0; nq < 4; ++nq) { Bv[nq] = *(const f4_t*)(bp + nq * 4); Cv[nq] = *(const f4_t*)(bp + 16 + nq * 4); }
      float du = dlt * uv;
      float e1 = __expf(dlt * Av0);
      float a = e1;
      float y = 0.f;
#pragma unroll
      for (int n = 0; n < 16; ++n) {
        float hn = a * h4[n >> 2][n & 3] + du * Bv[n >> 2][n & 3];
        h4[n >> 2][n & 3] = hn;
        y += hn * Cv[n >> 2][n & 3];
        a *= e1;
      }
      float zv = b2f(zy[row * 2048 + d]);
      float ov = (y + Dv * uv) * (zv / (1.f + __expf(-zv)));
      zy[row * 2048 + d] = f2b(ov);
    }
  } else {
#pragma unroll 2
    for (int i = 0; i < 32; ++i) {
      size_t row = (size_t)(row0 + i);
      float dlt = b2f(delta_bf[row * 2048 + d]);
      float uv  = b2f(ub[row * 2048 + d]);
      const float* bp = bc + row * 32;
      f4_t Bv[4], Cv[4];
#pragma unroll
      for (int nq = 0; nq < 4; ++nq) { Bv[nq] = *(const f4_t*)(bp + nq * 4); Cv[nq] = *(const f4_t*)(bp + 16 + nq * 4); }
      float du = dlt * uv;
      float y = 0.f;
#pragma unroll
      for (int n = 0; n < 16; ++n) {
        float a = __expf(dlt * Av[n]);
        float hn = a * h4[n >> 2][n & 3] + du * Bv[n >> 2][n & 3];
        h4[n >> 2][n & 3] = hn;
        y += hn * Cv[n >> 2][n & 3];
      }
      float zv = b2f(zy[row * 2048 + d]);
      float ov = (y + Dv * uv) * (zv / (1.f + __expf(-zv)));
      zy[row * 2048 + d] = f2b(ov);
    }
  }
}

// LayerNorm over h = y + x (bf16, residual added in gemm4_out epilogue).
__global__ __launch_bounds__(256)
void ln_kernel(const u16* __restrict__ hv,
               const float* __restrict__ lnw, const float* __restrict__ lnb,
               float* __restrict__ outp)
{
  __shared__ float ssum[4], ssq[4];
  int row = blockIdx.x, t = threadIdx.x;
  u16x4 hb = *(const u16x4*)(hv + (size_t)row * 1024 + t * 4);
  float v[4], s = 0.f, q = 0.f;
#pragma unroll
  for (int j = 0; j < 4; ++j) { v[j] = b2f(hb[j]); s += v[j]; q += v[j] * v[j]; }
#pragma unroll
  for (int m = 32; m; m >>= 1) { s += __shfl_xor(s, m, 64); q += __shfl_xor(q, m, 64); }
  int wv = t >> 6;
  if ((t & 63) == 0) { ssum[wv] = s; ssq[wv] = q; }
  __syncthreads();
  s = ssum[0] + ssum[1] + ssum[2] + ssum[3];
  q = ssq[0] + ssq[1] + ssq[2] + ssq[3];
  float mu = s * (1.f / 1024.f);
  float var = q * (1.f / 1024.f) - mu * mu;
  float rs = rsqrtf(var + 1e-5f);
  f4_t o;
#pragma unroll
  for (int j = 0; j < 4; ++j)
    o[j] = (v[j] - mu) * rs * lnw[t * 4 + j] + lnb[t * 4 + j];
  *(f4_t*)(outp + (size_t)row * 1024 + t * 4) = o;
}

extern "C" void kernel_launch(void* const* d_in, const int* in_sizes, int n_in,
                              void* d_out, int out_size, void* d_ws, size_t ws_size,
                              hipStream_t stream)
{
  const float* x      = (const float*)d_in[0];   // [2,2048,1024]
  const float* inW    = (const float*)d_in[1];   // [4096,1024]
  const float* convW  = (const float*)d_in[2];   // [2048,1,4]
  const float* convB  = (const float*)d_in[3];   // [2048]
  const float* xprojW = (const float*)d_in[4];   // [96,2048]
  const float* dtW    = (const float*)d_in[5];   // [2048,64]
  const float* dtB    = (const float*)d_in[6];   // [2048]
  const float* alog   = (const float*)d_in[7];   // [2048,16]
  const float* Dw     = (const float*)d_in[8];   // [2048]
  const float* outW   = (const float*)d_in[9];   // [1024,2048]
  const float* lnw    = (const float*)d_in[10];  // [1024]
  const float* lnb    = (const float*)d_in[11];  // [1024]
  float* out = (float*)d_out;                    // [2,2048,1024] f32 (16 MiB)

  char* ws = (char*)d_ws;
  u16*   xiz    = (u16*)(ws);
  u16*   zy     = xiz + 8388608;
  u16*   xb     = (u16*)(ws + 33554432);
  u16*   inWb   = xb + 4194304;
  u16*   u_bf   = (u16*)(ws + 33554432);          // overwrites xb/inWb after gemm8_in
  u16*   dtA    = (u16*)(ws + 50331648);
  float* bc     = (float*)(ws + 50855936);
  u16*   xprojWb= (u16*)(ws + 51380224);
  u16*   dtWb   = (u16*)(ws + 51773440);
  u16*   outWb  = (u16*)(ws + 52035584);
  u16*   delta  = xiz;                            // overwrites dead xi
  u16*   xpart  = (u16*)d_out;                    // x_proj bf16 partials [8][4096][96] = 6.3 MB
  u16*   Sbuf   = dtA;                            // S (dtA dead after gemm_dt)
  u16*   Qbuf   = (u16*)d_out;                    // Q bf16 [2,64,2048,16] = 8.39 MB
  u16*   hbuf   = (u16*)(ws);                     // h bf16 [4096,1024] = 8.4 MB (delta dead)

  dim3 blk(256);
  // fused f32 -> bf16 conversions (one launch)
  cvt_all<<<10560, blk, 0, stream>>>(x, inW, xprojW, dtW, outW,
                                     xb, inWb, xprojWb, dtWb, outWb);
  // in_proj: [4096,1024] x [4096,1024]^T -> xi | z (bf16); 8-phase 256^2 (R2)
  gemm8_in<<<dim3(16, 16), dim3(512), 0, stream>>>(xb, inWb, xiz);
  // depthwise causal conv + silu -> u (bf16; 4 rows/thread)
  conv_silu<<<1024, blk, 0, stream>>>(xiz, convW, convB, u_bf);
  // x_proj split-K (8 x 256): bf16 partials into d_out
  gemm_xp<<<dim3(8, 32), blk, 0, stream>>>(u_bf, 2048, xprojWb, 2048, 256, 96, xpart, nullptr);
  xproj_reduce<<<1536, blk, 0, stream>>>(xpart, dtA, bc);
  // dt_proj + softplus -> delta (bf16, overwrites xi)
  gemm_dt<<<dim3(16, 32), blk, 0, stream>>>(dtA, 64, dtWb, 64, 64, 2048, delta, dtB);
  // chunk-parallel scan (64 chunks x 32 steps): S1 -> combine -> S3 (Q bf16)
  scan_s1<<<1024, blk, 0, stream>>>(delta, u_bf, bc, alog, Sbuf, Qbuf);
  scan_comb<<<256, blk, 0, stream>>>(Sbuf, Qbuf, alog);
  scan_s3<<<1024, blk, 0, stream>>>(delta, u_bf, bc, alog, Qbuf, Dw, zy);
  // out_proj single-K 4-phase 128x128 + fused residual: h = bf16(y+x) -> ws
  gemm4_out<<<dim3(8, 32), blk, 0, stream>>>(zy, outWb, x, hbuf);
  // LayerNorm (bf16 h) -> f32 out
  ln_kernel<<<4096, blk, 0, stream>>>(hbuf, lnw, lnb, out);
}